// Round 5
// baseline (616.955 us; speedup 1.0000x reference)
//
#include <hip/hip_runtime.h>
#include <math.h>

#define TPB 256

__device__ __forceinline__ float lrelu(float a){ return a >= 0.f ? a : 0.2f*a; }

typedef __attribute__((ext_vector_type(8))) short bf16x8;
typedef __attribute__((ext_vector_type(4))) float f32x4;

// round-to-nearest-even fp32 -> bf16 bits
__device__ __forceinline__ unsigned short bfr(float f){
  unsigned u = __float_as_uint(f);
  return (unsigned short)((u + 0x7fffu + ((u >> 16) & 1u)) >> 16);
}

// async global->LDS, 16B per lane; dest must be wave-uniform base (lane*16 implicit)
__device__ __forceinline__ void gl_lds16(const void* g, void* l){
  __builtin_amdgcn_global_load_lds(
      (const __attribute__((address_space(1))) void*)g,
      (__attribute__((address_space(3))) void*)l, 16, 0, 0);
}

// ---------------- graph build: atomic CSR (L2-resident counters, low contention) ----------------
// Replaces the 8-kernel segmented-histogram chain (~270MB of slab traffic, edge
// stream re-read NSEG times) with 3 streaming passes + tiny scan. Edge order
// within a node becomes nondeterministic (atomic ranks) — aggregation is a sum,
// so only ~1e-7 fp noise. Self-loop handled by init=1 and slot-0 planting.

__global__ void k_init(int* __restrict__ deg, int* __restrict__ cnt, int N){
  int i = blockIdx.x*TPB + threadIdx.x;
  if(i < N){ deg[i] = 1; cnt[i] = 1; }   // self-loop pre-counted
}

__global__ __launch_bounds__(256) void k_deg(const int* __restrict__ rows, const int* __restrict__ cols,
    int* __restrict__ deg, int* __restrict__ cnt, int E){
  int e = blockIdx.x*256 + threadIdx.x;
  if(e >= E) return;
  atomicAdd(&deg[rows[e]], 1);
  atomicAdd(&cnt[cols[e]], 1);
}

// exclusive scan of cnt[0..N) into offs[0..N], 1024 elements per block
__global__ void k_scan_block(const int* __restrict__ cnt, int* __restrict__ bsum, int N){
  __shared__ int sdata[256];
  int base = blockIdx.x*1024 + threadIdx.x*4;
  int s = 0;
  #pragma unroll
  for(int i=0;i<4;i++){ int idx = base+i; if(idx < N) s += cnt[idx]; }
  sdata[threadIdx.x] = s; __syncthreads();
  for(int off=128; off>0; off>>=1){
    if(threadIdx.x < off) sdata[threadIdx.x] += sdata[threadIdx.x+off];
    __syncthreads();
  }
  if(threadIdx.x == 0) bsum[blockIdx.x] = sdata[0];
}

__global__ void k_scan_bsum(int* bsum, int NB){
  __shared__ int s[256];
  int t = threadIdx.x;
  int v = (t < NB) ? bsum[t] : 0;
  s[t] = v; __syncthreads();
  for(int off=1; off<256; off<<=1){
    int add = (t >= off) ? s[t-off] : 0;
    __syncthreads();
    s[t] += add;
    __syncthreads();
  }
  if(t < NB) bsum[t] = s[t] - v;   // exclusive
}

// scan-write + fused epilogue: offs, dinv, self-loop at slot 0, cursor = offs+1
__global__ void k_scan_write(const int* __restrict__ cnt, const int* __restrict__ bsum,
                             const int* __restrict__ deg,
                             int* __restrict__ offs, int* __restrict__ cursor,
                             int* __restrict__ csr, float* __restrict__ dinv, int N){
  __shared__ int sdata[256];
  int t = threadIdx.x;
  int base = blockIdx.x*1024 + t*4;
  int v[4]; int s = 0;
  #pragma unroll
  for(int i=0;i<4;i++){ int idx = base+i; v[i] = (idx < N) ? cnt[idx] : 0; s += v[i]; }
  sdata[t] = s; __syncthreads();
  int mine = s;
  for(int off=1; off<256; off<<=1){
    int add = (t >= off) ? sdata[t-off] : 0;
    __syncthreads();
    sdata[t] += add;
    __syncthreads();
  }
  int run = sdata[t] - mine + bsum[blockIdx.x];
  #pragma unroll
  for(int i=0;i<4;i++){
    int idx = base+i;
    if(idx < N){
      offs[idx]   = run;
      csr[run]    = idx;        // self-loop occupies slot 0
      cursor[idx] = run + 1;
      dinv[idx]   = 1.f / sqrtf((float)deg[idx]);
      run += v[i];
      if(idx == N-1) offs[N] = run;
    }
  }
}

__global__ __launch_bounds__(256) void k_fillA(const int* __restrict__ rows, const int* __restrict__ cols,
    int* __restrict__ cursor, int* __restrict__ csr, int E){
  int e = blockIdx.x*256 + threadIdx.x;
  if(e >= E) return;
  int pos = atomicAdd(&cursor[cols[e]], 1);
  csr[pos] = rows[e];
}

// ---------------- W1 prep: transpose + bf16 hi/lo split ----------------

__global__ void k_prepW(const float* __restrict__ W, short* __restrict__ Whi,
                        short* __restrict__ Wlo){
  int idx = blockIdx.x*256 + threadIdx.x;   // 32768
  int n = idx >> 8, k = idx & 255;
  float f = W[k*128 + n];
  unsigned short h = bfr(f);
  float hf = __uint_as_float(((unsigned)h) << 16);
  Whi[n*256 + k] = (short)h;
  Wlo[n*256 + k] = (short)bfr(f - hf);
}

// ---------------- x prep: bf16 hi/lo planes (enables global_load_lds in gemm1) ----------------
// Pads to Npad rows with zeros so gemm1 tail staging is in-bounds.

__global__ __launch_bounds__(256) void k_prepX(const float* __restrict__ x,
    unsigned short* __restrict__ xhi, unsigned short* __restrict__ xlo,
    long long Ntot, long long NtotPad){
  long long i = ((long long)blockIdx.x*256 + threadIdx.x)*8;
  if(i >= NtotPad) return;
  float v[8] = {0.f,0.f,0.f,0.f,0.f,0.f,0.f,0.f};
  if(i < Ntot){
    const float4* x4 = (const float4*)x;
    float4 a = x4[i>>2], b = x4[(i>>2)+1];
    v[0]=a.x; v[1]=a.y; v[2]=a.z; v[3]=a.w;
    v[4]=b.x; v[5]=b.y; v[6]=b.z; v[7]=b.w;
  }
  unsigned hp[4], lp[4];
  #pragma unroll
  for(int j=0;j<4;j++){
    unsigned short h0 = bfr(v[2*j]), h1 = bfr(v[2*j+1]);
    float r0 = v[2*j]   - __uint_as_float(((unsigned)h0)<<16);
    float r1 = v[2*j+1] - __uint_as_float(((unsigned)h1)<<16);
    hp[j] = (unsigned)h0 | ((unsigned)h1<<16);
    lp[j] = (unsigned)bfr(r0) | ((unsigned)bfr(r1)<<16);
  }
  *((uint4*)(xhi + i)) = make_uint4(hp[0],hp[1],hp[2],hp[3]);
  *((uint4*)(xlo + i)) = make_uint4(lp[0],lp[1],lp[2],lp[3]);
}

// ---------------- layer 1 GEMM: pure global_load_lds double-buffered pipeline ----------------
// All staging via global_load_lds (no data VGPRs -> nothing for the allocator to
// spill). Linear LDS dest + pre-swizzled SOURCE + swizzled ds_read.
// Swizzle: 16B-slot ^= (row>>1)&3  -> conflict-free ds_read_b128 and even staging.
// LDS per buffer: Ah 4K | Al 4K | Bh 8K | Bl 8K = 24KB; x2 buffers = 48KB.

#define BUFB 24576
__global__ __launch_bounds__(256) void k_gemm1(
    const unsigned short* __restrict__ xhi, const unsigned short* __restrict__ xlo,
    const short* __restrict__ Whi, const short* __restrict__ Wlo,
    const float* __restrict__ att1,
    unsigned* __restrict__ xtb, float* __restrict__ sl, float* __restrict__ sr, int N){
  __shared__ __align__(16) char smem[2*BUFB];
  float* fx = (float*)smem;                  // epilogue alias: 64*68 floats = 17408 B
  float* att_sh = (float*)(smem + 17408);    // 256 floats

  int tid = threadIdx.x;
  int n0 = blockIdx.x * 64;
  int w = tid >> 6, l = tid & 63;
  int wm = w & 1, wn = w >> 1;               // wm: 32-row half, wn: 64-col half
  int lm = l & 15, lq = l >> 4;

  f32x4 acc[2][4];
  #pragma unroll
  for(int a=0;a<2;a++)
    #pragma unroll
    for(int b=0;b<4;b++) acc[a][b] = (f32x4){0.f,0.f,0.f,0.f};

  // staging source addrs (per lane). A: 256 units (64 rows x 4 slots), wave w owns
  // units [w*64, w*64+64). unit u -> row u>>2, slot u&3; source k-block = slot^((row>>1)&3).
  int ua = (w<<6) | l;
  int ar = ua >> 2, aq = ua & 3;
  int as_ = aq ^ ((ar >> 1) & 3);
  const unsigned short* gAh = xhi + (size_t)(n0 + ar)*256 + as_*8;
  const unsigned short* gAl = xlo + (size_t)(n0 + ar)*256 + as_*8;
  // B: 512 units (128 rows x 4 slots), wave w owns [w*64,+64) and [256+w*64,+64).
  int ub0 = (w<<6) | l,  ub1 = 256 + ub0;
  int br0 = ub0 >> 2, bs0 = (ub0 & 3) ^ ((br0 >> 1) & 3);
  int br1 = ub1 >> 2, bs1 = (ub1 & 3) ^ ((br1 >> 1) & 3);
  const short* gBh0 = Whi + br0*256 + bs0*8;
  const short* gBh1 = Whi + br1*256 + bs1*8;
  const short* gBl0 = Wlo + br0*256 + bs0*8;
  const short* gBl1 = Wlo + br1*256 + bs1*8;
  int woff = w << 10;   // wave's 1KB LDS slice per 4KB group

  // fragment read offsets (shorts; row stride 32 shorts = 64B), swizzled
  int offA[2], offB[4];
  #pragma unroll
  for(int mt=0;mt<2;mt++){
    int rr = wm*32 + mt*16 + lm;
    offA[mt] = rr*32 + ((lq ^ ((rr>>1)&3)) << 3);
  }
  #pragma unroll
  for(int nt=0;nt<4;nt++){
    int rr = wn*64 + nt*16 + lm;
    offB[nt] = rr*32 + ((lq ^ ((rr>>1)&3)) << 3);
  }

  // prologue: stage chunk 0 into buf 0
  {
    char* base = smem;
    gl_lds16(gAh,  base          + woff);
    gl_lds16(gAl,  base + 4096   + woff);
    gl_lds16(gBh0, base + 8192   + woff);
    gl_lds16(gBh1, base + 12288  + woff);
    gl_lds16(gBl0, base + 16384  + woff);
    gl_lds16(gBl1, base + 20480  + woff);
  }
  __syncthreads();   // drains vmcnt before first read

  int cur = 0;
  #pragma unroll 1
  for(int c=0;c<8;c++){
    if(c < 7){
      int kb = (c+1) << 5;   // +32 shorts per chunk
      char* base = smem + (cur^1)*BUFB;
      gl_lds16(gAh  + kb, base          + woff);
      gl_lds16(gAl  + kb, base + 4096   + woff);
      gl_lds16(gBh0 + kb, base + 8192   + woff);
      gl_lds16(gBh1 + kb, base + 12288  + woff);
      gl_lds16(gBl0 + kb, base + 16384  + woff);
      gl_lds16(gBl1 + kb, base + 20480  + woff);
    }
    short* Ah = (short*)(smem + cur*BUFB);
    short* Al = (short*)(smem + cur*BUFB + 4096);
    short* Bh = (short*)(smem + cur*BUFB + 8192);
    short* Bl = (short*)(smem + cur*BUFB + 16384);
    bf16x8 ah[2], al2[2];
    #pragma unroll
    for(int mt=0;mt<2;mt++){
      ah[mt]  = *((bf16x8*)&Ah[offA[mt]]);
      al2[mt] = *((bf16x8*)&Al[offA[mt]]);
    }
    #pragma unroll
    for(int nt=0;nt<4;nt++){
      bf16x8 bh = *((bf16x8*)&Bh[offB[nt]]);
      bf16x8 bl = *((bf16x8*)&Bl[offB[nt]]);
      #pragma unroll
      for(int mt=0;mt<2;mt++){
        acc[mt][nt] = __builtin_amdgcn_mfma_f32_16x16x32_bf16(ah[mt],  bh, acc[mt][nt], 0,0,0);
        acc[mt][nt] = __builtin_amdgcn_mfma_f32_16x16x32_bf16(ah[mt],  bl, acc[mt][nt], 0,0,0);
        acc[mt][nt] = __builtin_amdgcn_mfma_f32_16x16x32_bf16(al2[mt], bh, acc[mt][nt], 0,0,0);
      }
    }
    __syncthreads();   // drains staging vmcnt + finishes reads of cur
    cur ^= 1;
  }

  // epilogue 1: bf16 payload stores. C/D layout: col=lm, row=lq*4+v.
  #pragma unroll
  for(int mt=0;mt<2;mt++){
    #pragma unroll
    for(int v=0;v<4;v++){
      int row = n0 + wm*32 + mt*16 + lq*4 + v;
      if(row < N){
        unsigned p0 = (unsigned)bfr(acc[mt][0][v]) | ((unsigned)bfr(acc[mt][2][v])<<16);
        unsigned p1 = (unsigned)bfr(acc[mt][1][v]) | ((unsigned)bfr(acc[mt][3][v])<<16);
        int jb = wn*32 + lm;
        xtb[(size_t)row*64 + jb]      = p0;
        xtb[(size_t)row*64 + jb + 16] = p1;
      }
    }
  }

  // epilogue 2: sl/sr via LDS transpose (fp32, pad-68 rows).
  att_sh[tid] = att1[tid];    // 256 floats = full att1
  #pragma unroll 1
  for(int p=0;p<2;p++){
    __syncthreads();
    if(wn == p){
      #pragma unroll
      for(int mt=0;mt<2;mt++)
        #pragma unroll
        for(int nt=0;nt<4;nt++)
          #pragma unroll
          for(int v=0;v<4;v++)
            fx[(wm*32 + mt*16 + lq*4 + v)*68 + nt*16 + lm] = acc[mt][nt][v];
    }
    __syncthreads();
    if(tid < 128){
      int rloc = tid >> 1, hh = tid & 1;
      int head = p*2 + hh;
      float a = 0.f, b = 0.f;
      #pragma unroll
      for(int c4=0;c4<8;c4++){
        float4 xv  = *((const float4*)&fx[rloc*68 + hh*32 + c4*4]);
        float4 alv = *((const float4*)&att_sh[head*64 + c4*4]);
        float4 arv = *((const float4*)&att_sh[head*64 + 32 + c4*4]);
        a += xv.x*alv.x + xv.y*alv.y + xv.z*alv.z + xv.w*alv.w;
        b += xv.x*arv.x + xv.y*arv.y + xv.z*arv.z + xv.w*arv.w;
      }
      int row = n0 + rloc;
      if(row < N){
        sl[(size_t)row*4 + head] = a;
        sr[(size_t)row*4 + head] = b;
      }
    }
  }
}

// ---------------- layer 1 aggregation: one wave per target node ----------------

__global__ __launch_bounds__(64) void k_agg1(const int* __restrict__ offs, const int* __restrict__ srcs,
    const float* __restrict__ sl, const float* __restrict__ sr, const float* __restrict__ dinv,
    const unsigned* __restrict__ xtb, const float* __restrict__ b1, float* __restrict__ h, int N){
  __shared__ int   s_sh[64];
  __shared__ float w_sh[64*4];
  int n = blockIdx.x;
  if(n >= N) return;
  int lane = threadIdx.x;
  int beg = offs[n], end = offs[n+1];
  int deg = end - beg;
  float4 sln = *((const float4*)(sl + (size_t)n*4));
  int h0 = lane >> 5;
  float den0=0.f,den1=0.f,den2=0.f,den3=0.f;
  float acc0=0.f, acc1=0.f;

  if(deg <= 64){
    int j = beg + lane;
    int s = 0; float wd = 0.f;
    float a0=-1e30f, a1=-1e30f, a2=-1e30f, a3=-1e30f;
    if(j < end){
      s = srcs[j];
      float4 a = *((const float4*)(sr + (size_t)s*4));
      a0 = lrelu(sln.x + a.x);
      a1 = lrelu(sln.y + a.y);
      a2 = lrelu(sln.z + a.z);
      a3 = lrelu(sln.w + a.w);
      wd = dinv[s];
    }
    float m0=a0,m1=a1,m2=a2,m3=a3;
    #pragma unroll
    for(int o=32;o>0;o>>=1){
      m0 = fmaxf(m0, __shfl_xor(m0,o));
      m1 = fmaxf(m1, __shfl_xor(m1,o));
      m2 = fmaxf(m2, __shfl_xor(m2,o));
      m3 = fmaxf(m3, __shfl_xor(m3,o));
    }
    den0 = __expf(a0 - m0);
    den1 = __expf(a1 - m1);
    den2 = __expf(a2 - m2);
    den3 = __expf(a3 - m3);
    s_sh[lane] = s;
    w_sh[lane*4+0] = wd*den0;
    w_sh[lane*4+1] = wd*den1;
    w_sh[lane*4+2] = wd*den2;
    w_sh[lane*4+3] = wd*den3;
    __syncthreads();
    int k = 0;
    for(; k+8<=deg; k+=8){
      int sk[8];
      #pragma unroll
      for(int u=0;u<8;u++) sk[u] = __builtin_amdgcn_readfirstlane(s_sh[k+u]);
      unsigned pv[8];
      #pragma unroll
      for(int u=0;u<8;u++) pv[u] = xtb[(size_t)sk[u]*64 + lane];
      #pragma unroll
      for(int u=0;u<8;u++){
        float2 wv = *((const float2*)&w_sh[(k+u)*4 + h0*2]);
        acc0 += wv.x * __uint_as_float(pv[u] << 16);
        acc1 += wv.y * __uint_as_float(pv[u] & 0xffff0000u);
      }
    }
    for(; k<deg; k++){
      int sk = __builtin_amdgcn_readfirstlane(s_sh[k]);
      unsigned pvv = xtb[(size_t)sk*64 + lane];
      float2 wv = *((const float2*)&w_sh[k*4 + h0*2]);
      acc0 += wv.x * __uint_as_float(pvv << 16);
      acc1 += wv.y * __uint_as_float(pvv & 0xffff0000u);
    }
  } else {
    float m0=-1e30f,m1=-1e30f,m2=-1e30f,m3=-1e30f;
    for(int j=beg+lane; j<end; j+=64){
      int s = srcs[j];
      float4 a = *((const float4*)(sr + (size_t)s*4));
      m0 = fmaxf(m0, lrelu(sln.x + a.x));
      m1 = fmaxf(m1, lrelu(sln.y + a.y));
      m2 = fmaxf(m2, lrelu(sln.z + a.z));
      m3 = fmaxf(m3, lrelu(sln.w + a.w));
    }
    #pragma unroll
    for(int o=32;o>0;o>>=1){
      m0 = fmaxf(m0, __shfl_xor(m0,o));
      m1 = fmaxf(m1, __shfl_xor(m1,o));
      m2 = fmaxf(m2, __shfl_xor(m2,o));
      m3 = fmaxf(m3, __shfl_xor(m3,o));
    }
    for(int c0=beg; c0<end; c0+=64){
      int cnt = min(64, end-c0);
      int j = c0 + lane;
      float e0=0.f,e1=0.f,e2=0.f,e3=0.f, wd=0.f; int s=0;
      if(j<end){
        s = srcs[j];
        float4 a = *((const float4*)(sr + (size_t)s*4));
        e0 = __expf(lrelu(sln.x + a.x) - m0);
        e1 = __expf(lrelu(sln.y + a.y) - m1);
        e2 = __expf(lrelu(sln.z + a.z) - m2);
        e3 = __expf(lrelu(sln.w + a.w) - m3);
        wd = dinv[s];
      }
      den0+=e0; den1+=e1; den2+=e2; den3+=e3;
      s_sh[lane] = s;
      w_sh[lane*4+0] = wd*e0;
      w_sh[lane*4+1] = wd*e1;
      w_sh[lane*4+2] = wd*e2;
      w_sh[lane*4+3] = wd*e3;
      __syncthreads();
      int k = 0;
      for(; k+8<=cnt; k+=8){
        int sk[8];
        #pragma unroll
        for(int u=0;u<8;u++) sk[u] = __builtin_amdgcn_readfirstlane(s_sh[k+u]);
        unsigned pv[8];
        #pragma unroll
        for(int u=0;u<8;u++) pv[u] = xtb[(size_t)sk[u]*64 + lane];
        #pragma unroll
        for(int u=0;u<8;u++){
          float2 wv = *((const float2*)&w_sh[(k+u)*4 + h0*2]);
          acc0 += wv.x * __uint_as_float(pv[u] << 16);
          acc1 += wv.y * __uint_as_float(pv[u] & 0xffff0000u);
        }
      }
      for(; k<cnt; k++){
        int sk = __builtin_amdgcn_readfirstlane(s_sh[k]);
        unsigned pvv = xtb[(size_t)sk*64 + lane];
        float2 wv = *((const float2*)&w_sh[k*4 + h0*2]);
        acc0 += wv.x * __uint_as_float(pvv << 16);
        acc1 += wv.y * __uint_as_float(pvv & 0xffff0000u);
      }
      __syncthreads();
    }
  }
  #pragma unroll
  for(int o=32;o>0;o>>=1){
    den0 += __shfl_xor(den0,o);
    den1 += __shfl_xor(den1,o);
    den2 += __shfl_xor(den2,o);
    den3 += __shfl_xor(den3,o);
  }
  float din = dinv[n];
  int ch0 = (lane < 32) ? lane : lane + 32;   // pairs (c, c+32)
  int ch1 = ch0 + 32;
  float d0 = (lane < 32) ? den0 : den2;
  float d1 = (lane < 32) ? den1 : den3;
  float o0 = din*acc0/(d0 + 1e-16f) + b1[ch0];
  float o1 = din*acc1/(d1 + 1e-16f) + b1[ch1];
  h[(size_t)n*128 + ch0] = o0 > 0.f ? o0 : 0.f;
  h[(size_t)n*128 + ch1] = o1 > 0.f ? o1 : 0.f;
}

// ---------------- layer 2 GEMM (128->16) + attention scalars, bf16-pair payload ----------------

__global__ __launch_bounds__(256) void k_gemm2(const float* __restrict__ hmat, const float* __restrict__ W2,
    const float* __restrict__ att2, unsigned* __restrict__ xt2b,
    float* __restrict__ sl2, float* __restrict__ sr2, int N){
  __shared__ float hs[16*132];
  __shared__ float ws[16*132];
  __shared__ float xs[16*16];
  int t = threadIdx.x;
  int n0 = blockIdx.x * 16;
  #pragma unroll
  for(int i=0;i<8;i++){
    int idx = t + 256*i;
    int k = idx >> 4, c = idx & 15;
    ws[c*132 + k] = W2[idx];
  }
  #pragma unroll
  for(int i=0;i<2;i++){
    int idx = t + 256*i;
    int r = idx >> 5, k4 = idx & 31;
    int n = n0 + r;
    float4 v = make_float4(0.f,0.f,0.f,0.f);
    if(n < N) v = ((const float4*)hmat)[(size_t)n*32 + k4];
    *((float4*)&hs[r*132 + k4*4]) = v;
  }
  __syncthreads();
  int r = t >> 4, c = t & 15;
  float acc = 0.f;
  for(int k=0;k<128;k+=4){
    float4 hv = *((const float4*)&hs[r*132+k]);
    float4 wv = *((const float4*)&ws[c*132+k]);
    acc += hv.x*wv.x + hv.y*wv.y + hv.z*wv.z + hv.w*wv.w;
  }
  xs[r*16 + c] = acc;
  __syncthreads();
  int n = n0 + r;
  if(c < 8 && n < N){
    unsigned pk = (unsigned)bfr(xs[r*16+c]) | ((unsigned)bfr(xs[r*16+c+8])<<16);
    xt2b[(size_t)n*8 + c] = pk;
  }
  if(t < 16){
    int nn = n0 + t;
    if(nn < N){
      float a = 0.f, b = 0.f;
      #pragma unroll
      for(int cc=0;cc<16;cc++){ float v = xs[t*16+cc]; a += v*att2[cc]; b += v*att2[16+cc]; }
      sl2[nn] = a; sr2[nn] = b;
    }
  }
}

// ---------------- layer 2 aggregation: 8 edge-groups x 8 channel-lanes ----------------

__global__ __launch_bounds__(64) void k_agg2(const int* __restrict__ offs, const int* __restrict__ srcs,
    const float* __restrict__ sl2, const float* __restrict__ sr2, const float* __restrict__ dinv,
    const unsigned* __restrict__ xt2b, const float* __restrict__ b2, float* __restrict__ out, int N){
  __shared__ int   s_sh[64];
  __shared__ float w_sh[64];
  int n = blockIdx.x;
  if(n >= N) return;
  int lane = threadIdx.x;
  int beg = offs[n], end = offs[n+1];
  int deg = end - beg;
  float sln = sl2[n];
  float den = 0.f, acc0 = 0.f, acc1 = 0.f;
  int grp = lane >> 3, ch = lane & 7;

  if(deg <= 64){
    int j = beg + lane;
    int s = 0; float wd = 0.f; float a = -1e30f;
    if(j < end){
      s = srcs[j];
      a = lrelu(sln + sr2[s]);
      wd = dinv[s];
    }
    float m = a;
    #pragma unroll
    for(int o=32;o>0;o>>=1) m = fmaxf(m, __shfl_xor(m,o));
    float e = __expf(a - m);
    den = e;
    s_sh[lane] = s;
    w_sh[lane] = wd*e;
    __syncthreads();
    for(int k=0;k<deg;k+=8){
      int kk = k + grp;
      if(kk < deg){
        int sk = s_sh[kk];
        float wk = w_sh[kk];
        unsigned pv = xt2b[(size_t)sk*8 + ch];
        acc0 += wk * __uint_as_float(pv << 16);
        acc1 += wk * __uint_as_float(pv & 0xffff0000u);
      }
    }
  } else {
    float m = -1e30f;
    for(int j=beg+lane; j<end; j+=64)
      m = fmaxf(m, lrelu(sln + sr2[srcs[j]]));
    #pragma unroll
    for(int o=32;o>0;o>>=1) m = fmaxf(m, __shfl_xor(m,o));
    for(int c0=beg; c0<end; c0+=64){
      int cnt = min(64, end-c0);
      int j = c0 + lane;
      float e=0.f, wd=0.f; int s=0;
      if(j<end){
        s = srcs[j];
        e = __expf(lrelu(sln + sr2[s]) - m);
        wd = dinv[s];
      }
      den += e;
      s_sh[lane] = s;
      w_sh[lane] = wd*e;
      __syncthreads();
      for(int k=0;k<cnt;k+=8){
        int kk = k + grp;
        if(kk < cnt){
          int sk = s_sh[kk];
          float wk = w_sh[kk];
          unsigned pv = xt2b[(size_t)sk*8 + ch];
          acc0 += wk * __uint_as_float(pv << 16);
          acc1 += wk * __uint_as_float(pv & 0xffff0000u);
        }
      }
      __syncthreads();
    }
  }
  #pragma unroll
  for(int o=32;o>0;o>>=1) den += __shfl_xor(den,o);
  acc0 += __shfl_xor(acc0,8);  acc0 += __shfl_xor(acc0,16);  acc0 += __shfl_xor(acc0,32);
  acc1 += __shfl_xor(acc1,8);  acc1 += __shfl_xor(acc1,16);  acc1 += __shfl_xor(acc1,32);
  if(lane < 8){
    float din = dinv[n];
    out[(size_t)n*16 + lane]     = din*acc0/(den + 1e-16f) + b2[lane];
    out[(size_t)n*16 + lane + 8] = din*acc1/(den + 1e-16f) + b2[lane+8];
  }
}

// ---------------- host launch ----------------

extern "C" void kernel_launch(void* const* d_in, const int* in_sizes, int n_in,
                              void* d_out, int out_size, void* d_ws, size_t ws_size,
                              hipStream_t stream){
  const float* x    = (const float*)d_in[0];
  const int*   ei   = (const int*)d_in[1];
  const float* W1   = (const float*)d_in[2];
  const float* att1 = (const float*)d_in[3];
  const float* b1   = (const float*)d_in[4];
  const float* W2   = (const float*)d_in[5];
  const float* att2 = (const float*)d_in[6];
  const float* b2   = (const float*)d_in[7];
  int N = in_sizes[0] / 256;
  int E = in_sizes[1] / 2;
  const int* rows = ei;
  const int* cols = ei + E;
  float* out = (float*)d_out;

  int ET   = E + N;
  int Npad = (N + 63) & ~63;

  char* p = (char*)d_ws;
  auto alloc = [&](size_t bytes)->void*{ void* q = p; p += (bytes + 255) & ~(size_t)255; return q; };
  int*      cnt     = (int*)alloc((size_t)N*4);
  int*      deg     = (int*)alloc((size_t)N*4);
  int*      cursor  = (int*)alloc((size_t)N*4);
  int*      offs    = (int*)alloc((size_t)(N+1)*4);
  int*      bsum    = (int*)alloc(256*4);
  int*      csr     = (int*)alloc((size_t)ET*4);
  float*    dinv    = (float*)alloc((size_t)N*4);
  unsigned* xtb     = (unsigned*)alloc((size_t)N*64*4);
  float*    sl1     = (float*)alloc((size_t)N*16);
  float*    sr1     = (float*)alloc((size_t)N*16);
  float*    hbuf    = (float*)alloc((size_t)Npad*512);   // also hosts xlo (Npad*256*2B)
  unsigned* xt2b    = (unsigned*)alloc((size_t)N*8*4);
  float*    sl2     = (float*)alloc((size_t)N*4);
  float*    sr2     = (float*)alloc((size_t)N*4);
  short*    Whi     = (short*)alloc((size_t)128*256*2);
  short*    Wlo     = (short*)alloc((size_t)128*256*2);
  unsigned short* xhi = (unsigned short*)alloc((size_t)Npad*256*2);

  // transient alias (consumed before its host is written):
  unsigned short* xlo = (unsigned short*)hbuf;   // consumed by k_gemm1, before k_agg1 writes hbuf

  int gN = (N + TPB - 1) / TPB;
  int gE = (E + 255) / 256;
  int NB = (N + 1023) / 1024;

  k_init<<<gN, TPB, 0, stream>>>(deg, cnt, N);
  k_deg<<<gE, 256, 0, stream>>>(rows, cols, deg, cnt, E);
  k_scan_block<<<NB, 256, 0, stream>>>(cnt, bsum, N);
  k_scan_bsum<<<1, 256, 0, stream>>>(bsum, NB);
  k_scan_write<<<NB, 256, 0, stream>>>(cnt, bsum, deg, offs, cursor, csr, dinv, N);
  k_fillA<<<gE, 256, 0, stream>>>(rows, cols, cursor, csr, E);

  k_prepW<<<128, 256, 0, stream>>>(W1, Whi, Wlo);
  long long Ntot = (long long)N*256, NtotPad = (long long)Npad*256;
  k_prepX<<<(int)((NtotPad + 2047)/2048), 256, 0, stream>>>(x, xhi, xlo, Ntot, NtotPad);
  k_gemm1<<<(N + 63)/64, 256, 0, stream>>>(xhi, xlo, Whi, Wlo, att1, xtb, sl1, sr1, N);
  k_agg1<<<N, 64, 0, stream>>>(offs, csr, sl1, sr1, dinv, xtb, b1, hbuf, N);

  k_gemm2<<<(N + 15)/16, 256, 0, stream>>>(hbuf, W2, att2, xt2b, sl2, sr2, N);
  k_agg2<<<N, 64, 0, stream>>>(offs, csr, sl2, sr2, dinv, xt2b, b2, out, N);
}

// Round 6
// 534.084 us; speedup vs baseline: 1.1552x; 1.1552x over previous
//
#include <hip/hip_runtime.h>
#include <math.h>

#define TPB 256
#define SEGN 512            // nodes per sort segment (col>>9)
#define SCAP 14336          // LDS sort buffer capacity (56KB); >> avg 8.8K slots/segment
#define CHB 8192            // edges per bucket block

__device__ __forceinline__ float lrelu(float a){ return a >= 0.f ? a : 0.2f*a; }

typedef __attribute__((ext_vector_type(8))) short bf16x8;
typedef __attribute__((ext_vector_type(4))) float f32x4;

// round-to-nearest-even fp32 -> bf16 bits
__device__ __forceinline__ unsigned short bfr(float f){
  unsigned u = __float_as_uint(f);
  return (unsigned short)((u + 0x7fffu + ((u >> 16) & 1u)) >> 16);
}

// async global->LDS, 16B per lane; dest must be wave-uniform base (lane*16 implicit)
__device__ __forceinline__ void gl_lds16(const void* g, void* l){
  __builtin_amdgcn_global_load_lds(
      (const __attribute__((address_space(1))) void*)g,
      (__attribute__((address_space(3))) void*)l, 16, 0, 0);
}

// ---------------- graph build ----------------
// Round-5 lesson: scattered 4B csr writes cost a full 64B HBM line each
// (k_fillA: WRITE_SIZE 104MB = ET*64B, 128us). Fix: counting-sort per
// 512-node segment — assemble the csr slice in LDS, stream it out in full
// lines. Packed edge = (col&511)<<17 | row  (requires N < 131072).

__global__ void k_init(int* __restrict__ deg, int* __restrict__ cnt, int N){
  int i = blockIdx.x*TPB + threadIdx.x;
  if(i < N){ deg[i] = 1; cnt[i] = 1; }   // self-loop pre-counted
}

// fire-and-forget atomics (no return value -> no dependency stall)
__global__ __launch_bounds__(256) void k_deg(const int* __restrict__ rows, const int* __restrict__ cols,
    int* __restrict__ deg, int* __restrict__ cnt, int E){
  int e = blockIdx.x*256 + threadIdx.x;
  if(e >= E) return;
  atomicAdd(&deg[rows[e]], 1);
  atomicAdd(&cnt[cols[e]], 1);
}

// exclusive scan of cnt[0..N) into offs[0..N], 1024 elements per block
__global__ void k_scan_block(const int* __restrict__ cnt, int* __restrict__ bsum, int N){
  __shared__ int sdata[256];
  int base = blockIdx.x*1024 + threadIdx.x*4;
  int s = 0;
  #pragma unroll
  for(int i=0;i<4;i++){ int idx = base+i; if(idx < N) s += cnt[idx]; }
  sdata[threadIdx.x] = s; __syncthreads();
  for(int off=128; off>0; off>>=1){
    if(threadIdx.x < off) sdata[threadIdx.x] += sdata[threadIdx.x+off];
    __syncthreads();
  }
  if(threadIdx.x == 0) bsum[blockIdx.x] = sdata[0];
}

__global__ void k_scan_bsum(int* bsum, int NB){
  __shared__ int s[256];
  int t = threadIdx.x;
  int v = (t < NB) ? bsum[t] : 0;
  s[t] = v; __syncthreads();
  for(int off=1; off<256; off<<=1){
    int add = (t >= off) ? s[t-off] : 0;
    __syncthreads();
    s[t] += add;
    __syncthreads();
  }
  if(t < NB) bsum[t] = s[t] - v;   // exclusive
}

// offs + dinv only (csr assembly moved to k_sortfill)
__global__ void k_scan_write(const int* __restrict__ cnt, const int* __restrict__ bsum,
                             const int* __restrict__ deg,
                             int* __restrict__ offs, float* __restrict__ dinv, int N){
  __shared__ int sdata[256];
  int t = threadIdx.x;
  int base = blockIdx.x*1024 + t*4;
  int v[4]; int s = 0;
  #pragma unroll
  for(int i=0;i<4;i++){ int idx = base+i; v[i] = (idx < N) ? cnt[idx] : 0; s += v[i]; }
  sdata[t] = s; __syncthreads();
  int mine = s;
  for(int off=1; off<256; off<<=1){
    int add = (t >= off) ? sdata[t-off] : 0;
    __syncthreads();
    sdata[t] += add;
    __syncthreads();
  }
  int run = sdata[t] - mine + bsum[blockIdx.x];
  #pragma unroll
  for(int i=0;i<4;i++){
    int idx = base+i;
    if(idx < N){
      offs[idx] = run;
      dinv[idx] = 1.f / sqrtf((float)deg[idx]);
      run += v[i];
      if(idx == N-1) offs[N] = run;
    }
  }
}

// per-segment edge counts -> exclusive scan -> ebase; bcur = ebase copy
__global__ void k_ebase(const int* __restrict__ offs, int* __restrict__ ebase,
                        int* __restrict__ bcur, int N, int NSEG2){
  __shared__ int s[256];
  int t = threadIdx.x;
  int ec = 0;
  if(t < NSEG2){
    int lo = t*SEGN, hi = min(N, lo+SEGN);
    ec = (offs[hi] - offs[lo]) - (hi - lo);   // real edges only (minus self-loops)
  }
  s[t] = ec; __syncthreads();
  for(int off=1; off<256; off<<=1){
    int add = (t >= off) ? s[t-off] : 0;
    __syncthreads();
    s[t] += add;
    __syncthreads();
  }
  if(t < NSEG2){
    int ex = s[t] - ec;
    ebase[t] = ex;
    bcur[t]  = ex;
    if(t == NSEG2-1) ebase[NSEG2] = s[t];
  }
}

// bucket scatter: LDS-rank per segment + one global reservation per seg per round
// -> ebuf writes are contiguous runs (line-granular), not per-edge scatter.
__global__ __launch_bounds__(256) void k_bucket(const int* __restrict__ rows, const int* __restrict__ cols,
    int* __restrict__ bcur, unsigned* __restrict__ ebuf, int E, int NSEG2){
  __shared__ int lhist[256];
  __shared__ int lbase[256];
  int tid = threadIdx.x;
  int e0 = blockIdx.x * CHB;
  #pragma unroll 1
  for(int r=0; r<4; r++){
    lhist[tid] = 0;
    __syncthreads();
    int eb = e0 + r*2048;
    unsigned pk[8]; int sg[8], rk[8];
    #pragma unroll
    for(int i=0;i<8;i++){
      int e = eb + i*256 + tid;
      sg[i] = -1;
      if(e < E){
        int cc = cols[e], rr = rows[e];
        sg[i] = cc >> 9;
        pk[i] = ((unsigned)(cc & (SEGN-1)) << 17) | (unsigned)rr;
        rk[i] = atomicAdd(&lhist[sg[i]], 1);
      }
    }
    __syncthreads();
    if(tid < NSEG2){
      int c = lhist[tid];
      lbase[tid] = c ? atomicAdd(&bcur[tid], c) : 0;
    }
    __syncthreads();
    #pragma unroll
    for(int i=0;i<8;i++)
      if(sg[i] >= 0) ebuf[lbase[sg[i]] + rk[i]] = pk[i];
    __syncthreads();
  }
}

// counting-sort fill: assemble segment's csr slice in LDS, stream out coalesced.
__global__ __launch_bounds__(256) void k_sortfill(const int* __restrict__ offs,
    const int* __restrict__ ebase, const unsigned* __restrict__ ebuf,
    int* __restrict__ csr, int N){
  __shared__ int lcur[SEGN];
  __shared__ int lbuf[SCAP];
  int s = blockIdx.x, tid = threadIdx.x;
  int lo = s*SEGN;
  int nn = min(SEGN, N - lo);
  int base = offs[lo];
  int total = offs[lo+nn] - base;
  int eb = ebase[s], ec = ebase[s+1] - eb;
  if(total <= SCAP){
    for(int li=tid; li<nn; li+=256){
      int o = offs[lo+li] - base;
      lbuf[o]  = lo + li;      // self-loop at slot 0 of each node
      lcur[li] = o + 1;
    }
    __syncthreads();
    for(int j=tid; j<ec; j+=256){
      unsigned pk = ebuf[eb + j];
      int li  = pk >> 17;
      int row = pk & 0x1FFFF;
      int p = atomicAdd(&lcur[li], 1);   // LDS atomic
      lbuf[p] = row;
    }
    __syncthreads();
    for(int j=tid; j<total; j+=256) csr[base + j] = lbuf[j];   // full-line streaming
  } else {
    // overflow fallback (statistically never at deg~17): direct scatter
    for(int li=tid; li<nn; li+=256){
      int o = offs[lo+li];
      csr[o] = lo + li;
      lcur[li] = o + 1;
    }
    __syncthreads();
    for(int j=tid; j<ec; j+=256){
      unsigned pk = ebuf[eb + j];
      int li  = pk >> 17;
      int row = pk & 0x1FFFF;
      int p = atomicAdd(&lcur[li], 1);
      csr[p] = row;
    }
  }
}

// ---------------- W1 prep: transpose + bf16 hi/lo split ----------------

__global__ void k_prepW(const float* __restrict__ W, short* __restrict__ Whi,
                        short* __restrict__ Wlo){
  int idx = blockIdx.x*256 + threadIdx.x;   // 32768
  int n = idx >> 8, k = idx & 255;
  float f = W[k*128 + n];
  unsigned short h = bfr(f);
  float hf = __uint_as_float(((unsigned)h) << 16);
  Whi[n*256 + k] = (short)h;
  Wlo[n*256 + k] = (short)bfr(f - hf);
}

// ---------------- x prep: bf16 hi/lo planes ----------------

__global__ __launch_bounds__(256) void k_prepX(const float* __restrict__ x,
    unsigned short* __restrict__ xhi, unsigned short* __restrict__ xlo,
    long long Ntot, long long NtotPad){
  long long i = ((long long)blockIdx.x*256 + threadIdx.x)*8;
  if(i >= NtotPad) return;
  float v[8] = {0.f,0.f,0.f,0.f,0.f,0.f,0.f,0.f};
  if(i < Ntot){
    const float4* x4 = (const float4*)x;
    float4 a = x4[i>>2], b = x4[(i>>2)+1];
    v[0]=a.x; v[1]=a.y; v[2]=a.z; v[3]=a.w;
    v[4]=b.x; v[5]=b.y; v[6]=b.z; v[7]=b.w;
  }
  unsigned hp[4], lp[4];
  #pragma unroll
  for(int j=0;j<4;j++){
    unsigned short h0 = bfr(v[2*j]), h1 = bfr(v[2*j+1]);
    float r0 = v[2*j]   - __uint_as_float(((unsigned)h0)<<16);
    float r1 = v[2*j+1] - __uint_as_float(((unsigned)h1)<<16);
    hp[j] = (unsigned)h0 | ((unsigned)h1<<16);
    lp[j] = (unsigned)bfr(r0) | ((unsigned)bfr(r1)<<16);
  }
  *((uint4*)(xhi + i)) = make_uint4(hp[0],hp[1],hp[2],hp[3]);
  *((uint4*)(xlo + i)) = make_uint4(lp[0],lp[1],lp[2],lp[3]);
}

// ---------------- layer 1 GEMM: pure global_load_lds double-buffered pipeline ----------------

#define BUFB 24576
__global__ __launch_bounds__(256) void k_gemm1(
    const unsigned short* __restrict__ xhi, const unsigned short* __restrict__ xlo,
    const short* __restrict__ Whi, const short* __restrict__ Wlo,
    const float* __restrict__ att1,
    unsigned* __restrict__ xtb, float* __restrict__ sl, float* __restrict__ sr, int N){
  __shared__ __align__(16) char smem[2*BUFB];
  float* fx = (float*)smem;                  // epilogue alias: 64*68 floats
  float* att_sh = (float*)(smem + 17408);    // 256 floats

  int tid = threadIdx.x;
  int n0 = blockIdx.x * 64;
  int w = tid >> 6, l = tid & 63;
  int wm = w & 1, wn = w >> 1;
  int lm = l & 15, lq = l >> 4;

  f32x4 acc[2][4];
  #pragma unroll
  for(int a=0;a<2;a++)
    #pragma unroll
    for(int b=0;b<4;b++) acc[a][b] = (f32x4){0.f,0.f,0.f,0.f};

  int ua = (w<<6) | l;
  int ar = ua >> 2, aq = ua & 3;
  int as_ = aq ^ ((ar >> 1) & 3);
  const unsigned short* gAh = xhi + (size_t)(n0 + ar)*256 + as_*8;
  const unsigned short* gAl = xlo + (size_t)(n0 + ar)*256 + as_*8;
  int ub0 = (w<<6) | l,  ub1 = 256 + ub0;
  int br0 = ub0 >> 2, bs0 = (ub0 & 3) ^ ((br0 >> 1) & 3);
  int br1 = ub1 >> 2, bs1 = (ub1 & 3) ^ ((br1 >> 1) & 3);
  const short* gBh0 = Whi + br0*256 + bs0*8;
  const short* gBh1 = Whi + br1*256 + bs1*8;
  const short* gBl0 = Wlo + br0*256 + bs0*8;
  const short* gBl1 = Wlo + br1*256 + bs1*8;
  int woff = w << 10;

  int offA[2], offB[4];
  #pragma unroll
  for(int mt=0;mt<2;mt++){
    int rr = wm*32 + mt*16 + lm;
    offA[mt] = rr*32 + ((lq ^ ((rr>>1)&3)) << 3);
  }
  #pragma unroll
  for(int nt=0;nt<4;nt++){
    int rr = wn*64 + nt*16 + lm;
    offB[nt] = rr*32 + ((lq ^ ((rr>>1)&3)) << 3);
  }

  {
    char* base = smem;
    gl_lds16(gAh,  base          + woff);
    gl_lds16(gAl,  base + 4096   + woff);
    gl_lds16(gBh0, base + 8192   + woff);
    gl_lds16(gBh1, base + 12288  + woff);
    gl_lds16(gBl0, base + 16384  + woff);
    gl_lds16(gBl1, base + 20480  + woff);
  }
  __syncthreads();

  int cur = 0;
  #pragma unroll 1
  for(int c=0;c<8;c++){
    if(c < 7){
      int kb = (c+1) << 5;
      char* base = smem + (cur^1)*BUFB;
      gl_lds16(gAh  + kb, base          + woff);
      gl_lds16(gAl  + kb, base + 4096   + woff);
      gl_lds16(gBh0 + kb, base + 8192   + woff);
      gl_lds16(gBh1 + kb, base + 12288  + woff);
      gl_lds16(gBl0 + kb, base + 16384  + woff);
      gl_lds16(gBl1 + kb, base + 20480  + woff);
    }
    short* Ah = (short*)(smem + cur*BUFB);
    short* Al = (short*)(smem + cur*BUFB + 4096);
    short* Bh = (short*)(smem + cur*BUFB + 8192);
    short* Bl = (short*)(smem + cur*BUFB + 16384);
    bf16x8 ah[2], al2[2];
    #pragma unroll
    for(int mt=0;mt<2;mt++){
      ah[mt]  = *((bf16x8*)&Ah[offA[mt]]);
      al2[mt] = *((bf16x8*)&Al[offA[mt]]);
    }
    #pragma unroll
    for(int nt=0;nt<4;nt++){
      bf16x8 bh = *((bf16x8*)&Bh[offB[nt]]);
      bf16x8 bl = *((bf16x8*)&Bl[offB[nt]]);
      #pragma unroll
      for(int mt=0;mt<2;mt++){
        acc[mt][nt] = __builtin_amdgcn_mfma_f32_16x16x32_bf16(ah[mt],  bh, acc[mt][nt], 0,0,0);
        acc[mt][nt] = __builtin_amdgcn_mfma_f32_16x16x32_bf16(ah[mt],  bl, acc[mt][nt], 0,0,0);
        acc[mt][nt] = __builtin_amdgcn_mfma_f32_16x16x32_bf16(al2[mt], bh, acc[mt][nt], 0,0,0);
      }
    }
    __syncthreads();
    cur ^= 1;
  }

  #pragma unroll
  for(int mt=0;mt<2;mt++){
    #pragma unroll
    for(int v=0;v<4;v++){
      int row = n0 + wm*32 + mt*16 + lq*4 + v;
      if(row < N){
        unsigned p0 = (unsigned)bfr(acc[mt][0][v]) | ((unsigned)bfr(acc[mt][2][v])<<16);
        unsigned p1 = (unsigned)bfr(acc[mt][1][v]) | ((unsigned)bfr(acc[mt][3][v])<<16);
        int jb = wn*32 + lm;
        xtb[(size_t)row*64 + jb]      = p0;
        xtb[(size_t)row*64 + jb + 16] = p1;
      }
    }
  }

  att_sh[tid] = att1[tid];
  #pragma unroll 1
  for(int p=0;p<2;p++){
    __syncthreads();
    if(wn == p){
      #pragma unroll
      for(int mt=0;mt<2;mt++)
        #pragma unroll
        for(int nt=0;nt<4;nt++)
          #pragma unroll
          for(int v=0;v<4;v++)
            fx[(wm*32 + mt*16 + lq*4 + v)*68 + nt*16 + lm] = acc[mt][nt][v];
    }
    __syncthreads();
    if(tid < 128){
      int rloc = tid >> 1, hh = tid & 1;
      int head = p*2 + hh;
      float a = 0.f, b = 0.f;
      #pragma unroll
      for(int c4=0;c4<8;c4++){
        float4 xv  = *((const float4*)&fx[rloc*68 + hh*32 + c4*4]);
        float4 alv = *((const float4*)&att_sh[head*64 + c4*4]);
        float4 arv = *((const float4*)&att_sh[head*64 + 32 + c4*4]);
        a += xv.x*alv.x + xv.y*alv.y + xv.z*alv.z + xv.w*alv.w;
        b += xv.x*arv.x + xv.y*arv.y + xv.z*arv.z + xv.w*arv.w;
      }
      int row = n0 + rloc;
      if(row < N){
        sl[(size_t)row*4 + head] = a;
        sr[(size_t)row*4 + head] = b;
      }
    }
  }
}

// ---------------- layer 1 aggregation: one wave per target node ----------------

__global__ __launch_bounds__(64) void k_agg1(const int* __restrict__ offs, const int* __restrict__ srcs,
    const float* __restrict__ sl, const float* __restrict__ sr, const float* __restrict__ dinv,
    const unsigned* __restrict__ xtb, const float* __restrict__ b1, float* __restrict__ h, int N){
  __shared__ int   s_sh[64];
  __shared__ float w_sh[64*4];
  int n = blockIdx.x;
  if(n >= N) return;
  int lane = threadIdx.x;
  int beg = offs[n], end = offs[n+1];
  int deg = end - beg;
  float4 sln = *((const float4*)(sl + (size_t)n*4));
  int h0 = lane >> 5;
  float den0=0.f,den1=0.f,den2=0.f,den3=0.f;
  float acc0=0.f, acc1=0.f;

  if(deg <= 64){
    int j = beg + lane;
    int s = 0; float wd = 0.f;
    float a0=-1e30f, a1=-1e30f, a2=-1e30f, a3=-1e30f;
    if(j < end){
      s = srcs[j];
      float4 a = *((const float4*)(sr + (size_t)s*4));
      a0 = lrelu(sln.x + a.x);
      a1 = lrelu(sln.y + a.y);
      a2 = lrelu(sln.z + a.z);
      a3 = lrelu(sln.w + a.w);
      wd = dinv[s];
    }
    float m0=a0,m1=a1,m2=a2,m3=a3;
    #pragma unroll
    for(int o=32;o>0;o>>=1){
      m0 = fmaxf(m0, __shfl_xor(m0,o));
      m1 = fmaxf(m1, __shfl_xor(m1,o));
      m2 = fmaxf(m2, __shfl_xor(m2,o));
      m3 = fmaxf(m3, __shfl_xor(m3,o));
    }
    den0 = __expf(a0 - m0);
    den1 = __expf(a1 - m1);
    den2 = __expf(a2 - m2);
    den3 = __expf(a3 - m3);
    s_sh[lane] = s;
    w_sh[lane*4+0] = wd*den0;
    w_sh[lane*4+1] = wd*den1;
    w_sh[lane*4+2] = wd*den2;
    w_sh[lane*4+3] = wd*den3;
    __syncthreads();
    int k = 0;
    for(; k+8<=deg; k+=8){
      int sk[8];
      #pragma unroll
      for(int u=0;u<8;u++) sk[u] = __builtin_amdgcn_readfirstlane(s_sh[k+u]);
      unsigned pv[8];
      #pragma unroll
      for(int u=0;u<8;u++) pv[u] = xtb[(size_t)sk[u]*64 + lane];
      #pragma unroll
      for(int u=0;u<8;u++){
        float2 wv = *((const float2*)&w_sh[(k+u)*4 + h0*2]);
        acc0 += wv.x * __uint_as_float(pv[u] << 16);
        acc1 += wv.y * __uint_as_float(pv[u] & 0xffff0000u);
      }
    }
    for(; k<deg; k++){
      int sk = __builtin_amdgcn_readfirstlane(s_sh[k]);
      unsigned pvv = xtb[(size_t)sk*64 + lane];
      float2 wv = *((const float2*)&w_sh[k*4 + h0*2]);
      acc0 += wv.x * __uint_as_float(pvv << 16);
      acc1 += wv.y * __uint_as_float(pvv & 0xffff0000u);
    }
  } else {
    float m0=-1e30f,m1=-1e30f,m2=-1e30f,m3=-1e30f;
    for(int j=beg+lane; j<end; j+=64){
      int s = srcs[j];
      float4 a = *((const float4*)(sr + (size_t)s*4));
      m0 = fmaxf(m0, lrelu(sln.x + a.x));
      m1 = fmaxf(m1, lrelu(sln.y + a.y));
      m2 = fmaxf(m2, lrelu(sln.z + a.z));
      m3 = fmaxf(m3, lrelu(sln.w + a.w));
    }
    #pragma unroll
    for(int o=32;o>0;o>>=1){
      m0 = fmaxf(m0, __shfl_xor(m0,o));
      m1 = fmaxf(m1, __shfl_xor(m1,o));
      m2 = fmaxf(m2, __shfl_xor(m2,o));
      m3 = fmaxf(m3, __shfl_xor(m3,o));
    }
    for(int c0=beg; c0<end; c0+=64){
      int cnt = min(64, end-c0);
      int j = c0 + lane;
      float e0=0.f,e1=0.f,e2=0.f,e3=0.f, wd=0.f; int s=0;
      if(j<end){
        s = srcs[j];
        float4 a = *((const float4*)(sr + (size_t)s*4));
        e0 = __expf(lrelu(sln.x + a.x) - m0);
        e1 = __expf(lrelu(sln.y + a.y) - m1);
        e2 = __expf(lrelu(sln.z + a.z) - m2);
        e3 = __expf(lrelu(sln.w + a.w) - m3);
        wd = dinv[s];
      }
      den0+=e0; den1+=e1; den2+=e2; den3+=e3;
      s_sh[lane] = s;
      w_sh[lane*4+0] = wd*e0;
      w_sh[lane*4+1] = wd*e1;
      w_sh[lane*4+2] = wd*e2;
      w_sh[lane*4+3] = wd*e3;
      __syncthreads();
      int k = 0;
      for(; k+8<=cnt; k+=8){
        int sk[8];
        #pragma unroll
        for(int u=0;u<8;u++) sk[u] = __builtin_amdgcn_readfirstlane(s_sh[k+u]);
        unsigned pv[8];
        #pragma unroll
        for(int u=0;u<8;u++) pv[u] = xtb[(size_t)sk[u]*64 + lane];
        #pragma unroll
        for(int u=0;u<8;u++){
          float2 wv = *((const float2*)&w_sh[(k+u)*4 + h0*2]);
          acc0 += wv.x * __uint_as_float(pv[u] << 16);
          acc1 += wv.y * __uint_as_float(pv[u] & 0xffff0000u);
        }
      }
      for(; k<cnt; k++){
        int sk = __builtin_amdgcn_readfirstlane(s_sh[k]);
        unsigned pvv = xtb[(size_t)sk*64 + lane];
        float2 wv = *((const float2*)&w_sh[k*4 + h0*2]);
        acc0 += wv.x * __uint_as_float(pvv << 16);
        acc1 += wv.y * __uint_as_float(pvv & 0xffff0000u);
      }
      __syncthreads();
    }
  }
  #pragma unroll
  for(int o=32;o>0;o>>=1){
    den0 += __shfl_xor(den0,o);
    den1 += __shfl_xor(den1,o);
    den2 += __shfl_xor(den2,o);
    den3 += __shfl_xor(den3,o);
  }
  float din = dinv[n];
  int ch0 = (lane < 32) ? lane : lane + 32;
  int ch1 = ch0 + 32;
  float d0 = (lane < 32) ? den0 : den2;
  float d1 = (lane < 32) ? den1 : den3;
  float o0 = din*acc0/(d0 + 1e-16f) + b1[ch0];
  float o1 = din*acc1/(d1 + 1e-16f) + b1[ch1];
  h[(size_t)n*128 + ch0] = o0 > 0.f ? o0 : 0.f;
  h[(size_t)n*128 + ch1] = o1 > 0.f ? o1 : 0.f;
}

// ---------------- layer 2 GEMM (128->16) + attention scalars ----------------

__global__ __launch_bounds__(256) void k_gemm2(const float* __restrict__ hmat, const float* __restrict__ W2,
    const float* __restrict__ att2, unsigned* __restrict__ xt2b,
    float* __restrict__ sl2, float* __restrict__ sr2, int N){
  __shared__ float hs[16*132];
  __shared__ float ws[16*132];
  __shared__ float xs[16*16];
  int t = threadIdx.x;
  int n0 = blockIdx.x * 16;
  #pragma unroll
  for(int i=0;i<8;i++){
    int idx = t + 256*i;
    int k = idx >> 4, c = idx & 15;
    ws[c*132 + k] = W2[idx];
  }
  #pragma unroll
  for(int i=0;i<2;i++){
    int idx = t + 256*i;
    int r = idx >> 5, k4 = idx & 31;
    int n = n0 + r;
    float4 v = make_float4(0.f,0.f,0.f,0.f);
    if(n < N) v = ((const float4*)hmat)[(size_t)n*32 + k4];
    *((float4*)&hs[r*132 + k4*4]) = v;
  }
  __syncthreads();
  int r = t >> 4, c = t & 15;
  float acc = 0.f;
  for(int k=0;k<128;k+=4){
    float4 hv = *((const float4*)&hs[r*132+k]);
    float4 wv = *((const float4*)&ws[c*132+k]);
    acc += hv.x*wv.x + hv.y*wv.y + hv.z*wv.z + hv.w*wv.w;
  }
  xs[r*16 + c] = acc;
  __syncthreads();
  int n = n0 + r;
  if(c < 8 && n < N){
    unsigned pk = (unsigned)bfr(xs[r*16+c]) | ((unsigned)bfr(xs[r*16+c+8])<<16);
    xt2b[(size_t)n*8 + c] = pk;
  }
  if(t < 16){
    int nn = n0 + t;
    if(nn < N){
      float a = 0.f, b = 0.f;
      #pragma unroll
      for(int cc=0;cc<16;cc++){ float v = xs[t*16+cc]; a += v*att2[cc]; b += v*att2[16+cc]; }
      sl2[nn] = a; sr2[nn] = b;
    }
  }
}

// ---------------- layer 2 aggregation ----------------

__global__ __launch_bounds__(64) void k_agg2(const int* __restrict__ offs, const int* __restrict__ srcs,
    const float* __restrict__ sl2, const float* __restrict__ sr2, const float* __restrict__ dinv,
    const unsigned* __restrict__ xt2b, const float* __restrict__ b2, float* __restrict__ out, int N){
  __shared__ int   s_sh[64];
  __shared__ float w_sh[64];
  int n = blockIdx.x;
  if(n >= N) return;
  int lane = threadIdx.x;
  int beg = offs[n], end = offs[n+1];
  int deg = end - beg;
  float sln = sl2[n];
  float den = 0.f, acc0 = 0.f, acc1 = 0.f;
  int grp = lane >> 3, ch = lane & 7;

  if(deg <= 64){
    int j = beg + lane;
    int s = 0; float wd = 0.f; float a = -1e30f;
    if(j < end){
      s = srcs[j];
      a = lrelu(sln + sr2[s]);
      wd = dinv[s];
    }
    float m = a;
    #pragma unroll
    for(int o=32;o>0;o>>=1) m = fmaxf(m, __shfl_xor(m,o));
    float e = __expf(a - m);
    den = e;
    s_sh[lane] = s;
    w_sh[lane] = wd*e;
    __syncthreads();
    for(int k=0;k<deg;k+=8){
      int kk = k + grp;
      if(kk < deg){
        int sk = s_sh[kk];
        float wk = w_sh[kk];
        unsigned pv = xt2b[(size_t)sk*8 + ch];
        acc0 += wk * __uint_as_float(pv << 16);
        acc1 += wk * __uint_as_float(pv & 0xffff0000u);
      }
    }
  } else {
    float m = -1e30f;
    for(int j=beg+lane; j<end; j+=64)
      m = fmaxf(m, lrelu(sln + sr2[srcs[j]]));
    #pragma unroll
    for(int o=32;o>0;o>>=1) m = fmaxf(m, __shfl_xor(m,o));
    for(int c0=beg; c0<end; c0+=64){
      int cnt = min(64, end-c0);
      int j = c0 + lane;
      float e=0.f, wd=0.f; int s=0;
      if(j<end){
        s = srcs[j];
        e = __expf(lrelu(sln + sr2[s]) - m);
        wd = dinv[s];
      }
      den += e;
      s_sh[lane] = s;
      w_sh[lane] = wd*e;
      __syncthreads();
      for(int k=0;k<cnt;k+=8){
        int kk = k + grp;
        if(kk < cnt){
          int sk = s_sh[kk];
          float wk = w_sh[kk];
          unsigned pv = xt2b[(size_t)sk*8 + ch];
          acc0 += wk * __uint_as_float(pv << 16);
          acc1 += wk * __uint_as_float(pv & 0xffff0000u);
        }
      }
      __syncthreads();
    }
  }
  #pragma unroll
  for(int o=32;o>0;o>>=1) den += __shfl_xor(den,o);
  acc0 += __shfl_xor(acc0,8);  acc0 += __shfl_xor(acc0,16);  acc0 += __shfl_xor(acc0,32);
  acc1 += __shfl_xor(acc1,8);  acc1 += __shfl_xor(acc1,16);  acc1 += __shfl_xor(acc1,32);
  if(lane < 8){
    float din = dinv[n];
    out[(size_t)n*16 + lane]     = din*acc0/(den + 1e-16f) + b2[lane];
    out[(size_t)n*16 + lane + 8] = din*acc1/(den + 1e-16f) + b2[lane+8];
  }
}

// ---------------- host launch ----------------

extern "C" void kernel_launch(void* const* d_in, const int* in_sizes, int n_in,
                              void* d_out, int out_size, void* d_ws, size_t ws_size,
                              hipStream_t stream){
  const float* x    = (const float*)d_in[0];
  const int*   ei   = (const int*)d_in[1];
  const float* W1   = (const float*)d_in[2];
  const float* att1 = (const float*)d_in[3];
  const float* b1   = (const float*)d_in[4];
  const float* W2   = (const float*)d_in[5];
  const float* att2 = (const float*)d_in[6];
  const float* b2   = (const float*)d_in[7];
  int N = in_sizes[0] / 256;
  int E = in_sizes[1] / 2;
  const int* rows = ei;
  const int* cols = ei + E;
  float* out = (float*)d_out;

  int ET    = E + N;
  int Npad  = (N + 63) & ~63;
  int NSEG2 = (N + SEGN - 1) / SEGN;   // requires N < 131072 (17-bit row pack)

  char* p = (char*)d_ws;
  auto alloc = [&](size_t bytes)->void*{ void* q = p; p += (bytes + 255) & ~(size_t)255; return q; };
  int*      cnt     = (int*)alloc((size_t)N*4);
  int*      deg     = (int*)alloc((size_t)N*4);
  int*      offs    = (int*)alloc((size_t)(N+1)*4);
  int*      bsum    = (int*)alloc(256*4);
  int*      ebase   = (int*)alloc(257*4);
  int*      bcur    = (int*)alloc(256*4);
  int*      csr     = (int*)alloc((size_t)ET*4);
  float*    dinv    = (float*)alloc((size_t)N*4);
  unsigned* xtb     = (unsigned*)alloc((size_t)N*64*4);
  float*    sl1     = (float*)alloc((size_t)N*16);
  float*    sr1     = (float*)alloc((size_t)N*16);
  float*    hbuf    = (float*)alloc((size_t)Npad*512);   // also hosts xlo
  unsigned* xt2b    = (unsigned*)alloc((size_t)N*8*4);
  float*    sl2     = (float*)alloc((size_t)N*4);
  float*    sr2     = (float*)alloc((size_t)N*4);
  short*    Whi     = (short*)alloc((size_t)128*256*2);
  short*    Wlo     = (short*)alloc((size_t)128*256*2);
  unsigned short* xhi = (unsigned short*)alloc((size_t)Npad*256*2);

  // transient aliases (consumed before their hosts are written):
  unsigned*       ebuf = (unsigned*)xtb;         // consumed by k_sortfill before k_gemm1 writes xtb
  unsigned short* xlo  = (unsigned short*)hbuf;  // consumed by k_gemm1 before k_agg1 writes hbuf

  int gN = (N + TPB - 1) / TPB;
  int gE = (E + 255) / 256;
  int NB = (N + 1023) / 1024;

  k_init<<<gN, TPB, 0, stream>>>(deg, cnt, N);
  k_deg<<<gE, 256, 0, stream>>>(rows, cols, deg, cnt, E);
  k_scan_block<<<NB, 256, 0, stream>>>(cnt, bsum, N);
  k_scan_bsum<<<1, 256, 0, stream>>>(bsum, NB);
  k_scan_write<<<NB, 256, 0, stream>>>(cnt, bsum, deg, offs, dinv, N);
  k_ebase<<<1, 256, 0, stream>>>(offs, ebase, bcur, N, NSEG2);
  k_bucket<<<(E + CHB - 1)/CHB, 256, 0, stream>>>(rows, cols, bcur, ebuf, E, NSEG2);
  k_sortfill<<<NSEG2, 256, 0, stream>>>(offs, ebase, ebuf, csr, N);

  k_prepW<<<128, 256, 0, stream>>>(W1, Whi, Wlo);
  long long Ntot = (long long)N*256, NtotPad = (long long)Npad*256;
  k_prepX<<<(int)((NtotPad + 2047)/2048), 256, 0, stream>>>(x, xhi, xlo, Ntot, NtotPad);
  k_gemm1<<<(N + 63)/64, 256, 0, stream>>>(xhi, xlo, Whi, Wlo, att1, xtb, sl1, sr1, N);
  k_agg1<<<N, 64, 0, stream>>>(offs, csr, sl1, sr1, dinv, xtb, b1, hbuf, N);

  k_gemm2<<<(N + 15)/16, 256, 0, stream>>>(hbuf, W2, att2, xt2b, sl2, sr2, N);
  k_agg2<<<N, 64, 0, stream>>>(offs, csr, sl2, sr2, dinv, xt2b, b2, out, N);
}

// Round 7
// 447.437 us; speedup vs baseline: 1.3789x; 1.1937x over previous
//
#include <hip/hip_runtime.h>
#include <math.h>

#define TPB 256
#define SEGN 512            // nodes per sort segment (col>>9)
#define SCAP 14336          // LDS sort buffer capacity (56KB)
#define CHB 8192            // edges per bucket block
#define CAPC 12288          // fixed bucket capacity per segment (mean 8163, +45 sigma)

__device__ __forceinline__ float lrelu(float a){ return a >= 0.f ? a : 0.2f*a; }

typedef __attribute__((ext_vector_type(8))) short bf16x8;
typedef __attribute__((ext_vector_type(4))) float f32x4;

// round-to-nearest-even fp32 -> bf16 bits
__device__ __forceinline__ unsigned short bfr(float f){
  unsigned u = __float_as_uint(f);
  return (unsigned short)((u + 0x7fffu + ((u >> 16) & 1u)) >> 16);
}

// async global->LDS, 16B per lane; dest must be wave-uniform base (lane*16 implicit)
__device__ __forceinline__ void gl_lds16(const void* g, void* l){
  __builtin_amdgcn_global_load_lds(
      (const __attribute__((address_space(1))) void*)g,
      (__attribute__((address_space(3))) void*)l, 16, 0, 0);
}

// ---------------- graph build ----------------
// Round-5/6 lessons: (a) scattered 4B global writes cost a 64B line each;
// (b) per-edge GLOBAL atomics cost ~32B memory-side traffic each (per-XCD L2s
// are non-coherent; k_deg: 3.2M atomics -> 99.8MB WRITE, 124us). So: NO
// per-edge global atomics, NO per-edge scattered writes. Everything goes
// through LDS-ranked buckets with block-level reservations (~150K atomics),
// fixed-capacity regions (no dependence on counts), then per-segment LDS
// histogram / counting-sort with coalesced streaming output.

__global__ void k_binit(int* __restrict__ bcurC, int* __restrict__ bcurR, int NSEG2){
  int t = threadIdx.x;
  if(t < NSEG2){ bcurC[t] = t*CAPC; bcurR[t] = t*CAPC; }
}

// two-phase bucket scatter: LDS-rank per segment + one global reservation per
// seg per round -> contiguous runs, line-granular writes.
__global__ __launch_bounds__(256) void k_bucket2(const int* __restrict__ rows, const int* __restrict__ cols,
    int* __restrict__ bcurC, int* __restrict__ bcurR,
    unsigned* __restrict__ ebufC, unsigned short* __restrict__ ebufR, int E, int NSEG2){
  __shared__ int lhist[256];
  __shared__ int lbase[256];
  int tid = threadIdx.x;
  int e0 = blockIdx.x * CHB;
  // phase C: col-keyed, payload = (col&511)<<17 | row   (requires N < 131072)
  #pragma unroll 1
  for(int r=0; r<4; r++){
    lhist[tid] = 0;
    __syncthreads();
    int eb = e0 + r*2048;
    unsigned pk[8]; int sg[8], rk[8];
    #pragma unroll
    for(int i=0;i<8;i++){
      int e = eb + i*256 + tid;
      sg[i] = -1;
      if(e < E){
        int cc = cols[e], rr = rows[e];
        sg[i] = cc >> 9;
        pk[i] = ((unsigned)(cc & (SEGN-1)) << 17) | (unsigned)rr;
        rk[i] = atomicAdd(&lhist[sg[i]], 1);
      }
    }
    __syncthreads();
    if(tid < NSEG2){
      int c = lhist[tid];
      lbase[tid] = c ? atomicAdd(&bcurC[tid], c) : 0;
    }
    __syncthreads();
    #pragma unroll
    for(int i=0;i<8;i++)
      if(sg[i] >= 0){
        int p = lbase[sg[i]] + rk[i];
        if(p < (sg[i]+1)*CAPC) ebufC[p] = pk[i];   // overflow guard (never hits)
      }
    __syncthreads();
  }
  // phase R: row-keyed, payload = row&511 (for deg counting only)
  #pragma unroll 1
  for(int r=0; r<4; r++){
    lhist[tid] = 0;
    __syncthreads();
    int eb = e0 + r*2048;
    int sg[8], rk[8]; unsigned short pv[8];
    #pragma unroll
    for(int i=0;i<8;i++){
      int e = eb + i*256 + tid;
      sg[i] = -1;
      if(e < E){
        int rr = rows[e];
        sg[i] = rr >> 9;
        pv[i] = (unsigned short)(rr & (SEGN-1));
        rk[i] = atomicAdd(&lhist[sg[i]], 1);
      }
    }
    __syncthreads();
    if(tid < NSEG2){
      int c = lhist[tid];
      lbase[tid] = c ? atomicAdd(&bcurR[tid], c) : 0;
    }
    __syncthreads();
    #pragma unroll
    for(int i=0;i<8;i++)
      if(sg[i] >= 0){
        int p = lbase[sg[i]] + rk[i];
        if(p < (sg[i]+1)*CAPC) ebufR[p] = pv[i];
      }
    __syncthreads();
  }
}

// per-segment LDS histograms of both buckets -> cnt (+1 self-loop) and dinv
__global__ __launch_bounds__(256) void k_cntseg(const int* __restrict__ bcurC, const int* __restrict__ bcurR,
    const unsigned* __restrict__ ebufC, const unsigned short* __restrict__ ebufR,
    int* __restrict__ cnt, float* __restrict__ dinv, int N){
  __shared__ int hc[SEGN];
  __shared__ int hr[SEGN];
  int s = blockIdx.x, tid = threadIdx.x;
  int lo = s*SEGN;
  int nn = min(SEGN, N - lo);
  for(int i=tid; i<SEGN; i+=256){ hc[i] = 0; hr[i] = 0; }
  __syncthreads();
  int cb = s*CAPC;
  int cc = min(bcurC[s] - cb, CAPC);
  int rc = min(bcurR[s] - cb, CAPC);
  for(int j=tid; j<cc; j+=256) atomicAdd(&hc[ebufC[cb + j] >> 17], 1);
  for(int j=tid; j<rc; j+=256) atomicAdd(&hr[ebufR[cb + j]], 1);
  __syncthreads();
  for(int i=tid; i<nn; i+=256){
    cnt[lo+i]  = hc[i] + 1;                              // + self-loop
    dinv[lo+i] = 1.f / sqrtf((float)(hr[i] + 1));
  }
}

// exclusive scan of cnt[0..N) into offs[0..N], 1024 elements per block
__global__ void k_scan_block(const int* __restrict__ cnt, int* __restrict__ bsum, int N){
  __shared__ int sdata[256];
  int base = blockIdx.x*1024 + threadIdx.x*4;
  int s = 0;
  #pragma unroll
  for(int i=0;i<4;i++){ int idx = base+i; if(idx < N) s += cnt[idx]; }
  sdata[threadIdx.x] = s; __syncthreads();
  for(int off=128; off>0; off>>=1){
    if(threadIdx.x < off) sdata[threadIdx.x] += sdata[threadIdx.x+off];
    __syncthreads();
  }
  if(threadIdx.x == 0) bsum[blockIdx.x] = sdata[0];
}

__global__ void k_scan_bsum(int* bsum, int NB){
  __shared__ int s[256];
  int t = threadIdx.x;
  int v = (t < NB) ? bsum[t] : 0;
  s[t] = v; __syncthreads();
  for(int off=1; off<256; off<<=1){
    int add = (t >= off) ? s[t-off] : 0;
    __syncthreads();
    s[t] += add;
    __syncthreads();
  }
  if(t < NB) bsum[t] = s[t] - v;   // exclusive
}

__global__ void k_scan_write(const int* __restrict__ cnt, const int* __restrict__ bsum,
                             int* __restrict__ offs, int N){
  __shared__ int sdata[256];
  int t = threadIdx.x;
  int base = blockIdx.x*1024 + t*4;
  int v[4]; int s = 0;
  #pragma unroll
  for(int i=0;i<4;i++){ int idx = base+i; v[i] = (idx < N) ? cnt[idx] : 0; s += v[i]; }
  sdata[t] = s; __syncthreads();
  int mine = s;
  for(int off=1; off<256; off<<=1){
    int add = (t >= off) ? sdata[t-off] : 0;
    __syncthreads();
    sdata[t] += add;
    __syncthreads();
  }
  int run = sdata[t] - mine + bsum[blockIdx.x];
  #pragma unroll
  for(int i=0;i<4;i++){
    int idx = base+i;
    if(idx < N){
      offs[idx] = run;
      run += v[i];
      if(idx == N-1) offs[N] = run;
    }
  }
}

// counting-sort fill: assemble segment's csr slice in LDS, stream out coalesced.
__global__ __launch_bounds__(256) void k_sortfill(const int* __restrict__ offs,
    const int* __restrict__ bcurC, const unsigned* __restrict__ ebuf,
    int* __restrict__ csr, int N){
  __shared__ int lcur[SEGN];
  __shared__ int lbuf[SCAP];
  int s = blockIdx.x, tid = threadIdx.x;
  int lo = s*SEGN;
  int nn = min(SEGN, N - lo);
  int base = offs[lo];
  int total = offs[lo+nn] - base;
  int eb = s*CAPC;
  int ec = min(bcurC[s] - eb, CAPC);
  if(total <= SCAP){
    for(int li=tid; li<nn; li+=256){
      int o = offs[lo+li] - base;
      lbuf[o]  = lo + li;      // self-loop at slot 0 of each node
      lcur[li] = o + 1;
    }
    __syncthreads();
    for(int j=tid; j<ec; j+=256){
      unsigned pk = ebuf[eb + j];
      int li  = pk >> 17;
      int row = pk & 0x1FFFF;
      int p = atomicAdd(&lcur[li], 1);   // LDS atomic
      lbuf[p] = row;
    }
    __syncthreads();
    for(int j=tid; j<total; j+=256) csr[base + j] = lbuf[j];   // full-line streaming
  } else {
    // overflow fallback (statistically never at deg~17): direct scatter
    for(int li=tid; li<nn; li+=256){
      int o = offs[lo+li];
      csr[o] = lo + li;
      lcur[li] = o + 1;
    }
    __syncthreads();
    for(int j=tid; j<ec; j+=256){
      unsigned pk = ebuf[eb + j];
      int li  = pk >> 17;
      int row = pk & 0x1FFFF;
      int p = atomicAdd(&lcur[li], 1);
      csr[p] = row;
    }
  }
}

// ---------------- W1 prep: transpose + bf16 hi/lo split ----------------

__global__ void k_prepW(const float* __restrict__ W, short* __restrict__ Whi,
                        short* __restrict__ Wlo){
  int idx = blockIdx.x*256 + threadIdx.x;   // 32768
  int n = idx >> 8, k = idx & 255;
  float f = W[k*128 + n];
  unsigned short h = bfr(f);
  float hf = __uint_as_float(((unsigned)h) << 16);
  Whi[n*256 + k] = (short)h;
  Wlo[n*256 + k] = (short)bfr(f - hf);
}

// ---------------- x prep: bf16 hi/lo planes ----------------

__global__ __launch_bounds__(256) void k_prepX(const float* __restrict__ x,
    unsigned short* __restrict__ xhi, unsigned short* __restrict__ xlo,
    long long Ntot, long long NtotPad){
  long long i = ((long long)blockIdx.x*256 + threadIdx.x)*8;
  if(i >= NtotPad) return;
  float v[8] = {0.f,0.f,0.f,0.f,0.f,0.f,0.f,0.f};
  if(i < Ntot){
    const float4* x4 = (const float4*)x;
    float4 a = x4[i>>2], b = x4[(i>>2)+1];
    v[0]=a.x; v[1]=a.y; v[2]=a.z; v[3]=a.w;
    v[4]=b.x; v[5]=b.y; v[6]=b.z; v[7]=b.w;
  }
  unsigned hp[4], lp[4];
  #pragma unroll
  for(int j=0;j<4;j++){
    unsigned short h0 = bfr(v[2*j]), h1 = bfr(v[2*j+1]);
    float r0 = v[2*j]   - __uint_as_float(((unsigned)h0)<<16);
    float r1 = v[2*j+1] - __uint_as_float(((unsigned)h1)<<16);
    hp[j] = (unsigned)h0 | ((unsigned)h1<<16);
    lp[j] = (unsigned)bfr(r0) | ((unsigned)bfr(r1)<<16);
  }
  *((uint4*)(xhi + i)) = make_uint4(hp[0],hp[1],hp[2],hp[3]);
  *((uint4*)(xlo + i)) = make_uint4(lp[0],lp[1],lp[2],lp[3]);
}

// ---------------- layer 1 GEMM: pure global_load_lds double-buffered pipeline ----------------

#define BUFB 24576
__global__ __launch_bounds__(256) void k_gemm1(
    const unsigned short* __restrict__ xhi, const unsigned short* __restrict__ xlo,
    const short* __restrict__ Whi, const short* __restrict__ Wlo,
    const float* __restrict__ att1,
    unsigned* __restrict__ xtb, float* __restrict__ sl, float* __restrict__ sr, int N){
  __shared__ __align__(16) char smem[2*BUFB];
  float* fx = (float*)smem;                  // epilogue alias: 64*68 floats
  float* att_sh = (float*)(smem + 17408);    // 256 floats

  int tid = threadIdx.x;
  int n0 = blockIdx.x * 64;
  int w = tid >> 6, l = tid & 63;
  int wm = w & 1, wn = w >> 1;
  int lm = l & 15, lq = l >> 4;

  f32x4 acc[2][4];
  #pragma unroll
  for(int a=0;a<2;a++)
    #pragma unroll
    for(int b=0;b<4;b++) acc[a][b] = (f32x4){0.f,0.f,0.f,0.f};

  int ua = (w<<6) | l;
  int ar = ua >> 2, aq = ua & 3;
  int as_ = aq ^ ((ar >> 1) & 3);
  const unsigned short* gAh = xhi + (size_t)(n0 + ar)*256 + as_*8;
  const unsigned short* gAl = xlo + (size_t)(n0 + ar)*256 + as_*8;
  int ub0 = (w<<6) | l,  ub1 = 256 + ub0;
  int br0 = ub0 >> 2, bs0 = (ub0 & 3) ^ ((br0 >> 1) & 3);
  int br1 = ub1 >> 2, bs1 = (ub1 & 3) ^ ((br1 >> 1) & 3);
  const short* gBh0 = Whi + br0*256 + bs0*8;
  const short* gBh1 = Whi + br1*256 + bs1*8;
  const short* gBl0 = Wlo + br0*256 + bs0*8;
  const short* gBl1 = Wlo + br1*256 + bs1*8;
  int woff = w << 10;

  int offA[2], offB[4];
  #pragma unroll
  for(int mt=0;mt<2;mt++){
    int rr = wm*32 + mt*16 + lm;
    offA[mt] = rr*32 + ((lq ^ ((rr>>1)&3)) << 3);
  }
  #pragma unroll
  for(int nt=0;nt<4;nt++){
    int rr = wn*64 + nt*16 + lm;
    offB[nt] = rr*32 + ((lq ^ ((rr>>1)&3)) << 3);
  }

  {
    char* base = smem;
    gl_lds16(gAh,  base          + woff);
    gl_lds16(gAl,  base + 4096   + woff);
    gl_lds16(gBh0, base + 8192   + woff);
    gl_lds16(gBh1, base + 12288  + woff);
    gl_lds16(gBl0, base + 16384  + woff);
    gl_lds16(gBl1, base + 20480  + woff);
  }
  __syncthreads();

  int cur = 0;
  #pragma unroll 1
  for(int c=0;c<8;c++){
    if(c < 7){
      int kb = (c+1) << 5;
      char* base = smem + (cur^1)*BUFB;
      gl_lds16(gAh  + kb, base          + woff);
      gl_lds16(gAl  + kb, base + 4096   + woff);
      gl_lds16(gBh0 + kb, base + 8192   + woff);
      gl_lds16(gBh1 + kb, base + 12288  + woff);
      gl_lds16(gBl0 + kb, base + 16384  + woff);
      gl_lds16(gBl1 + kb, base + 20480  + woff);
    }
    short* Ah = (short*)(smem + cur*BUFB);
    short* Al = (short*)(smem + cur*BUFB + 4096);
    short* Bh = (short*)(smem + cur*BUFB + 8192);
    short* Bl = (short*)(smem + cur*BUFB + 16384);
    bf16x8 ah[2], al2[2];
    #pragma unroll
    for(int mt=0;mt<2;mt++){
      ah[mt]  = *((bf16x8*)&Ah[offA[mt]]);
      al2[mt] = *((bf16x8*)&Al[offA[mt]]);
    }
    #pragma unroll
    for(int nt=0;nt<4;nt++){
      bf16x8 bh = *((bf16x8*)&Bh[offB[nt]]);
      bf16x8 bl = *((bf16x8*)&Bl[offB[nt]]);
      #pragma unroll
      for(int mt=0;mt<2;mt++){
        acc[mt][nt] = __builtin_amdgcn_mfma_f32_16x16x32_bf16(ah[mt],  bh, acc[mt][nt], 0,0,0);
        acc[mt][nt] = __builtin_amdgcn_mfma_f32_16x16x32_bf16(ah[mt],  bl, acc[mt][nt], 0,0,0);
        acc[mt][nt] = __builtin_amdgcn_mfma_f32_16x16x32_bf16(al2[mt], bh, acc[mt][nt], 0,0,0);
      }
    }
    __syncthreads();
    cur ^= 1;
  }

  #pragma unroll
  for(int mt=0;mt<2;mt++){
    #pragma unroll
    for(int v=0;v<4;v++){
      int row = n0 + wm*32 + mt*16 + lq*4 + v;
      if(row < N){
        unsigned p0 = (unsigned)bfr(acc[mt][0][v]) | ((unsigned)bfr(acc[mt][2][v])<<16);
        unsigned p1 = (unsigned)bfr(acc[mt][1][v]) | ((unsigned)bfr(acc[mt][3][v])<<16);
        int jb = wn*32 + lm;
        xtb[(size_t)row*64 + jb]      = p0;
        xtb[(size_t)row*64 + jb + 16] = p1;
      }
    }
  }

  att_sh[tid] = att1[tid];
  #pragma unroll 1
  for(int p=0;p<2;p++){
    __syncthreads();
    if(wn == p){
      #pragma unroll
      for(int mt=0;mt<2;mt++)
        #pragma unroll
        for(int nt=0;nt<4;nt++)
          #pragma unroll
          for(int v=0;v<4;v++)
            fx[(wm*32 + mt*16 + lq*4 + v)*68 + nt*16 + lm] = acc[mt][nt][v];
    }
    __syncthreads();
    if(tid < 128){
      int rloc = tid >> 1, hh = tid & 1;
      int head = p*2 + hh;
      float a = 0.f, b = 0.f;
      #pragma unroll
      for(int c4=0;c4<8;c4++){
        float4 xv  = *((const float4*)&fx[rloc*68 + hh*32 + c4*4]);
        float4 alv = *((const float4*)&att_sh[head*64 + c4*4]);
        float4 arv = *((const float4*)&att_sh[head*64 + 32 + c4*4]);
        a += xv.x*alv.x + xv.y*alv.y + xv.z*alv.z + xv.w*alv.w;
        b += xv.x*arv.x + xv.y*arv.y + xv.z*arv.z + xv.w*arv.w;
      }
      int row = n0 + rloc;
      if(row < N){
        sl[(size_t)row*4 + head] = a;
        sr[(size_t)row*4 + head] = b;
      }
    }
  }
}

// ---------------- layer 1 aggregation: one wave per target node ----------------

__global__ __launch_bounds__(64) void k_agg1(const int* __restrict__ offs, const int* __restrict__ srcs,
    const float* __restrict__ sl, const float* __restrict__ sr, const float* __restrict__ dinv,
    const unsigned* __restrict__ xtb, const float* __restrict__ b1, float* __restrict__ h, int N){
  __shared__ int   s_sh[64];
  __shared__ float w_sh[64*4];
  int n = blockIdx.x;
  if(n >= N) return;
  int lane = threadIdx.x;
  int beg = offs[n], end = offs[n+1];
  int deg = end - beg;
  float4 sln = *((const float4*)(sl + (size_t)n*4));
  int h0 = lane >> 5;
  float den0=0.f,den1=0.f,den2=0.f,den3=0.f;
  float acc0=0.f, acc1=0.f;

  if(deg <= 64){
    int j = beg + lane;
    int s = 0; float wd = 0.f;
    float a0=-1e30f, a1=-1e30f, a2=-1e30f, a3=-1e30f;
    if(j < end){
      s = srcs[j];
      float4 a = *((const float4*)(sr + (size_t)s*4));
      a0 = lrelu(sln.x + a.x);
      a1 = lrelu(sln.y + a.y);
      a2 = lrelu(sln.z + a.z);
      a3 = lrelu(sln.w + a.w);
      wd = dinv[s];
    }
    float m0=a0,m1=a1,m2=a2,m3=a3;
    #pragma unroll
    for(int o=32;o>0;o>>=1){
      m0 = fmaxf(m0, __shfl_xor(m0,o));
      m1 = fmaxf(m1, __shfl_xor(m1,o));
      m2 = fmaxf(m2, __shfl_xor(m2,o));
      m3 = fmaxf(m3, __shfl_xor(m3,o));
    }
    den0 = __expf(a0 - m0);
    den1 = __expf(a1 - m1);
    den2 = __expf(a2 - m2);
    den3 = __expf(a3 - m3);
    s_sh[lane] = s;
    w_sh[lane*4+0] = wd*den0;
    w_sh[lane*4+1] = wd*den1;
    w_sh[lane*4+2] = wd*den2;
    w_sh[lane*4+3] = wd*den3;
    __syncthreads();
    int k = 0;
    for(; k+8<=deg; k+=8){
      int sk[8];
      #pragma unroll
      for(int u=0;u<8;u++) sk[u] = __builtin_amdgcn_readfirstlane(s_sh[k+u]);
      unsigned pv[8];
      #pragma unroll
      for(int u=0;u<8;u++) pv[u] = xtb[(size_t)sk[u]*64 + lane];
      #pragma unroll
      for(int u=0;u<8;u++){
        float2 wv = *((const float2*)&w_sh[(k+u)*4 + h0*2]);
        acc0 += wv.x * __uint_as_float(pv[u] << 16);
        acc1 += wv.y * __uint_as_float(pv[u] & 0xffff0000u);
      }
    }
    for(; k<deg; k++){
      int sk = __builtin_amdgcn_readfirstlane(s_sh[k]);
      unsigned pvv = xtb[(size_t)sk*64 + lane];
      float2 wv = *((const float2*)&w_sh[k*4 + h0*2]);
      acc0 += wv.x * __uint_as_float(pvv << 16);
      acc1 += wv.y * __uint_as_float(pvv & 0xffff0000u);
    }
  } else {
    float m0=-1e30f,m1=-1e30f,m2=-1e30f,m3=-1e30f;
    for(int j=beg+lane; j<end; j+=64){
      int s = srcs[j];
      float4 a = *((const float4*)(sr + (size_t)s*4));
      m0 = fmaxf(m0, lrelu(sln.x + a.x));
      m1 = fmaxf(m1, lrelu(sln.y + a.y));
      m2 = fmaxf(m2, lrelu(sln.z + a.z));
      m3 = fmaxf(m3, lrelu(sln.w + a.w));
    }
    #pragma unroll
    for(int o=32;o>0;o>>=1){
      m0 = fmaxf(m0, __shfl_xor(m0,o));
      m1 = fmaxf(m1, __shfl_xor(m1,o));
      m2 = fmaxf(m2, __shfl_xor(m2,o));
      m3 = fmaxf(m3, __shfl_xor(m3,o));
    }
    for(int c0=beg; c0<end; c0+=64){
      int cnt = min(64, end-c0);
      int j = c0 + lane;
      float e0=0.f,e1=0.f,e2=0.f,e3=0.f, wd=0.f; int s=0;
      if(j<end){
        s = srcs[j];
        float4 a = *((const float4*)(sr + (size_t)s*4));
        e0 = __expf(lrelu(sln.x + a.x) - m0);
        e1 = __expf(lrelu(sln.y + a.y) - m1);
        e2 = __expf(lrelu(sln.z + a.z) - m2);
        e3 = __expf(lrelu(sln.w + a.w) - m3);
        wd = dinv[s];
      }
      den0+=e0; den1+=e1; den2+=e2; den3+=e3;
      s_sh[lane] = s;
      w_sh[lane*4+0] = wd*e0;
      w_sh[lane*4+1] = wd*e1;
      w_sh[lane*4+2] = wd*e2;
      w_sh[lane*4+3] = wd*e3;
      __syncthreads();
      int k = 0;
      for(; k+8<=cnt; k+=8){
        int sk[8];
        #pragma unroll
        for(int u=0;u<8;u++) sk[u] = __builtin_amdgcn_readfirstlane(s_sh[k+u]);
        unsigned pv[8];
        #pragma unroll
        for(int u=0;u<8;u++) pv[u] = xtb[(size_t)sk[u]*64 + lane];
        #pragma unroll
        for(int u=0;u<8;u++){
          float2 wv = *((const float2*)&w_sh[(k+u)*4 + h0*2]);
          acc0 += wv.x * __uint_as_float(pv[u] << 16);
          acc1 += wv.y * __uint_as_float(pv[u] & 0xffff0000u);
        }
      }
      for(; k<cnt; k++){
        int sk = __builtin_amdgcn_readfirstlane(s_sh[k]);
        unsigned pvv = xtb[(size_t)sk*64 + lane];
        float2 wv = *((const float2*)&w_sh[k*4 + h0*2]);
        acc0 += wv.x * __uint_as_float(pvv << 16);
        acc1 += wv.y * __uint_as_float(pvv & 0xffff0000u);
      }
      __syncthreads();
    }
  }
  #pragma unroll
  for(int o=32;o>0;o>>=1){
    den0 += __shfl_xor(den0,o);
    den1 += __shfl_xor(den1,o);
    den2 += __shfl_xor(den2,o);
    den3 += __shfl_xor(den3,o);
  }
  float din = dinv[n];
  int ch0 = (lane < 32) ? lane : lane + 32;
  int ch1 = ch0 + 32;
  float d0 = (lane < 32) ? den0 : den2;
  float d1 = (lane < 32) ? den1 : den3;
  float o0 = din*acc0/(d0 + 1e-16f) + b1[ch0];
  float o1 = din*acc1/(d1 + 1e-16f) + b1[ch1];
  h[(size_t)n*128 + ch0] = o0 > 0.f ? o0 : 0.f;
  h[(size_t)n*128 + ch1] = o1 > 0.f ? o1 : 0.f;
}

// ---------------- layer 2 GEMM (128->16) + attention scalars ----------------

__global__ __launch_bounds__(256) void k_gemm2(const float* __restrict__ hmat, const float* __restrict__ W2,
    const float* __restrict__ att2, unsigned* __restrict__ xt2b,
    float* __restrict__ sl2, float* __restrict__ sr2, int N){
  __shared__ float hs[16*132];
  __shared__ float ws[16*132];
  __shared__ float xs[16*16];
  int t = threadIdx.x;
  int n0 = blockIdx.x * 16;
  #pragma unroll
  for(int i=0;i<8;i++){
    int idx = t + 256*i;
    int k = idx >> 4, c = idx & 15;
    ws[c*132 + k] = W2[idx];
  }
  #pragma unroll
  for(int i=0;i<2;i++){
    int idx = t + 256*i;
    int r = idx >> 5, k4 = idx & 31;
    int n = n0 + r;
    float4 v = make_float4(0.f,0.f,0.f,0.f);
    if(n < N) v = ((const float4*)hmat)[(size_t)n*32 + k4];
    *((float4*)&hs[r*132 + k4*4]) = v;
  }
  __syncthreads();
  int r = t >> 4, c = t & 15;
  float acc = 0.f;
  for(int k=0;k<128;k+=4){
    float4 hv = *((const float4*)&hs[r*132+k]);
    float4 wv = *((const float4*)&ws[c*132+k]);
    acc += hv.x*wv.x + hv.y*wv.y + hv.z*wv.z + hv.w*wv.w;
  }
  xs[r*16 + c] = acc;
  __syncthreads();
  int n = n0 + r;
  if(c < 8 && n < N){
    unsigned pk = (unsigned)bfr(xs[r*16+c]) | ((unsigned)bfr(xs[r*16+c+8])<<16);
    xt2b[(size_t)n*8 + c] = pk;
  }
  if(t < 16){
    int nn = n0 + t;
    if(nn < N){
      float a = 0.f, b = 0.f;
      #pragma unroll
      for(int cc=0;cc<16;cc++){ float v = xs[t*16+cc]; a += v*att2[cc]; b += v*att2[16+cc]; }
      sl2[nn] = a; sr2[nn] = b;
    }
  }
}

// ---------------- layer 2 aggregation ----------------

__global__ __launch_bounds__(64) void k_agg2(const int* __restrict__ offs, const int* __restrict__ srcs,
    const float* __restrict__ sl2, const float* __restrict__ sr2, const float* __restrict__ dinv,
    const unsigned* __restrict__ xt2b, const float* __restrict__ b2, float* __restrict__ out, int N){
  __shared__ int   s_sh[64];
  __shared__ float w_sh[64];
  int n = blockIdx.x;
  if(n >= N) return;
  int lane = threadIdx.x;
  int beg = offs[n], end = offs[n+1];
  int deg = end - beg;
  float sln = sl2[n];
  float den = 0.f, acc0 = 0.f, acc1 = 0.f;
  int grp = lane >> 3, ch = lane & 7;

  if(deg <= 64){
    int j = beg + lane;
    int s = 0; float wd = 0.f; float a = -1e30f;
    if(j < end){
      s = srcs[j];
      a = lrelu(sln + sr2[s]);
      wd = dinv[s];
    }
    float m = a;
    #pragma unroll
    for(int o=32;o>0;o>>=1) m = fmaxf(m, __shfl_xor(m,o));
    float e = __expf(a - m);
    den = e;
    s_sh[lane] = s;
    w_sh[lane] = wd*e;
    __syncthreads();
    for(int k=0;k<deg;k+=8){
      int kk = k + grp;
      if(kk < deg){
        int sk = s_sh[kk];
        float wk = w_sh[kk];
        unsigned pv = xt2b[(size_t)sk*8 + ch];
        acc0 += wk * __uint_as_float(pv << 16);
        acc1 += wk * __uint_as_float(pv & 0xffff0000u);
      }
    }
  } else {
    float m = -1e30f;
    for(int j=beg+lane; j<end; j+=64)
      m = fmaxf(m, lrelu(sln + sr2[srcs[j]]));
    #pragma unroll
    for(int o=32;o>0;o>>=1) m = fmaxf(m, __shfl_xor(m,o));
    for(int c0=beg; c0<end; c0+=64){
      int cnt = min(64, end-c0);
      int j = c0 + lane;
      float e=0.f, wd=0.f; int s=0;
      if(j<end){
        s = srcs[j];
        e = __expf(lrelu(sln + sr2[s]) - m);
        wd = dinv[s];
      }
      den += e;
      s_sh[lane] = s;
      w_sh[lane] = wd*e;
      __syncthreads();
      for(int k=0;k<cnt;k+=8){
        int kk = k + grp;
        if(kk < cnt){
          int sk = s_sh[kk];
          float wk = w_sh[kk];
          unsigned pv = xt2b[(size_t)sk*8 + ch];
          acc0 += wk * __uint_as_float(pv << 16);
          acc1 += wk * __uint_as_float(pv & 0xffff0000u);
        }
      }
      __syncthreads();
    }
  }
  #pragma unroll
  for(int o=32;o>0;o>>=1) den += __shfl_xor(den,o);
  acc0 += __shfl_xor(acc0,8);  acc0 += __shfl_xor(acc0,16);  acc0 += __shfl_xor(acc0,32);
  acc1 += __shfl_xor(acc1,8);  acc1 += __shfl_xor(acc1,16);  acc1 += __shfl_xor(acc1,32);
  if(lane < 8){
    float din = dinv[n];
    out[(size_t)n*16 + lane]     = din*acc0/(den + 1e-16f) + b2[lane];
    out[(size_t)n*16 + lane + 8] = din*acc1/(den + 1e-16f) + b2[lane+8];
  }
}

// ---------------- host launch ----------------

extern "C" void kernel_launch(void* const* d_in, const int* in_sizes, int n_in,
                              void* d_out, int out_size, void* d_ws, size_t ws_size,
                              hipStream_t stream){
  const float* x    = (const float*)d_in[0];
  const int*   ei   = (const int*)d_in[1];
  const float* W1   = (const float*)d_in[2];
  const float* att1 = (const float*)d_in[3];
  const float* b1   = (const float*)d_in[4];
  const float* W2   = (const float*)d_in[5];
  const float* att2 = (const float*)d_in[6];
  const float* b2   = (const float*)d_in[7];
  int N = in_sizes[0] / 256;
  int E = in_sizes[1] / 2;
  const int* rows = ei;
  const int* cols = ei + E;
  float* out = (float*)d_out;

  int ET    = E + N;
  int Npad  = (N + 63) & ~63;
  int NSEG2 = (N + SEGN - 1) / SEGN;   // requires N < 131072 (17-bit row pack), <=256 segs

  char* p = (char*)d_ws;
  auto alloc = [&](size_t bytes)->void*{ void* q = p; p += (bytes + 255) & ~(size_t)255; return q; };
  int*      cnt     = (int*)alloc((size_t)N*4);
  int*      offs    = (int*)alloc((size_t)(N+1)*4);
  int*      bsum    = (int*)alloc(256*4);
  int*      bcurC   = (int*)alloc(256*4);
  int*      bcurR   = (int*)alloc(256*4);
  int*      csr     = (int*)alloc((size_t)ET*4);
  float*    dinv    = (float*)alloc((size_t)N*4);
  unsigned* xtb     = (unsigned*)alloc((size_t)N*64*4);
  float*    sl1     = (float*)alloc((size_t)N*16);
  float*    sr1     = (float*)alloc((size_t)N*16);
  float*    hbuf    = (float*)alloc((size_t)Npad*512);   // also hosts xlo
  unsigned* xt2b    = (unsigned*)alloc((size_t)N*8*4);
  float*    sl2     = (float*)alloc((size_t)N*4);
  float*    sr2     = (float*)alloc((size_t)N*4);
  short*    Whi     = (short*)alloc((size_t)128*256*2);
  short*    Wlo     = (short*)alloc((size_t)128*256*2);
  unsigned short* xhi = (unsigned short*)alloc((size_t)Npad*256*2);

  // transient aliases (consumed before their hosts are written):
  // ebufC (NSEG2*CAPC*4 = 9.6MB) + ebufR (4.8MB) live inside xtb (25.6MB),
  // both consumed by k_cntseg/k_sortfill before k_gemm1 writes xtb.
  unsigned*       ebufC = (unsigned*)xtb;
  unsigned short* ebufR = (unsigned short*)(ebufC + (size_t)NSEG2*CAPC);
  unsigned short* xlo   = (unsigned short*)hbuf;  // consumed by k_gemm1 before k_agg1 writes hbuf

  int NB = (N + 1023) / 1024;
  int gB = (E + CHB - 1) / CHB;

  k_binit<<<1, 256, 0, stream>>>(bcurC, bcurR, NSEG2);
  k_bucket2<<<gB, 256, 0, stream>>>(rows, cols, bcurC, bcurR, ebufC, ebufR, E, NSEG2);
  k_cntseg<<<NSEG2, 256, 0, stream>>>(bcurC, bcurR, ebufC, ebufR, cnt, dinv, N);
  k_scan_block<<<NB, 256, 0, stream>>>(cnt, bsum, N);
  k_scan_bsum<<<1, 256, 0, stream>>>(bsum, NB);
  k_scan_write<<<NB, 256, 0, stream>>>(cnt, bsum, offs, N);
  k_sortfill<<<NSEG2, 256, 0, stream>>>(offs, bcurC, ebufC, csr, N);

  k_prepW<<<128, 256, 0, stream>>>(W1, Whi, Wlo);
  long long Ntot = (long long)N*256, NtotPad = (long long)Npad*256;
  k_prepX<<<(int)((NtotPad + 2047)/2048), 256, 0, stream>>>(x, xhi, xlo, Ntot, NtotPad);
  k_gemm1<<<(N + 63)/64, 256, 0, stream>>>(xhi, xlo, Whi, Wlo, att1, xtb, sl1, sr1, N);
  k_agg1<<<N, 64, 0, stream>>>(offs, csr, sl1, sr1, dinv, xtb, b1, hbuf, N);

  k_gemm2<<<(N + 15)/16, 256, 0, stream>>>(hbuf, W2, att2, xt2b, sl2, sr2, N);
  k_agg2<<<N, 64, 0, stream>>>(offs, csr, sl2, sr2, dinv, xt2b, b2, out, N);
}

// Round 8
// 414.658 us; speedup vs baseline: 1.4879x; 1.0791x over previous
//
#include <hip/hip_runtime.h>
#include <math.h>

#define TPB 256
#define SEGN 512            // nodes per sort segment (col>>9)
#define SCAP 14336          // LDS sort buffer capacity (56KB)
#define CHB 8192            // edges per bucket block
#define CAPC 12288          // fixed bucket capacity per segment (mean 8163, +45 sigma)

__device__ __forceinline__ float lrelu(float a){ return a >= 0.f ? a : 0.2f*a; }

typedef __attribute__((ext_vector_type(8))) short bf16x8;
typedef __attribute__((ext_vector_type(4))) float f32x4;

// round-to-nearest-even fp32 -> bf16 bits
__device__ __forceinline__ unsigned short bfr(float f){
  unsigned u = __float_as_uint(f);
  return (unsigned short)((u + 0x7fffu + ((u >> 16) & 1u)) >> 16);
}

// async global->LDS, 16B per lane; dest must be wave-uniform base (lane*16 implicit)
__device__ __forceinline__ void gl_lds16(const void* g, void* l){
  __builtin_amdgcn_global_load_lds(
      (const __attribute__((address_space(1))) void*)g,
      (__attribute__((address_space(3))) void*)l, 16, 0, 0);
}

// ---------------- graph build ----------------
// Lessons (rounds 5/6): no per-edge global atomics (~32B memory-side traffic
// each), no scattered 4B global writes (64B line each). LDS-ranked buckets with
// block-level RELATIVE reservations (cursors zeroed by hipMemsetAsync), then
// per-segment LDS histogram / counting-sort with coalesced streaming output.

// two-phase bucket scatter: LDS-rank per segment + one global reservation per
// seg per round -> contiguous runs, line-granular writes.
__global__ __launch_bounds__(256) void k_bucket2(const int* __restrict__ rows, const int* __restrict__ cols,
    int* __restrict__ bcurC, int* __restrict__ bcurR,
    unsigned* __restrict__ ebufC, unsigned short* __restrict__ ebufR, int E, int NSEG2){
  __shared__ int lhist[256];
  __shared__ int lbase[256];
  int tid = threadIdx.x;
  int e0 = blockIdx.x * CHB;
  // phase C: col-keyed, payload = (col&511)<<17 | row   (requires N < 131072)
  #pragma unroll 1
  for(int r=0; r<4; r++){
    lhist[tid] = 0;
    __syncthreads();
    int eb = e0 + r*2048;
    unsigned pk[8]; int sg[8], rk[8];
    #pragma unroll
    for(int i=0;i<8;i++){
      int e = eb + i*256 + tid;
      sg[i] = -1;
      if(e < E){
        int cc = cols[e], rr = rows[e];
        sg[i] = cc >> 9;
        pk[i] = ((unsigned)(cc & (SEGN-1)) << 17) | (unsigned)rr;
        rk[i] = atomicAdd(&lhist[sg[i]], 1);
      }
    }
    __syncthreads();
    if(tid < NSEG2){
      int c = lhist[tid];
      lbase[tid] = c ? atomicAdd(&bcurC[tid], c) : 0;
    }
    __syncthreads();
    #pragma unroll
    for(int i=0;i<8;i++)
      if(sg[i] >= 0){
        int p = lbase[sg[i]] + rk[i];
        if(p < CAPC) ebufC[sg[i]*CAPC + p] = pk[i];   // overflow guard (never hits)
      }
    __syncthreads();
  }
  // phase R: row-keyed, payload = row&511 (for deg counting only)
  #pragma unroll 1
  for(int r=0; r<4; r++){
    lhist[tid] = 0;
    __syncthreads();
    int eb = e0 + r*2048;
    int sg[8], rk[8]; unsigned short pv[8];
    #pragma unroll
    for(int i=0;i<8;i++){
      int e = eb + i*256 + tid;
      sg[i] = -1;
      if(e < E){
        int rr = rows[e];
        sg[i] = rr >> 9;
        pv[i] = (unsigned short)(rr & (SEGN-1));
        rk[i] = atomicAdd(&lhist[sg[i]], 1);
      }
    }
    __syncthreads();
    if(tid < NSEG2){
      int c = lhist[tid];
      lbase[tid] = c ? atomicAdd(&bcurR[tid], c) : 0;
    }
    __syncthreads();
    #pragma unroll
    for(int i=0;i<8;i++)
      if(sg[i] >= 0){
        int p = lbase[sg[i]] + rk[i];
        if(p < CAPC) ebufR[sg[i]*CAPC + p] = pv[i];
      }
    __syncthreads();
  }
}

// per-segment LDS histograms of both buckets -> cnt (+1 self-loop), dinv,
// and the segment's cnt-total (bsum) for the scan (fused former k_scan_block).
__global__ __launch_bounds__(256) void k_cntseg(const int* __restrict__ bcurC, const int* __restrict__ bcurR,
    const unsigned* __restrict__ ebufC, const unsigned short* __restrict__ ebufR,
    int* __restrict__ cnt, float* __restrict__ dinv, int* __restrict__ bsum, int N){
  __shared__ int hc[SEGN];
  __shared__ int hr[SEGN];
  __shared__ int red[256];
  int s = blockIdx.x, tid = threadIdx.x;
  int lo = s*SEGN;
  int nn = min(SEGN, N - lo);
  for(int i=tid; i<SEGN; i+=256){ hc[i] = 0; hr[i] = 0; }
  __syncthreads();
  int cb = s*CAPC;
  int cc = min(bcurC[s], CAPC);
  int rc = min(bcurR[s], CAPC);
  for(int j=tid; j<cc; j+=256) atomicAdd(&hc[ebufC[cb + j] >> 17], 1);
  for(int j=tid; j<rc; j+=256) atomicAdd(&hr[ebufR[cb + j]], 1);
  __syncthreads();
  int tsum = 0;
  for(int i=tid; i<nn; i+=256){
    int c = hc[i] + 1;                                   // + self-loop
    cnt[lo+i]  = c;
    tsum += c;
    dinv[lo+i] = 1.f / sqrtf((float)(hr[i] + 1));
  }
  red[tid] = tsum; __syncthreads();
  for(int off=128; off>0; off>>=1){
    if(tid < off) red[tid] += red[tid+off];
    __syncthreads();
  }
  if(tid == 0) bsum[s] = red[0];
}

__global__ void k_scan_bsum(int* bsum, int NB){
  __shared__ int s[256];
  int t = threadIdx.x;
  int v = (t < NB) ? bsum[t] : 0;
  s[t] = v; __syncthreads();
  for(int off=1; off<256; off<<=1){
    int add = (t >= off) ? s[t-off] : 0;
    __syncthreads();
    s[t] += add;
    __syncthreads();
  }
  if(t < NB) bsum[t] = s[t] - v;   // exclusive
}

// 512 nodes per block (matches segment granularity -> bsum[blockIdx] direct)
__global__ void k_scan_write(const int* __restrict__ cnt, const int* __restrict__ bsum,
                             int* __restrict__ offs, int N){
  __shared__ int sdata[256];
  int t = threadIdx.x;
  int base = blockIdx.x*512 + t*2;
  int v0 = (base   < N) ? cnt[base]   : 0;
  int v1 = (base+1 < N) ? cnt[base+1] : 0;
  int s = v0 + v1;
  sdata[t] = s; __syncthreads();
  int mine = s;
  for(int off=1; off<256; off<<=1){
    int add = (t >= off) ? sdata[t-off] : 0;
    __syncthreads();
    sdata[t] += add;
    __syncthreads();
  }
  int run = sdata[t] - mine + bsum[blockIdx.x];
  if(base < N){
    offs[base] = run; run += v0;
    if(base == N-1) offs[N] = run;
  }
  if(base+1 < N){
    offs[base+1] = run; run += v1;
    if(base+1 == N-1) offs[N] = run;
  }
}

// counting-sort fill: assemble segment's csr slice in LDS, stream out coalesced.
__global__ __launch_bounds__(256) void k_sortfill(const int* __restrict__ offs,
    const int* __restrict__ bcurC, const unsigned* __restrict__ ebuf,
    int* __restrict__ csr, int N){
  __shared__ int lcur[SEGN];
  __shared__ int lbuf[SCAP];
  int s = blockIdx.x, tid = threadIdx.x;
  int lo = s*SEGN;
  int nn = min(SEGN, N - lo);
  int base = offs[lo];
  int total = offs[lo+nn] - base;
  int eb = s*CAPC;
  int ec = min(bcurC[s], CAPC);
  if(total <= SCAP){
    for(int li=tid; li<nn; li+=256){
      int o = offs[lo+li] - base;
      lbuf[o]  = lo + li;      // self-loop at slot 0 of each node
      lcur[li] = o + 1;
    }
    __syncthreads();
    for(int j=tid; j<ec; j+=256){
      unsigned pk = ebuf[eb + j];
      int li  = pk >> 17;
      int row = pk & 0x1FFFF;
      int p = atomicAdd(&lcur[li], 1);   // LDS atomic
      lbuf[p] = row;
    }
    __syncthreads();
    for(int j=tid; j<total; j+=256) csr[base + j] = lbuf[j];   // full-line streaming
  } else {
    // overflow fallback (statistically never at deg~17): direct scatter
    for(int li=tid; li<nn; li+=256){
      int o = offs[lo+li];
      csr[o] = lo + li;
      lcur[li] = o + 1;
    }
    __syncthreads();
    for(int j=tid; j<ec; j+=256){
      unsigned pk = ebuf[eb + j];
      int li  = pk >> 17;
      int row = pk & 0x1FFFF;
      int p = atomicAdd(&lcur[li], 1);
      csr[p] = row;
    }
  }
}

// ---------------- W1 prep: transpose + bf16 hi/lo split ----------------

__global__ void k_prepW(const float* __restrict__ W, short* __restrict__ Whi,
                        short* __restrict__ Wlo){
  int idx = blockIdx.x*256 + threadIdx.x;   // 32768
  int n = idx >> 8, k = idx & 255;
  float f = W[k*128 + n];
  unsigned short h = bfr(f);
  float hf = __uint_as_float(((unsigned)h) << 16);
  Whi[n*256 + k] = (short)h;
  Wlo[n*256 + k] = (short)bfr(f - hf);
}

// ---------------- layer 1 GEMM: f32-A global_load_lds pipeline ----------------
// x is staged RAW f32 (4B/elem == xhi+xlo bytes), hi/lo bf16 split happens at
// fragment-read time in registers -> k_prepX (204MB round-trip, ~33us) deleted.
// A: 64 rows x 128B, 8 slots of 16B, swizzle slot ^= row&7 (2-way conflicts,
// free). Source pre-swizzled with the same involution; LDS dest linear.
// LDS per buffer: A-f32 8K | Bh 8K | Bl 8K = 24KB; x2 buffers = 48KB.

#define BUFB 24576
__global__ __launch_bounds__(256) void k_gemm1(
    const float* __restrict__ x,
    const short* __restrict__ Whi, const short* __restrict__ Wlo,
    const float* __restrict__ att1,
    unsigned* __restrict__ xtb, float* __restrict__ sl, float* __restrict__ sr, int N){
  __shared__ __align__(16) char smem[2*BUFB];
  float* fx = (float*)smem;                  // epilogue alias: 64*68 floats
  float* att_sh = (float*)(smem + 17408);    // 256 floats

  int tid = threadIdx.x;
  int n0 = blockIdx.x * 64;
  int w = tid >> 6, l = tid & 63;
  int wm = w & 1, wn = w >> 1;
  int lm = l & 15, lq = l >> 4;

  f32x4 acc[2][4];
  #pragma unroll
  for(int a=0;a<2;a++)
    #pragma unroll
    for(int b=0;b<4;b++) acc[a][b] = (f32x4){0.f,0.f,0.f,0.f};

  // A staging: 512 units (64 rows x 8 f32-quads), 2 calls; OOB rows clamp to
  // N-1 (valid memory; garbage rows masked by row<N store guards).
  int ua0 = (w<<6) | l, ua1 = 256 + ua0;
  int ar0 = ua0 >> 3, as0 = (ua0 & 7) ^ (ar0 & 7);
  int ar1 = ua1 >> 3, as1 = (ua1 & 7) ^ (ar1 & 7);
  const float* gA0 = x + (size_t)min(n0 + ar0, N-1)*256 + as0*4;
  const float* gA1 = x + (size_t)min(n0 + ar1, N-1)*256 + as1*4;
  // B staging: 512 units (128 rows x 4 slots of 8 shorts)
  int ub0 = (w<<6) | l,  ub1 = 256 + ub0;
  int br0 = ub0 >> 2, bs0 = (ub0 & 3) ^ ((br0 >> 1) & 3);
  int br1 = ub1 >> 2, bs1 = (ub1 & 3) ^ ((br1 >> 1) & 3);
  const short* gBh0 = Whi + br0*256 + bs0*8;
  const short* gBh1 = Whi + br1*256 + bs1*8;
  const short* gBl0 = Wlo + br0*256 + bs0*8;
  const short* gBl1 = Wlo + br1*256 + bs1*8;
  int woff = w << 10;

  // fragment read offsets. A in floats (row stride 32 floats = 128B):
  int offAf[2][2], offB[4];
  #pragma unroll
  for(int mt=0;mt<2;mt++){
    int rr = wm*32 + mt*16 + lm;
    offAf[mt][0] = rr*32 + (((2*lq+0) ^ (rr&7)) << 2);
    offAf[mt][1] = rr*32 + (((2*lq+1) ^ (rr&7)) << 2);
  }
  #pragma unroll
  for(int nt=0;nt<4;nt++){
    int rr = wn*64 + nt*16 + lm;
    offB[nt] = rr*32 + ((lq ^ ((rr>>1)&3)) << 3);
  }

  // prologue: stage chunk 0 into buf 0
  {
    char* base = smem;
    gl_lds16(gA0,  base          + woff);
    gl_lds16(gA1,  base + 4096   + woff);
    gl_lds16(gBh0, base + 8192   + woff);
    gl_lds16(gBh1, base + 12288  + woff);
    gl_lds16(gBl0, base + 16384  + woff);
    gl_lds16(gBl1, base + 20480  + woff);
  }
  __syncthreads();

  int cur = 0;
  #pragma unroll 1
  for(int c=0;c<8;c++){
    if(c < 7){
      int kf = (c+1) << 5;   // +32 floats / +32 shorts per chunk
      char* base = smem + (cur^1)*BUFB;
      gl_lds16(gA0  + kf, base          + woff);
      gl_lds16(gA1  + kf, base + 4096   + woff);
      gl_lds16(gBh0 + kf, base + 8192   + woff);
      gl_lds16(gBh1 + kf, base + 12288  + woff);
      gl_lds16(gBl0 + kf, base + 16384  + woff);
      gl_lds16(gBl1 + kf, base + 20480  + woff);
    }
    float* Axf = (float*)(smem + cur*BUFB);
    short* Bh  = (short*)(smem + cur*BUFB + 8192);
    short* Bl  = (short*)(smem + cur*BUFB + 16384);
    bf16x8 ah[2], al2[2];
    #pragma unroll
    for(int mt=0;mt<2;mt++){
      float4 f0 = *((const float4*)&Axf[offAf[mt][0]]);
      float4 f1 = *((const float4*)&Axf[offAf[mt][1]]);
      float fa[8] = {f0.x,f0.y,f0.z,f0.w,f1.x,f1.y,f1.z,f1.w};
      #pragma unroll
      for(int j=0;j<8;j++){
        unsigned short hb = bfr(fa[j]);
        float hf = __uint_as_float(((unsigned)hb) << 16);
        ah[mt][j]  = (short)hb;
        al2[mt][j] = (short)bfr(fa[j] - hf);
      }
    }
    #pragma unroll
    for(int nt=0;nt<4;nt++){
      bf16x8 bh = *((bf16x8*)&Bh[offB[nt]]);
      bf16x8 bl = *((bf16x8*)&Bl[offB[nt]]);
      #pragma unroll
      for(int mt=0;mt<2;mt++){
        acc[mt][nt] = __builtin_amdgcn_mfma_f32_16x16x32_bf16(ah[mt],  bh, acc[mt][nt], 0,0,0);
        acc[mt][nt] = __builtin_amdgcn_mfma_f32_16x16x32_bf16(ah[mt],  bl, acc[mt][nt], 0,0,0);
        acc[mt][nt] = __builtin_amdgcn_mfma_f32_16x16x32_bf16(al2[mt], bh, acc[mt][nt], 0,0,0);
      }
    }
    __syncthreads();
    cur ^= 1;
  }

  // epilogue 1: bf16 payload stores. C/D layout: col=lm, row=lq*4+v.
  #pragma unroll
  for(int mt=0;mt<2;mt++){
    #pragma unroll
    for(int v=0;v<4;v++){
      int row = n0 + wm*32 + mt*16 + lq*4 + v;
      if(row < N){
        unsigned p0 = (unsigned)bfr(acc[mt][0][v]) | ((unsigned)bfr(acc[mt][2][v])<<16);
        unsigned p1 = (unsigned)bfr(acc[mt][1][v]) | ((unsigned)bfr(acc[mt][3][v])<<16);
        int jb = wn*32 + lm;
        xtb[(size_t)row*64 + jb]      = p0;
        xtb[(size_t)row*64 + jb + 16] = p1;
      }
    }
  }

  // epilogue 2: sl/sr via LDS transpose (fp32, pad-68 rows).
  att_sh[tid] = att1[tid];
  #pragma unroll 1
  for(int p=0;p<2;p++){
    __syncthreads();
    if(wn == p){
      #pragma unroll
      for(int mt=0;mt<2;mt++)
        #pragma unroll
        for(int nt=0;nt<4;nt++)
          #pragma unroll
          for(int v=0;v<4;v++)
            fx[(wm*32 + mt*16 + lq*4 + v)*68 + nt*16 + lm] = acc[mt][nt][v];
    }
    __syncthreads();
    if(tid < 128){
      int rloc = tid >> 1, hh = tid & 1;
      int head = p*2 + hh;
      float a = 0.f, b = 0.f;
      #pragma unroll
      for(int c4=0;c4<8;c4++){
        float4 xv  = *((const float4*)&fx[rloc*68 + hh*32 + c4*4]);
        float4 alv = *((const float4*)&att_sh[head*64 + c4*4]);
        float4 arv = *((const float4*)&att_sh[head*64 + 32 + c4*4]);
        a += xv.x*alv.x + xv.y*alv.y + xv.z*alv.z + xv.w*alv.w;
        b += xv.x*arv.x + xv.y*arv.y + xv.z*arv.z + xv.w*arv.w;
      }
      int row = n0 + rloc;
      if(row < N){
        sl[(size_t)row*4 + head] = a;
        sr[(size_t)row*4 + head] = b;
      }
    }
  }
}

// ---------------- layer 1 aggregation: one wave per target node ----------------

__global__ __launch_bounds__(64) void k_agg1(const int* __restrict__ offs, const int* __restrict__ srcs,
    const float* __restrict__ sl, const float* __restrict__ sr, const float* __restrict__ dinv,
    const unsigned* __restrict__ xtb, const float* __restrict__ b1, float* __restrict__ h, int N){
  __shared__ int   s_sh[64];
  __shared__ float w_sh[64*4];
  int n = blockIdx.x;
  if(n >= N) return;
  int lane = threadIdx.x;
  int beg = offs[n], end = offs[n+1];
  int deg = end - beg;
  float4 sln = *((const float4*)(sl + (size_t)n*4));
  int h0 = lane >> 5;
  float den0=0.f,den1=0.f,den2=0.f,den3=0.f;
  float acc0=0.f, acc1=0.f;

  if(deg <= 64){
    int j = beg + lane;
    int s = 0; float wd = 0.f;
    float a0=-1e30f, a1=-1e30f, a2=-1e30f, a3=-1e30f;
    if(j < end){
      s = srcs[j];
      float4 a = *((const float4*)(sr + (size_t)s*4));
      a0 = lrelu(sln.x + a.x);
      a1 = lrelu(sln.y + a.y);
      a2 = lrelu(sln.z + a.z);
      a3 = lrelu(sln.w + a.w);
      wd = dinv[s];
    }
    float m0=a0,m1=a1,m2=a2,m3=a3;
    #pragma unroll
    for(int o=32;o>0;o>>=1){
      m0 = fmaxf(m0, __shfl_xor(m0,o));
      m1 = fmaxf(m1, __shfl_xor(m1,o));
      m2 = fmaxf(m2, __shfl_xor(m2,o));
      m3 = fmaxf(m3, __shfl_xor(m3,o));
    }
    den0 = __expf(a0 - m0);
    den1 = __expf(a1 - m1);
    den2 = __expf(a2 - m2);
    den3 = __expf(a3 - m3);
    s_sh[lane] = s;
    w_sh[lane*4+0] = wd*den0;
    w_sh[lane*4+1] = wd*den1;
    w_sh[lane*4+2] = wd*den2;
    w_sh[lane*4+3] = wd*den3;
    __syncthreads();
    int k = 0;
    for(; k+8<=deg; k+=8){
      int sk[8];
      #pragma unroll
      for(int u=0;u<8;u++) sk[u] = __builtin_amdgcn_readfirstlane(s_sh[k+u]);
      unsigned pv[8];
      #pragma unroll
      for(int u=0;u<8;u++) pv[u] = xtb[(size_t)sk[u]*64 + lane];
      #pragma unroll
      for(int u=0;u<8;u++){
        float2 wv = *((const float2*)&w_sh[(k+u)*4 + h0*2]);
        acc0 += wv.x * __uint_as_float(pv[u] << 16);
        acc1 += wv.y * __uint_as_float(pv[u] & 0xffff0000u);
      }
    }
    for(; k<deg; k++){
      int sk = __builtin_amdgcn_readfirstlane(s_sh[k]);
      unsigned pvv = xtb[(size_t)sk*64 + lane];
      float2 wv = *((const float2*)&w_sh[k*4 + h0*2]);
      acc0 += wv.x * __uint_as_float(pvv << 16);
      acc1 += wv.y * __uint_as_float(pvv & 0xffff0000u);
    }
  } else {
    float m0=-1e30f,m1=-1e30f,m2=-1e30f,m3=-1e30f;
    for(int j=beg+lane; j<end; j+=64){
      int s = srcs[j];
      float4 a = *((const float4*)(sr + (size_t)s*4));
      m0 = fmaxf(m0, lrelu(sln.x + a.x));
      m1 = fmaxf(m1, lrelu(sln.y + a.y));
      m2 = fmaxf(m2, lrelu(sln.z + a.z));
      m3 = fmaxf(m3, lrelu(sln.w + a.w));
    }
    #pragma unroll
    for(int o=32;o>0;o>>=1){
      m0 = fmaxf(m0, __shfl_xor(m0,o));
      m1 = fmaxf(m1, __shfl_xor(m1,o));
      m2 = fmaxf(m2, __shfl_xor(m2,o));
      m3 = fmaxf(m3, __shfl_xor(m3,o));
    }
    for(int c0=beg; c0<end; c0+=64){
      int cnt = min(64, end-c0);
      int j = c0 + lane;
      float e0=0.f,e1=0.f,e2=0.f,e3=0.f, wd=0.f; int s=0;
      if(j<end){
        s = srcs[j];
        float4 a = *((const float4*)(sr + (size_t)s*4));
        e0 = __expf(lrelu(sln.x + a.x) - m0);
        e1 = __expf(lrelu(sln.y + a.y) - m1);
        e2 = __expf(lrelu(sln.z + a.z) - m2);
        e3 = __expf(lrelu(sln.w + a.w) - m3);
        wd = dinv[s];
      }
      den0+=e0; den1+=e1; den2+=e2; den3+=e3;
      s_sh[lane] = s;
      w_sh[lane*4+0] = wd*e0;
      w_sh[lane*4+1] = wd*e1;
      w_sh[lane*4+2] = wd*e2;
      w_sh[lane*4+3] = wd*e3;
      __syncthreads();
      int k = 0;
      for(; k+8<=cnt; k+=8){
        int sk[8];
        #pragma unroll
        for(int u=0;u<8;u++) sk[u] = __builtin_amdgcn_readfirstlane(s_sh[k+u]);
        unsigned pv[8];
        #pragma unroll
        for(int u=0;u<8;u++) pv[u] = xtb[(size_t)sk[u]*64 + lane];
        #pragma unroll
        for(int u=0;u<8;u++){
          float2 wv = *((const float2*)&w_sh[(k+u)*4 + h0*2]);
          acc0 += wv.x * __uint_as_float(pv[u] << 16);
          acc1 += wv.y * __uint_as_float(pv[u] & 0xffff0000u);
        }
      }
      for(; k<cnt; k++){
        int sk = __builtin_amdgcn_readfirstlane(s_sh[k]);
        unsigned pvv = xtb[(size_t)sk*64 + lane];
        float2 wv = *((const float2*)&w_sh[k*4 + h0*2]);
        acc0 += wv.x * __uint_as_float(pvv << 16);
        acc1 += wv.y * __uint_as_float(pvv & 0xffff0000u);
      }
      __syncthreads();
    }
  }
  #pragma unroll
  for(int o=32;o>0;o>>=1){
    den0 += __shfl_xor(den0,o);
    den1 += __shfl_xor(den1,o);
    den2 += __shfl_xor(den2,o);
    den3 += __shfl_xor(den3,o);
  }
  float din = dinv[n];
  int ch0 = (lane < 32) ? lane : lane + 32;
  int ch1 = ch0 + 32;
  float d0 = (lane < 32) ? den0 : den2;
  float d1 = (lane < 32) ? den1 : den3;
  float o0 = din*acc0/(d0 + 1e-16f) + b1[ch0];
  float o1 = din*acc1/(d1 + 1e-16f) + b1[ch1];
  h[(size_t)n*128 + ch0] = o0 > 0.f ? o0 : 0.f;
  h[(size_t)n*128 + ch1] = o1 > 0.f ? o1 : 0.f;
}

// ---------------- layer 2 GEMM (128->16) + attention scalars ----------------

__global__ __launch_bounds__(256) void k_gemm2(const float* __restrict__ hmat, const float* __restrict__ W2,
    const float* __restrict__ att2, unsigned* __restrict__ xt2b,
    float* __restrict__ sl2, float* __restrict__ sr2, int N){
  __shared__ float hs[16*132];
  __shared__ float ws[16*132];
  __shared__ float xs[16*16];
  int t = threadIdx.x;
  int n0 = blockIdx.x * 16;
  #pragma unroll
  for(int i=0;i<8;i++){
    int idx = t + 256*i;
    int k = idx >> 4, c = idx & 15;
    ws[c*132 + k] = W2[idx];
  }
  #pragma unroll
  for(int i=0;i<2;i++){
    int idx = t + 256*i;
    int r = idx >> 5, k4 = idx & 31;
    int n = n0 + r;
    float4 v = make_float4(0.f,0.f,0.f,0.f);
    if(n < N) v = ((const float4*)hmat)[(size_t)n*32 + k4];
    *((float4*)&hs[r*132 + k4*4]) = v;
  }
  __syncthreads();
  int r = t >> 4, c = t & 15;
  float acc = 0.f;
  for(int k=0;k<128;k+=4){
    float4 hv = *((const float4*)&hs[r*132+k]);
    float4 wv = *((const float4*)&ws[c*132+k]);
    acc += hv.x*wv.x + hv.y*wv.y + hv.z*wv.z + hv.w*wv.w;
  }
  xs[r*16 + c] = acc;
  __syncthreads();
  int n = n0 + r;
  if(c < 8 && n < N){
    unsigned pk = (unsigned)bfr(xs[r*16+c]) | ((unsigned)bfr(xs[r*16+c+8])<<16);
    xt2b[(size_t)n*8 + c] = pk;
  }
  if(t < 16){
    int nn = n0 + t;
    if(nn < N){
      float a = 0.f, b = 0.f;
      #pragma unroll
      for(int cc=0;cc<16;cc++){ float v = xs[t*16+cc]; a += v*att2[cc]; b += v*att2[16+cc]; }
      sl2[nn] = a; sr2[nn] = b;
    }
  }
}

// ---------------- layer 2 aggregation ----------------

__global__ __launch_bounds__(64) void k_agg2(const int* __restrict__ offs, const int* __restrict__ srcs,
    const float* __restrict__ sl2, const float* __restrict__ sr2, const float* __restrict__ dinv,
    const unsigned* __restrict__ xt2b, const float* __restrict__ b2, float* __restrict__ out, int N){
  __shared__ int   s_sh[64];
  __shared__ float w_sh[64];
  int n = blockIdx.x;
  if(n >= N) return;
  int lane = threadIdx.x;
  int beg = offs[n], end = offs[n+1];
  int deg = end - beg;
  float sln = sl2[n];
  float den = 0.f, acc0 = 0.f, acc1 = 0.f;
  int grp = lane >> 3, ch = lane & 7;

  if(deg <= 64){
    int j = beg + lane;
    int s = 0; float wd = 0.f; float a = -1e30f;
    if(j < end){
      s = srcs[j];
      a = lrelu(sln + sr2[s]);
      wd = dinv[s];
    }
    float m = a;
    #pragma unroll
    for(int o=32;o>0;o>>=1) m = fmaxf(m, __shfl_xor(m,o));
    float e = __expf(a - m);
    den = e;
    s_sh[lane] = s;
    w_sh[lane] = wd*e;
    __syncthreads();
    for(int k=0;k<deg;k+=8){
      int kk = k + grp;
      if(kk < deg){
        int sk = s_sh[kk];
        float wk = w_sh[kk];
        unsigned pv = xt2b[(size_t)sk*8 + ch];
        acc0 += wk * __uint_as_float(pv << 16);
        acc1 += wk * __uint_as_float(pv & 0xffff0000u);
      }
    }
  } else {
    float m = -1e30f;
    for(int j=beg+lane; j<end; j+=64)
      m = fmaxf(m, lrelu(sln + sr2[srcs[j]]));
    #pragma unroll
    for(int o=32;o>0;o>>=1) m = fmaxf(m, __shfl_xor(m,o));
    for(int c0=beg; c0<end; c0+=64){
      int cnt = min(64, end-c0);
      int j = c0 + lane;
      float e=0.f, wd=0.f; int s=0;
      if(j<end){
        s = srcs[j];
        e = __expf(lrelu(sln + sr2[s]) - m);
        wd = dinv[s];
      }
      den += e;
      s_sh[lane] = s;
      w_sh[lane] = wd*e;
      __syncthreads();
      for(int k=0;k<cnt;k+=8){
        int kk = k + grp;
        if(kk < cnt){
          int sk = s_sh[kk];
          float wk = w_sh[kk];
          unsigned pv = xt2b[(size_t)sk*8 + ch];
          acc0 += wk * __uint_as_float(pv << 16);
          acc1 += wk * __uint_as_float(pv & 0xffff0000u);
        }
      }
      __syncthreads();
    }
  }
  #pragma unroll
  for(int o=32;o>0;o>>=1) den += __shfl_xor(den,o);
  acc0 += __shfl_xor(acc0,8);  acc0 += __shfl_xor(acc0,16);  acc0 += __shfl_xor(acc0,32);
  acc1 += __shfl_xor(acc1,8);  acc1 += __shfl_xor(acc1,16);  acc1 += __shfl_xor(acc1,32);
  if(lane < 8){
    float din = dinv[n];
    out[(size_t)n*16 + lane]     = din*acc0/(den + 1e-16f) + b2[lane];
    out[(size_t)n*16 + lane + 8] = din*acc1/(den + 1e-16f) + b2[lane+8];
  }
}

// ---------------- host launch ----------------

extern "C" void kernel_launch(void* const* d_in, const int* in_sizes, int n_in,
                              void* d_out, int out_size, void* d_ws, size_t ws_size,
                              hipStream_t stream){
  const float* x    = (const float*)d_in[0];
  const int*   ei   = (const int*)d_in[1];
  const float* W1   = (const float*)d_in[2];
  const float* att1 = (const float*)d_in[3];
  const float* b1   = (const float*)d_in[4];
  const float* W2   = (const float*)d_in[5];
  const float* att2 = (const float*)d_in[6];
  const float* b2   = (const float*)d_in[7];
  int N = in_sizes[0] / 256;
  int E = in_sizes[1] / 2;
  const int* rows = ei;
  const int* cols = ei + E;
  float* out = (float*)d_out;

  int ET    = E + N;
  int NSEG2 = (N + SEGN - 1) / SEGN;   // requires N < 131072 (17-bit row pack), <=256 segs

  char* p = (char*)d_ws;
  auto alloc = [&](size_t bytes)->void*{ void* q = p; p += (bytes + 255) & ~(size_t)255; return q; };
  int*      cnt     = (int*)alloc((size_t)N*4);
  int*      offs    = (int*)alloc((size_t)(N+1)*4);
  int*      bsum    = (int*)alloc(256*4);
  int*      bcur    = (int*)alloc(512*4);     // [0:256)=C cursors, [256:512)=R cursors
  int*      csr     = (int*)alloc((size_t)ET*4);
  float*    dinv    = (float*)alloc((size_t)N*4);
  unsigned* xtb     = (unsigned*)alloc((size_t)N*64*4);
  float*    sl1     = (float*)alloc((size_t)N*16);
  float*    sr1     = (float*)alloc((size_t)N*16);
  float*    hbuf    = (float*)alloc((size_t)N*128*4);
  unsigned* xt2b    = (unsigned*)alloc((size_t)N*8*4);
  float*    sl2     = (float*)alloc((size_t)N*4);
  float*    sr2     = (float*)alloc((size_t)N*4);
  short*    Whi     = (short*)alloc((size_t)128*256*2);
  short*    Wlo     = (short*)alloc((size_t)128*256*2);

  int* bcurC = bcur;
  int* bcurR = bcur + 256;

  // transient aliases (consumed before their hosts are written):
  // ebufC (NSEG2*CAPC*4 ~ 9.6MB) + ebufR (~4.8MB) live inside xtb (25.6MB),
  // both consumed by k_cntseg/k_sortfill before k_gemm1 writes xtb.
  unsigned*       ebufC = (unsigned*)xtb;
  unsigned short* ebufR = (unsigned short*)(ebufC + (size_t)NSEG2*CAPC);

  int gB = (E + CHB - 1) / CHB;

  hipMemsetAsync(bcur, 0, 512*4, stream);
  k_bucket2<<<gB, 256, 0, stream>>>(rows, cols, bcurC, bcurR, ebufC, ebufR, E, NSEG2);
  k_cntseg<<<NSEG2, 256, 0, stream>>>(bcurC, bcurR, ebufC, ebufR, cnt, dinv, bsum, N);
  k_scan_bsum<<<1, 256, 0, stream>>>(bsum, NSEG2);
  k_scan_write<<<NSEG2, 256, 0, stream>>>(cnt, bsum, offs, N);
  k_sortfill<<<NSEG2, 256, 0, stream>>>(offs, bcurC, ebufC, csr, N);

  k_prepW<<<128, 256, 0, stream>>>(W1, Whi, Wlo);
  k_gemm1<<<(N + 63)/64, 256, 0, stream>>>(x, Whi, Wlo, att1, xtb, sl1, sr1, N);
  k_agg1<<<N, 64, 0, stream>>>(offs, csr, sl1, sr1, dinv, xtb, b1, hbuf, N);

  k_gemm2<<<(N + 15)/16, 256, 0, stream>>>(hbuf, W2, att2, xt2b, sl2, sr2, N);
  k_agg2<<<N, 64, 0, stream>>>(offs, csr, sl2, sr2, dinv, xt2b, b2, out, N);
}

// Round 9
// 406.411 us; speedup vs baseline: 1.5181x; 1.0203x over previous
//
#include <hip/hip_runtime.h>
#include <math.h>

#define TPB 256
#define SEGN 512            // nodes per sort segment (col>>9)
#define SCAP 14336          // LDS sort buffer capacity (56KB)
#define CHB 8192            // edges per bucket block
#define CAPC 12288          // fixed bucket capacity per segment (mean 8163, +45 sigma)

__device__ __forceinline__ float lrelu(float a){ return a >= 0.f ? a : 0.2f*a; }

typedef __attribute__((ext_vector_type(8))) short bf16x8;
typedef __attribute__((ext_vector_type(4))) float f32x4;

// round-to-nearest-even fp32 -> bf16 bits
__device__ __forceinline__ unsigned short bfr(float f){
  unsigned u = __float_as_uint(f);
  return (unsigned short)((u + 0x7fffu + ((u >> 16) & 1u)) >> 16);
}

// async global->LDS, 16B per lane; dest must be wave-uniform base (lane*16 implicit)
__device__ __forceinline__ void gl_lds16(const void* g, void* l){
  __builtin_amdgcn_global_load_lds(
      (const __attribute__((address_space(1))) void*)g,
      (__attribute__((address_space(3))) void*)l, 16, 0, 0);
}

// ---------------- graph build ----------------
// Rules (rounds 5/6): no per-edge global atomics, no scattered 4B global
// writes. LDS-ranked buckets with block-level reservations, per-segment LDS
// histogram / counting-sort, coalesced streaming output.
// Round 9: C and R phases merged into one edge pass (rows read once, half the
// reservation rounds); scan_write fused into sortfill (segment-granular).

__global__ __launch_bounds__(256) void k_bucketM(const int* __restrict__ rows, const int* __restrict__ cols,
    int* __restrict__ bcurC, int* __restrict__ bcurR,
    unsigned* __restrict__ ebufC, unsigned short* __restrict__ ebufR, int E, int NSEG2){
  __shared__ int lhC[256], lbC[256], lhR[256], lbR[256];
  int tid = threadIdx.x;
  int e0 = blockIdx.x * CHB;
  #pragma unroll 1
  for(int r=0; r<4; r++){
    lhC[tid] = 0; lhR[tid] = 0;
    __syncthreads();
    int eb = e0 + r*2048;
    unsigned pk[8]; int sgC[8], rkC[8], sgR[8], rkR[8]; int pvR[8];
    #pragma unroll
    for(int i=0;i<8;i++){
      int e = eb + i*256 + tid;
      sgC[i] = -1;
      if(e < E){
        int cc = cols[e], rr = rows[e];
        sgC[i] = cc >> 9;
        pk[i]  = ((unsigned)(cc & (SEGN-1)) << 17) | (unsigned)rr;  // N < 131072
        rkC[i] = atomicAdd(&lhC[sgC[i]], 1);
        sgR[i] = rr >> 9;
        pvR[i] = rr & (SEGN-1);
        rkR[i] = atomicAdd(&lhR[sgR[i]], 1);
      }
    }
    __syncthreads();
    if(tid < NSEG2){
      int c = lhC[tid];  lbC[tid] = c  ? atomicAdd(&bcurC[tid], c)  : 0;
      int c2 = lhR[tid]; lbR[tid] = c2 ? atomicAdd(&bcurR[tid], c2) : 0;
    }
    __syncthreads();
    #pragma unroll
    for(int i=0;i<8;i++)
      if(sgC[i] >= 0){
        int p = lbC[sgC[i]] + rkC[i];
        if(p < CAPC) ebufC[sgC[i]*CAPC + p] = pk[i];     // overflow guard (never hits)
        int p2 = lbR[sgR[i]] + rkR[i];
        if(p2 < CAPC) ebufR[sgR[i]*CAPC + p2] = (unsigned short)pvR[i];
      }
    __syncthreads();
  }
}

// per-segment LDS histograms of both buckets -> cnt (+1 self-loop), dinv, bsum
__global__ __launch_bounds__(256) void k_cntseg(const int* __restrict__ bcurC, const int* __restrict__ bcurR,
    const unsigned* __restrict__ ebufC, const unsigned short* __restrict__ ebufR,
    int* __restrict__ cnt, float* __restrict__ dinv, int* __restrict__ bsum, int N){
  __shared__ int hc[SEGN];
  __shared__ int hr[SEGN];
  __shared__ int red[256];
  int s = blockIdx.x, tid = threadIdx.x;
  int lo = s*SEGN;
  int nn = min(SEGN, N - lo);
  for(int i=tid; i<SEGN; i+=256){ hc[i] = 0; hr[i] = 0; }
  __syncthreads();
  int cb = s*CAPC;
  int cc = min(bcurC[s], CAPC);
  int rc = min(bcurR[s], CAPC);
  for(int j=tid; j<cc; j+=256) atomicAdd(&hc[ebufC[cb + j] >> 17], 1);
  for(int j=tid; j<rc; j+=256) atomicAdd(&hr[ebufR[cb + j]], 1);
  __syncthreads();
  int tsum = 0;
  for(int i=tid; i<nn; i+=256){
    int c = hc[i] + 1;                                   // + self-loop
    cnt[lo+i]  = c;
    tsum += c;
    dinv[lo+i] = 1.f / sqrtf((float)(hr[i] + 1));
  }
  red[tid] = tsum; __syncthreads();
  for(int off=128; off>0; off>>=1){
    if(tid < off) red[tid] += red[tid+off];
    __syncthreads();
  }
  if(tid == 0) bsum[s] = red[0];
}

__global__ void k_scan_bsum(int* bsum, int NB){
  __shared__ int s[256];
  int t = threadIdx.x;
  int v = (t < NB) ? bsum[t] : 0;
  s[t] = v; __syncthreads();
  for(int off=1; off<256; off<<=1){
    int add = (t >= off) ? s[t-off] : 0;
    __syncthreads();
    s[t] += add;
    __syncthreads();
  }
  if(t < NB) bsum[t] = s[t] - v;   // exclusive
}

// fused scan-write + counting-sort fill: block = segment. Local scan of cnt
// gives offs; csr slice assembled in LDS, streamed out coalesced.
__global__ __launch_bounds__(256) void k_sortfill2(const int* __restrict__ cnt,
    const int* __restrict__ bsum, const int* __restrict__ bcurC,
    const unsigned* __restrict__ ebuf, int* __restrict__ offs,
    int* __restrict__ csr, int N){
  __shared__ int lcur[SEGN];
  __shared__ int lbuf[SCAP];
  __shared__ int sdata[256];
  int s = blockIdx.x, tid = threadIdx.x;
  int lo = s*SEGN;
  int nn = min(SEGN, N - lo);
  int base = bsum[s];
  int i0 = tid*2, i1 = i0+1;
  int v0 = (i0 < nn) ? cnt[lo+i0] : 0;
  int v1 = (i1 < nn) ? cnt[lo+i1] : 0;
  int ssum = v0 + v1;
  sdata[tid] = ssum; __syncthreads();
  int mine = ssum;
  for(int off=1; off<256; off<<=1){
    int add = (tid >= off) ? sdata[tid-off] : 0;
    __syncthreads();
    sdata[tid] += add;
    __syncthreads();
  }
  int total = sdata[255];
  int run0 = sdata[tid] - mine;
  int run1 = run0 + v0;
  int eb = s*CAPC;
  int ec = min(bcurC[s], CAPC);
  if(total <= SCAP){
    if(i0 < nn){
      offs[lo+i0] = base + run0;
      lbuf[run0]  = lo + i0;        // self-loop at slot 0
      lcur[i0]    = run0 + 1;
      if(lo+i0 == N-1) offs[N] = base + run0 + v0;
    }
    if(i1 < nn){
      offs[lo+i1] = base + run1;
      lbuf[run1]  = lo + i1;
      lcur[i1]    = run1 + 1;
      if(lo+i1 == N-1) offs[N] = base + run1 + v1;
    }
    __syncthreads();
    for(int j=tid; j<ec; j+=256){
      unsigned pk = ebuf[eb + j];
      int li  = pk >> 17;
      int row = pk & 0x1FFFF;
      int p = atomicAdd(&lcur[li], 1);   // LDS atomic
      lbuf[p] = row;
    }
    __syncthreads();
    for(int j=tid; j<total; j+=256) csr[base + j] = lbuf[j];   // full-line streaming
  } else {
    // overflow fallback (statistically never): direct scatter, global cursors
    if(i0 < nn){
      offs[lo+i0] = base + run0;
      csr[base+run0] = lo + i0;
      lcur[i0] = base + run0 + 1;
      if(lo+i0 == N-1) offs[N] = base + run0 + v0;
    }
    if(i1 < nn){
      offs[lo+i1] = base + run1;
      csr[base+run1] = lo + i1;
      lcur[i1] = base + run1 + 1;
      if(lo+i1 == N-1) offs[N] = base + run1 + v1;
    }
    __syncthreads();
    for(int j=tid; j<ec; j+=256){
      unsigned pk = ebuf[eb + j];
      int li  = pk >> 17;
      int row = pk & 0x1FFFF;
      int p = atomicAdd(&lcur[li], 1);
      csr[p] = row;
    }
  }
}

// ---------------- W1 prep: transpose + bf16 hi/lo split ----------------

__global__ void k_prepW(const float* __restrict__ W, short* __restrict__ Whi,
                        short* __restrict__ Wlo){
  int idx = blockIdx.x*256 + threadIdx.x;   // 32768
  int n = idx >> 8, k = idx & 255;
  float f = W[k*128 + n];
  unsigned short h = bfr(f);
  float hf = __uint_as_float(((unsigned)h) << 16);
  Whi[n*256 + k] = (short)h;
  Wlo[n*256 + k] = (short)bfr(f - hf);
}

// ---------------- layer 1 GEMM: f32-A global_load_lds pipeline ----------------

#define BUFB 24576
__global__ __launch_bounds__(256) void k_gemm1(
    const float* __restrict__ x,
    const short* __restrict__ Whi, const short* __restrict__ Wlo,
    const float* __restrict__ att1,
    unsigned* __restrict__ xtb, float* __restrict__ sl, float* __restrict__ sr, int N){
  __shared__ __align__(16) char smem[2*BUFB];
  float* fx = (float*)smem;                  // epilogue alias: 64*68 floats
  float* att_sh = (float*)(smem + 17408);    // 256 floats

  int tid = threadIdx.x;
  int n0 = blockIdx.x * 64;
  int w = tid >> 6, l = tid & 63;
  int wm = w & 1, wn = w >> 1;
  int lm = l & 15, lq = l >> 4;

  f32x4 acc[2][4];
  #pragma unroll
  for(int a=0;a<2;a++)
    #pragma unroll
    for(int b=0;b<4;b++) acc[a][b] = (f32x4){0.f,0.f,0.f,0.f};

  int ua0 = (w<<6) | l, ua1 = 256 + ua0;
  int ar0 = ua0 >> 3, as0 = (ua0 & 7) ^ (ar0 & 7);
  int ar1 = ua1 >> 3, as1 = (ua1 & 7) ^ (ar1 & 7);
  const float* gA0 = x + (size_t)min(n0 + ar0, N-1)*256 + as0*4;
  const float* gA1 = x + (size_t)min(n0 + ar1, N-1)*256 + as1*4;
  int ub0 = (w<<6) | l,  ub1 = 256 + ub0;
  int br0 = ub0 >> 2, bs0 = (ub0 & 3) ^ ((br0 >> 1) & 3);
  int br1 = ub1 >> 2, bs1 = (ub1 & 3) ^ ((br1 >> 1) & 3);
  const short* gBh0 = Whi + br0*256 + bs0*8;
  const short* gBh1 = Whi + br1*256 + bs1*8;
  const short* gBl0 = Wlo + br0*256 + bs0*8;
  const short* gBl1 = Wlo + br1*256 + bs1*8;
  int woff = w << 10;

  int offAf[2][2], offB[4];
  #pragma unroll
  for(int mt=0;mt<2;mt++){
    int rr = wm*32 + mt*16 + lm;
    offAf[mt][0] = rr*32 + (((2*lq+0) ^ (rr&7)) << 2);
    offAf[mt][1] = rr*32 + (((2*lq+1) ^ (rr&7)) << 2);
  }
  #pragma unroll
  for(int nt=0;nt<4;nt++){
    int rr = wn*64 + nt*16 + lm;
    offB[nt] = rr*32 + ((lq ^ ((rr>>1)&3)) << 3);
  }

  {
    char* base = smem;
    gl_lds16(gA0,  base          + woff);
    gl_lds16(gA1,  base + 4096   + woff);
    gl_lds16(gBh0, base + 8192   + woff);
    gl_lds16(gBh1, base + 12288  + woff);
    gl_lds16(gBl0, base + 16384  + woff);
    gl_lds16(gBl1, base + 20480  + woff);
  }
  __syncthreads();

  int cur = 0;
  #pragma unroll 1
  for(int c=0;c<8;c++){
    if(c < 7){
      int kf = (c+1) << 5;
      char* base = smem + (cur^1)*BUFB;
      gl_lds16(gA0  + kf, base          + woff);
      gl_lds16(gA1  + kf, base + 4096   + woff);
      gl_lds16(gBh0 + kf, base + 8192   + woff);
      gl_lds16(gBh1 + kf, base + 12288  + woff);
      gl_lds16(gBl0 + kf, base + 16384  + woff);
      gl_lds16(gBl1 + kf, base + 20480  + woff);
    }
    float* Axf = (float*)(smem + cur*BUFB);
    short* Bh  = (short*)(smem + cur*BUFB + 8192);
    short* Bl  = (short*)(smem + cur*BUFB + 16384);
    bf16x8 ah[2], al2[2];
    #pragma unroll
    for(int mt=0;mt<2;mt++){
      float4 f0 = *((const float4*)&Axf[offAf[mt][0]]);
      float4 f1 = *((const float4*)&Axf[offAf[mt][1]]);
      float fa[8] = {f0.x,f0.y,f0.z,f0.w,f1.x,f1.y,f1.z,f1.w};
      #pragma unroll
      for(int j=0;j<8;j++){
        unsigned short hb = bfr(fa[j]);
        float hf = __uint_as_float(((unsigned)hb) << 16);
        ah[mt][j]  = (short)hb;
        al2[mt][j] = (short)bfr(fa[j] - hf);
      }
    }
    #pragma unroll
    for(int nt=0;nt<4;nt++){
      bf16x8 bh = *((bf16x8*)&Bh[offB[nt]]);
      bf16x8 bl = *((bf16x8*)&Bl[offB[nt]]);
      #pragma unroll
      for(int mt=0;mt<2;mt++){
        acc[mt][nt] = __builtin_amdgcn_mfma_f32_16x16x32_bf16(ah[mt],  bh, acc[mt][nt], 0,0,0);
        acc[mt][nt] = __builtin_amdgcn_mfma_f32_16x16x32_bf16(ah[mt],  bl, acc[mt][nt], 0,0,0);
        acc[mt][nt] = __builtin_amdgcn_mfma_f32_16x16x32_bf16(al2[mt], bh, acc[mt][nt], 0,0,0);
      }
    }
    __syncthreads();
    cur ^= 1;
  }

  #pragma unroll
  for(int mt=0;mt<2;mt++){
    #pragma unroll
    for(int v=0;v<4;v++){
      int row = n0 + wm*32 + mt*16 + lq*4 + v;
      if(row < N){
        unsigned p0 = (unsigned)bfr(acc[mt][0][v]) | ((unsigned)bfr(acc[mt][2][v])<<16);
        unsigned p1 = (unsigned)bfr(acc[mt][1][v]) | ((unsigned)bfr(acc[mt][3][v])<<16);
        int jb = wn*32 + lm;
        xtb[(size_t)row*64 + jb]      = p0;
        xtb[(size_t)row*64 + jb + 16] = p1;
      }
    }
  }

  att_sh[tid] = att1[tid];
  #pragma unroll 1
  for(int p=0;p<2;p++){
    __syncthreads();
    if(wn == p){
      #pragma unroll
      for(int mt=0;mt<2;mt++)
        #pragma unroll
        for(int nt=0;nt<4;nt++)
          #pragma unroll
          for(int v=0;v<4;v++)
            fx[(wm*32 + mt*16 + lq*4 + v)*68 + nt*16 + lm] = acc[mt][nt][v];
    }
    __syncthreads();
    if(tid < 128){
      int rloc = tid >> 1, hh = tid & 1;
      int head = p*2 + hh;
      float a = 0.f, b = 0.f;
      #pragma unroll
      for(int c4=0;c4<8;c4++){
        float4 xv  = *((const float4*)&fx[rloc*68 + hh*32 + c4*4]);
        float4 alv = *((const float4*)&att_sh[head*64 + c4*4]);
        float4 arv = *((const float4*)&att_sh[head*64 + 32 + c4*4]);
        a += xv.x*alv.x + xv.y*alv.y + xv.z*alv.z + xv.w*alv.w;
        b += xv.x*arv.x + xv.y*arv.y + xv.z*arv.z + xv.w*arv.w;
      }
      int row = n0 + rloc;
      if(row < N){
        sl[(size_t)row*4 + head] = a;
        sr[(size_t)row*4 + head] = b;
      }
    }
  }
}

// ---------------- layer 1 aggregation + FUSED layer-2 projection ----------------
// h (128 fp32) never touches HBM: held in 512B LDS, projected through W2
// (L1-resident 8KB) to xt2 (16), emitting xt2b/sl2/sr2 directly.
// Removes agg1's 50MB hbuf write + the entire k_gemm2 (102MB round-trip).

__global__ __launch_bounds__(64) void k_agg1(const int* __restrict__ offs, const int* __restrict__ srcs,
    const float* __restrict__ sl, const float* __restrict__ sr, const float* __restrict__ dinv,
    const unsigned* __restrict__ xtb, const float* __restrict__ b1,
    const float* __restrict__ W2, const float* __restrict__ att2,
    float* __restrict__ sl2, float* __restrict__ sr2, unsigned* __restrict__ xt2b, int N){
  __shared__ int   s_sh[64];
  __shared__ float w_sh[64*4];
  __shared__ float h_sh[144];          // 128 h + 16 xt2
  int n = blockIdx.x;
  if(n >= N) return;
  int lane = threadIdx.x;
  int beg = offs[n], end = offs[n+1];
  int deg = end - beg;
  float4 sln = *((const float4*)(sl + (size_t)n*4));
  int h0 = lane >> 5;
  float den0=0.f,den1=0.f,den2=0.f,den3=0.f;
  float acc0=0.f, acc1=0.f;

  if(deg <= 64){
    int j = beg + lane;
    int s = 0; float wd = 0.f;
    float a0=-1e30f, a1=-1e30f, a2=-1e30f, a3=-1e30f;
    if(j < end){
      s = srcs[j];
      float4 a = *((const float4*)(sr + (size_t)s*4));
      a0 = lrelu(sln.x + a.x);
      a1 = lrelu(sln.y + a.y);
      a2 = lrelu(sln.z + a.z);
      a3 = lrelu(sln.w + a.w);
      wd = dinv[s];
    }
    float m0=a0,m1=a1,m2=a2,m3=a3;
    #pragma unroll
    for(int o=32;o>0;o>>=1){
      m0 = fmaxf(m0, __shfl_xor(m0,o));
      m1 = fmaxf(m1, __shfl_xor(m1,o));
      m2 = fmaxf(m2, __shfl_xor(m2,o));
      m3 = fmaxf(m3, __shfl_xor(m3,o));
    }
    den0 = __expf(a0 - m0);
    den1 = __expf(a1 - m1);
    den2 = __expf(a2 - m2);
    den3 = __expf(a3 - m3);
    s_sh[lane] = s;
    w_sh[lane*4+0] = wd*den0;
    w_sh[lane*4+1] = wd*den1;
    w_sh[lane*4+2] = wd*den2;
    w_sh[lane*4+3] = wd*den3;
    __syncthreads();
    int k = 0;
    for(; k+8<=deg; k+=8){
      int sk[8];
      #pragma unroll
      for(int u=0;u<8;u++) sk[u] = __builtin_amdgcn_readfirstlane(s_sh[k+u]);
      unsigned pv[8];
      #pragma unroll
      for(int u=0;u<8;u++) pv[u] = xtb[(size_t)sk[u]*64 + lane];
      #pragma unroll
      for(int u=0;u<8;u++){
        float2 wv = *((const float2*)&w_sh[(k+u)*4 + h0*2]);
        acc0 += wv.x * __uint_as_float(pv[u] << 16);
        acc1 += wv.y * __uint_as_float(pv[u] & 0xffff0000u);
      }
    }
    for(; k<deg; k++){
      int sk = __builtin_amdgcn_readfirstlane(s_sh[k]);
      unsigned pvv = xtb[(size_t)sk*64 + lane];
      float2 wv = *((const float2*)&w_sh[k*4 + h0*2]);
      acc0 += wv.x * __uint_as_float(pvv << 16);
      acc1 += wv.y * __uint_as_float(pvv & 0xffff0000u);
    }
  } else {
    float m0=-1e30f,m1=-1e30f,m2=-1e30f,m3=-1e30f;
    for(int j=beg+lane; j<end; j+=64){
      int s = srcs[j];
      float4 a = *((const float4*)(sr + (size_t)s*4));
      m0 = fmaxf(m0, lrelu(sln.x + a.x));
      m1 = fmaxf(m1, lrelu(sln.y + a.y));
      m2 = fmaxf(m2, lrelu(sln.z + a.z));
      m3 = fmaxf(m3, lrelu(sln.w + a.w));
    }
    #pragma unroll
    for(int o=32;o>0;o>>=1){
      m0 = fmaxf(m0, __shfl_xor(m0,o));
      m1 = fmaxf(m1, __shfl_xor(m1,o));
      m2 = fmaxf(m2, __shfl_xor(m2,o));
      m3 = fmaxf(m3, __shfl_xor(m3,o));
    }
    for(int c0=beg; c0<end; c0+=64){
      int cnt = min(64, end-c0);
      int j = c0 + lane;
      float e0=0.f,e1=0.f,e2=0.f,e3=0.f, wd=0.f; int s=0;
      if(j<end){
        s = srcs[j];
        float4 a = *((const float4*)(sr + (size_t)s*4));
        e0 = __expf(lrelu(sln.x + a.x) - m0);
        e1 = __expf(lrelu(sln.y + a.y) - m1);
        e2 = __expf(lrelu(sln.z + a.z) - m2);
        e3 = __expf(lrelu(sln.w + a.w) - m3);
        wd = dinv[s];
      }
      den0+=e0; den1+=e1; den2+=e2; den3+=e3;
      s_sh[lane] = s;
      w_sh[lane*4+0] = wd*e0;
      w_sh[lane*4+1] = wd*e1;
      w_sh[lane*4+2] = wd*e2;
      w_sh[lane*4+3] = wd*e3;
      __syncthreads();
      int k = 0;
      for(; k+8<=cnt; k+=8){
        int sk[8];
        #pragma unroll
        for(int u=0;u<8;u++) sk[u] = __builtin_amdgcn_readfirstlane(s_sh[k+u]);
        unsigned pv[8];
        #pragma unroll
        for(int u=0;u<8;u++) pv[u] = xtb[(size_t)sk[u]*64 + lane];
        #pragma unroll
        for(int u=0;u<8;u++){
          float2 wv = *((const float2*)&w_sh[(k+u)*4 + h0*2]);
          acc0 += wv.x * __uint_as_float(pv[u] << 16);
          acc1 += wv.y * __uint_as_float(pv[u] & 0xffff0000u);
        }
      }
      for(; k<cnt; k++){
        int sk = __builtin_amdgcn_readfirstlane(s_sh[k]);
        unsigned pvv = xtb[(size_t)sk*64 + lane];
        float2 wv = *((const float2*)&w_sh[k*4 + h0*2]);
        acc0 += wv.x * __uint_as_float(pvv << 16);
        acc1 += wv.y * __uint_as_float(pvv & 0xffff0000u);
      }
      __syncthreads();
    }
  }
  #pragma unroll
  for(int o=32;o>0;o>>=1){
    den0 += __shfl_xor(den0,o);
    den1 += __shfl_xor(den1,o);
    den2 += __shfl_xor(den2,o);
    den3 += __shfl_xor(den3,o);
  }
  float din = dinv[n];
  int ch0 = (lane < 32) ? lane : lane + 32;   // pairs (c, c+32)
  int ch1 = ch0 + 32;
  float d0 = (lane < 32) ? den0 : den2;
  float d1 = (lane < 32) ? den1 : den3;
  float o0 = din*acc0/(d0 + 1e-16f) + b1[ch0];
  float o1 = din*acc1/(d1 + 1e-16f) + b1[ch1];
  o0 = o0 > 0.f ? o0 : 0.f;
  o1 = o1 > 0.f ? o1 : 0.f;

  // ---- fused layer-2 projection (former k_gemm2) ----
  h_sh[ch0] = o0;
  h_sh[ch1] = o1;
  __syncthreads();
  int c4 = lane & 3, q = lane >> 2;          // c4: output quad, q: 8-k slice
  const float4* W24 = (const float4*)W2;     // W2[k][c] -> W24[k*4 + c4]
  f32x4 a4 = (f32x4){0.f,0.f,0.f,0.f};
  #pragma unroll
  for(int j=0;j<8;j++){
    int k = q*8 + j;
    float hv = h_sh[k];
    float4 wv = W24[k*4 + c4];
    a4[0] += hv*wv.x; a4[1] += hv*wv.y; a4[2] += hv*wv.z; a4[3] += hv*wv.w;
  }
  #pragma unroll
  for(int o=4;o<64;o<<=1){
    a4[0] += __shfl_xor(a4[0],o);
    a4[1] += __shfl_xor(a4[1],o);
    a4[2] += __shfl_xor(a4[2],o);
    a4[3] += __shfl_xor(a4[3],o);
  }
  if(lane < 4){
    h_sh[128 + lane*4 + 0] = a4[0];
    h_sh[128 + lane*4 + 1] = a4[1];
    h_sh[128 + lane*4 + 2] = a4[2];
    h_sh[128 + lane*4 + 3] = a4[3];
  }
  __syncthreads();
  if(lane < 16){
    float v = h_sh[128 + lane];
    float t0 = v*att2[lane], t1 = v*att2[16 + lane];
    #pragma unroll
    for(int o=1;o<16;o<<=1){ t0 += __shfl_xor(t0,o); t1 += __shfl_xor(t1,o); }
    if(lane == 0){ sl2[n] = t0; sr2[n] = t1; }
  }
  if(lane < 8){
    unsigned pk = (unsigned)bfr(h_sh[128+lane]) | ((unsigned)bfr(h_sh[128+lane+8])<<16);
    xt2b[(size_t)n*8 + lane] = pk;
  }
}

// ---------------- layer 2 aggregation ----------------

__global__ __launch_bounds__(64) void k_agg2(const int* __restrict__ offs, const int* __restrict__ srcs,
    const float* __restrict__ sl2, const float* __restrict__ sr2, const float* __restrict__ dinv,
    const unsigned* __restrict__ xt2b, const float* __restrict__ b2, float* __restrict__ out, int N){
  __shared__ int   s_sh[64];
  __shared__ float w_sh[64];
  int n = blockIdx.x;
  if(n >= N) return;
  int lane = threadIdx.x;
  int beg = offs[n], end = offs[n+1];
  int deg = end - beg;
  float sln = sl2[n];
  float den = 0.f, acc0 = 0.f, acc1 = 0.f;
  int grp = lane >> 3, ch = lane & 7;

  if(deg <= 64){
    int j = beg + lane;
    int s = 0; float wd = 0.f; float a = -1e30f;
    if(j < end){
      s = srcs[j];
      a = lrelu(sln + sr2[s]);
      wd = dinv[s];
    }
    float m = a;
    #pragma unroll
    for(int o=32;o>0;o>>=1) m = fmaxf(m, __shfl_xor(m,o));
    float e = __expf(a - m);
    den = e;
    s_sh[lane] = s;
    w_sh[lane] = wd*e;
    __syncthreads();
    for(int k=0;k<deg;k+=8){
      int kk = k + grp;
      if(kk < deg){
        int sk = s_sh[kk];
        float wk = w_sh[kk];
        unsigned pv = xt2b[(size_t)sk*8 + ch];
        acc0 += wk * __uint_as_float(pv << 16);
        acc1 += wk * __uint_as_float(pv & 0xffff0000u);
      }
    }
  } else {
    float m = -1e30f;
    for(int j=beg+lane; j<end; j+=64)
      m = fmaxf(m, lrelu(sln + sr2[srcs[j]]));
    #pragma unroll
    for(int o=32;o>0;o>>=1) m = fmaxf(m, __shfl_xor(m,o));
    for(int c0=beg; c0<end; c0+=64){
      int cnt = min(64, end-c0);
      int j = c0 + lane;
      float e=0.f, wd=0.f; int s=0;
      if(j<end){
        s = srcs[j];
        e = __expf(lrelu(sln + sr2[s]) - m);
        wd = dinv[s];
      }
      den += e;
      s_sh[lane] = s;
      w_sh[lane] = wd*e;
      __syncthreads();
      for(int k=0;k<cnt;k+=8){
        int kk = k + grp;
        if(kk < cnt){
          int sk = s_sh[kk];
          float wk = w_sh[kk];
          unsigned pv = xt2b[(size_t)sk*8 + ch];
          acc0 += wk * __uint_as_float(pv << 16);
          acc1 += wk * __uint_as_float(pv & 0xffff0000u);
        }
      }
      __syncthreads();
    }
  }
  #pragma unroll
  for(int o=32;o>0;o>>=1) den += __shfl_xor(den,o);
  acc0 += __shfl_xor(acc0,8);  acc0 += __shfl_xor(acc0,16);  acc0 += __shfl_xor(acc0,32);
  acc1 += __shfl_xor(acc1,8);  acc1 += __shfl_xor(acc1,16);  acc1 += __shfl_xor(acc1,32);
  if(lane < 8){
    float din = dinv[n];
    out[(size_t)n*16 + lane]     = din*acc0/(den + 1e-16f) + b2[lane];
    out[(size_t)n*16 + lane + 8] = din*acc1/(den + 1e-16f) + b2[lane+8];
  }
}

// ---------------- host launch ----------------

extern "C" void kernel_launch(void* const* d_in, const int* in_sizes, int n_in,
                              void* d_out, int out_size, void* d_ws, size_t ws_size,
                              hipStream_t stream){
  const float* x    = (const float*)d_in[0];
  const int*   ei   = (const int*)d_in[1];
  const float* W1   = (const float*)d_in[2];
  const float* att1 = (const float*)d_in[3];
  const float* b1   = (const float*)d_in[4];
  const float* W2   = (const float*)d_in[5];
  const float* att2 = (const float*)d_in[6];
  const float* b2   = (const float*)d_in[7];
  int N = in_sizes[0] / 256;
  int E = in_sizes[1] / 2;
  const int* rows = ei;
  const int* cols = ei + E;
  float* out = (float*)d_out;

  int ET    = E + N;
  int NSEG2 = (N + SEGN - 1) / SEGN;   // requires N < 131072 (17-bit row pack), <=256 segs

  char* p = (char*)d_ws;
  auto alloc = [&](size_t bytes)->void*{ void* q = p; p += (bytes + 255) & ~(size_t)255; return q; };
  int*      cnt     = (int*)alloc((size_t)N*4);
  int*      offs    = (int*)alloc((size_t)(N+1)*4);
  int*      bsum    = (int*)alloc(256*4);
  int*      bcur    = (int*)alloc(512*4);     // [0:256)=C cursors, [256:512)=R cursors
  int*      csr     = (int*)alloc((size_t)ET*4);
  float*    dinv    = (float*)alloc((size_t)N*4);
  unsigned* xtb     = (unsigned*)alloc((size_t)N*64*4);
  float*    sl1     = (float*)alloc((size_t)N*16);
  float*    sr1     = (float*)alloc((size_t)N*16);
  unsigned* xt2b    = (unsigned*)alloc((size_t)N*8*4);
  float*    sl2     = (float*)alloc((size_t)N*4);
  float*    sr2     = (float*)alloc((size_t)N*4);
  short*    Whi     = (short*)alloc((size_t)128*256*2);
  short*    Wlo     = (short*)alloc((size_t)128*256*2);

  int* bcurC = bcur;
  int* bcurR = bcur + 256;

  // transient aliases (consumed by cntseg/sortfill2 before k_gemm1 writes xtb):
  unsigned*       ebufC = (unsigned*)xtb;                              // ~9.6MB
  unsigned short* ebufR = (unsigned short*)(ebufC + (size_t)NSEG2*CAPC); // ~4.8MB

  int gB = (E + CHB - 1) / CHB;

  hipMemsetAsync(bcur, 0, 512*4, stream);
  k_bucketM<<<gB, 256, 0, stream>>>(rows, cols, bcurC, bcurR, ebufC, ebufR, E, NSEG2);
  k_cntseg<<<NSEG2, 256, 0, stream>>>(bcurC, bcurR, ebufC, ebufR, cnt, dinv, bsum, N);
  k_scan_bsum<<<1, 256, 0, stream>>>(bsum, NSEG2);
  k_sortfill2<<<NSEG2, 256, 0, stream>>>(cnt, bsum, bcurC, ebufC, offs, csr, N);

  k_prepW<<<128, 256, 0, stream>>>(W1, Whi, Wlo);
  k_gemm1<<<(N + 63)/64, 256, 0, stream>>>(x, Whi, Wlo, att1, xtb, sl1, sr1, N);
  k_agg1<<<N, 64, 0, stream>>>(offs, csr, sl1, sr1, dinv, xtb, b1, W2, att2, sl2, sr2, xt2b, N);
  k_agg2<<<N, 64, 0, stream>>>(offs, csr, sl2, sr2, dinv, xt2b, b2, out, N);
}

// Round 10
// 406.406 us; speedup vs baseline: 1.5181x; 1.0000x over previous
//
#include <hip/hip_runtime.h>
#include <math.h>

#define TPB 256
#define SEGN 512            // nodes per sort segment (col>>9)
#define SCAP 14336          // LDS sort buffer capacity (56KB)
#define CHB 8192            // edges per bucket block
#define CAPC 12288          // fixed bucket capacity per segment (mean 8163, +45 sigma)

__device__ __forceinline__ float lrelu(float a){ return a >= 0.f ? a : 0.2f*a; }

typedef __attribute__((ext_vector_type(8))) short bf16x8;
typedef __attribute__((ext_vector_type(4))) float f32x4;

// round-to-nearest-even fp32 -> bf16 bits
__device__ __forceinline__ unsigned short bfr(float f){
  unsigned u = __float_as_uint(f);
  return (unsigned short)((u + 0x7fffu + ((u >> 16) & 1u)) >> 16);
}

// async global->LDS, 16B per lane; dest must be wave-uniform base (lane*16 implicit)
__device__ __forceinline__ void gl_lds16(const void* g, void* l){
  __builtin_amdgcn_global_load_lds(
      (const __attribute__((address_space(1))) void*)g,
      (__attribute__((address_space(3))) void*)l, 16, 0, 0);
}

// ---------------- graph build ----------------
// Rules (rounds 5/6): no per-edge global atomics, no scattered 4B global
// writes. LDS-ranked buckets with block-level reservations, per-segment LDS
// histogram / counting-sort, coalesced streaming output.

__global__ __launch_bounds__(256) void k_bucketM(const int* __restrict__ rows, const int* __restrict__ cols,
    int* __restrict__ bcurC, int* __restrict__ bcurR,
    unsigned* __restrict__ ebufC, unsigned short* __restrict__ ebufR, int E, int NSEG2){
  __shared__ int lhC[256], lbC[256], lhR[256], lbR[256];
  int tid = threadIdx.x;
  int e0 = blockIdx.x * CHB;
  #pragma unroll 1
  for(int r=0; r<4; r++){
    lhC[tid] = 0; lhR[tid] = 0;
    __syncthreads();
    int eb = e0 + r*2048;
    unsigned pk[8]; int sgC[8], rkC[8], sgR[8], rkR[8]; int pvR[8];
    #pragma unroll
    for(int i=0;i<8;i++){
      int e = eb + i*256 + tid;
      sgC[i] = -1;
      if(e < E){
        int cc = cols[e], rr = rows[e];
        sgC[i] = cc >> 9;
        pk[i]  = ((unsigned)(cc & (SEGN-1)) << 17) | (unsigned)rr;  // N < 131072
        rkC[i] = atomicAdd(&lhC[sgC[i]], 1);
        sgR[i] = rr >> 9;
        pvR[i] = rr & (SEGN-1);
        rkR[i] = atomicAdd(&lhR[sgR[i]], 1);
      }
    }
    __syncthreads();
    if(tid < NSEG2){
      int c = lhC[tid];  lbC[tid] = c  ? atomicAdd(&bcurC[tid], c)  : 0;
      int c2 = lhR[tid]; lbR[tid] = c2 ? atomicAdd(&bcurR[tid], c2) : 0;
    }
    __syncthreads();
    #pragma unroll
    for(int i=0;i<8;i++)
      if(sgC[i] >= 0){
        int p = lbC[sgC[i]] + rkC[i];
        if(p < CAPC) ebufC[sgC[i]*CAPC + p] = pk[i];     // overflow guard (never hits)
        int p2 = lbR[sgR[i]] + rkR[i];
        if(p2 < CAPC) ebufR[sgR[i]*CAPC + p2] = (unsigned short)pvR[i];
      }
    __syncthreads();
  }
}

// per-segment LDS histograms of both buckets -> cnt (+1 self-loop), dinv, bsum
__global__ __launch_bounds__(256) void k_cntseg(const int* __restrict__ bcurC, const int* __restrict__ bcurR,
    const unsigned* __restrict__ ebufC, const unsigned short* __restrict__ ebufR,
    int* __restrict__ cnt, float* __restrict__ dinv, int* __restrict__ bsum, int N){
  __shared__ int hc[SEGN];
  __shared__ int hr[SEGN];
  __shared__ int red[256];
  int s = blockIdx.x, tid = threadIdx.x;
  int lo = s*SEGN;
  int nn = min(SEGN, N - lo);
  for(int i=tid; i<SEGN; i+=256){ hc[i] = 0; hr[i] = 0; }
  __syncthreads();
  int cb = s*CAPC;
  int cc = min(bcurC[s], CAPC);
  int rc = min(bcurR[s], CAPC);
  for(int j=tid; j<cc; j+=256) atomicAdd(&hc[ebufC[cb + j] >> 17], 1);
  for(int j=tid; j<rc; j+=256) atomicAdd(&hr[ebufR[cb + j]], 1);
  __syncthreads();
  int tsum = 0;
  for(int i=tid; i<nn; i+=256){
    int c = hc[i] + 1;                                   // + self-loop
    cnt[lo+i]  = c;
    tsum += c;
    dinv[lo+i] = 1.f / sqrtf((float)(hr[i] + 1));
  }
  red[tid] = tsum; __syncthreads();
  for(int off=128; off>0; off>>=1){
    if(tid < off) red[tid] += red[tid+off];
    __syncthreads();
  }
  if(tid == 0) bsum[s] = red[0];
}

__global__ void k_scan_bsum(int* bsum, int NB){
  __shared__ int s[256];
  int t = threadIdx.x;
  int v = (t < NB) ? bsum[t] : 0;
  s[t] = v; __syncthreads();
  for(int off=1; off<256; off<<=1){
    int add = (t >= off) ? s[t-off] : 0;
    __syncthreads();
    s[t] += add;
    __syncthreads();
  }
  if(t < NB) bsum[t] = s[t] - v;   // exclusive
}

// fused scan-write + counting-sort fill: block = segment.
__global__ __launch_bounds__(256) void k_sortfill2(const int* __restrict__ cnt,
    const int* __restrict__ bsum, const int* __restrict__ bcurC,
    const unsigned* __restrict__ ebuf, int* __restrict__ offs,
    int* __restrict__ csr, int N){
  __shared__ int lcur[SEGN];
  __shared__ int lbuf[SCAP];
  __shared__ int sdata[256];
  int s = blockIdx.x, tid = threadIdx.x;
  int lo = s*SEGN;
  int nn = min(SEGN, N - lo);
  int base = bsum[s];
  int i0 = tid*2, i1 = i0+1;
  int v0 = (i0 < nn) ? cnt[lo+i0] : 0;
  int v1 = (i1 < nn) ? cnt[lo+i1] : 0;
  int ssum = v0 + v1;
  sdata[tid] = ssum; __syncthreads();
  int mine = ssum;
  for(int off=1; off<256; off<<=1){
    int add = (tid >= off) ? sdata[tid-off] : 0;
    __syncthreads();
    sdata[tid] += add;
    __syncthreads();
  }
  int total = sdata[255];
  int run0 = sdata[tid] - mine;
  int run1 = run0 + v0;
  int eb = s*CAPC;
  int ec = min(bcurC[s], CAPC);
  if(total <= SCAP){
    if(i0 < nn){
      offs[lo+i0] = base + run0;
      lbuf[run0]  = lo + i0;        // self-loop at slot 0
      lcur[i0]    = run0 + 1;
      if(lo+i0 == N-1) offs[N] = base + run0 + v0;
    }
    if(i1 < nn){
      offs[lo+i1] = base + run1;
      lbuf[run1]  = lo + i1;
      lcur[i1]    = run1 + 1;
      if(lo+i1 == N-1) offs[N] = base + run1 + v1;
    }
    __syncthreads();
    for(int j=tid; j<ec; j+=256){
      unsigned pk = ebuf[eb + j];
      int li  = pk >> 17;
      int row = pk & 0x1FFFF;
      int p = atomicAdd(&lcur[li], 1);   // LDS atomic
      lbuf[p] = row;
    }
    __syncthreads();
    for(int j=tid; j<total; j+=256) csr[base + j] = lbuf[j];   // full-line streaming
  } else {
    // overflow fallback (statistically never): direct scatter
    if(i0 < nn){
      offs[lo+i0] = base + run0;
      csr[base+run0] = lo + i0;
      lcur[i0] = base + run0 + 1;
      if(lo+i0 == N-1) offs[N] = base + run0 + v0;
    }
    if(i1 < nn){
      offs[lo+i1] = base + run1;
      csr[base+run1] = lo + i1;
      lcur[i1] = base + run1 + 1;
      if(lo+i1 == N-1) offs[N] = base + run1 + v1;
    }
    __syncthreads();
    for(int j=tid; j<ec; j+=256){
      unsigned pk = ebuf[eb + j];
      int li  = pk >> 17;
      int row = pk & 0x1FFFF;
      int p = atomicAdd(&lcur[li], 1);
      csr[p] = row;
    }
  }
}

// ---------------- W1 prep: transpose + bf16 hi/lo split ----------------

__global__ void k_prepW(const float* __restrict__ W, short* __restrict__ Whi,
                        short* __restrict__ Wlo){
  int idx = blockIdx.x*256 + threadIdx.x;   // 32768
  int n = idx >> 8, k = idx & 255;
  float f = W[k*128 + n];
  unsigned short h = bfr(f);
  float hf = __uint_as_float(((unsigned)h) << 16);
  Whi[n*256 + k] = (short)h;
  Wlo[n*256 + k] = (short)bfr(f - hf);
}

// ---------------- layer 1 GEMM: f32-A global_load_lds pipeline ----------------

#define BUFB 24576
__global__ __launch_bounds__(256) void k_gemm1(
    const float* __restrict__ x,
    const short* __restrict__ Whi, const short* __restrict__ Wlo,
    const float* __restrict__ att1,
    unsigned* __restrict__ xtb, float* __restrict__ sl, float* __restrict__ sr, int N){
  __shared__ __align__(16) char smem[2*BUFB];
  float* fx = (float*)smem;                  // epilogue alias: 64*68 floats
  float* att_sh = (float*)(smem + 17408);    // 256 floats

  int tid = threadIdx.x;
  int n0 = blockIdx.x * 64;
  int w = tid >> 6, l = tid & 63;
  int wm = w & 1, wn = w >> 1;
  int lm = l & 15, lq = l >> 4;

  f32x4 acc[2][4];
  #pragma unroll
  for(int a=0;a<2;a++)
    #pragma unroll
    for(int b=0;b<4;b++) acc[a][b] = (f32x4){0.f,0.f,0.f,0.f};

  int ua0 = (w<<6) | l, ua1 = 256 + ua0;
  int ar0 = ua0 >> 3, as0 = (ua0 & 7) ^ (ar0 & 7);
  int ar1 = ua1 >> 3, as1 = (ua1 & 7) ^ (ar1 & 7);
  const float* gA0 = x + (size_t)min(n0 + ar0, N-1)*256 + as0*4;
  const float* gA1 = x + (size_t)min(n0 + ar1, N-1)*256 + as1*4;
  int ub0 = (w<<6) | l,  ub1 = 256 + ub0;
  int br0 = ub0 >> 2, bs0 = (ub0 & 3) ^ ((br0 >> 1) & 3);
  int br1 = ub1 >> 2, bs1 = (ub1 & 3) ^ ((br1 >> 1) & 3);
  const short* gBh0 = Whi + br0*256 + bs0*8;
  const short* gBh1 = Whi + br1*256 + bs1*8;
  const short* gBl0 = Wlo + br0*256 + bs0*8;
  const short* gBl1 = Wlo + br1*256 + bs1*8;
  int woff = w << 10;

  int offAf[2][2], offB[4];
  #pragma unroll
  for(int mt=0;mt<2;mt++){
    int rr = wm*32 + mt*16 + lm;
    offAf[mt][0] = rr*32 + (((2*lq+0) ^ (rr&7)) << 2);
    offAf[mt][1] = rr*32 + (((2*lq+1) ^ (rr&7)) << 2);
  }
  #pragma unroll
  for(int nt=0;nt<4;nt++){
    int rr = wn*64 + nt*16 + lm;
    offB[nt] = rr*32 + ((lq ^ ((rr>>1)&3)) << 3);
  }

  {
    char* base = smem;
    gl_lds16(gA0,  base          + woff);
    gl_lds16(gA1,  base + 4096   + woff);
    gl_lds16(gBh0, base + 8192   + woff);
    gl_lds16(gBh1, base + 12288  + woff);
    gl_lds16(gBl0, base + 16384  + woff);
    gl_lds16(gBl1, base + 20480  + woff);
  }
  __syncthreads();

  int cur = 0;
  #pragma unroll 1
  for(int c=0;c<8;c++){
    if(c < 7){
      int kf = (c+1) << 5;
      char* base = smem + (cur^1)*BUFB;
      gl_lds16(gA0  + kf, base          + woff);
      gl_lds16(gA1  + kf, base + 4096   + woff);
      gl_lds16(gBh0 + kf, base + 8192   + woff);
      gl_lds16(gBh1 + kf, base + 12288  + woff);
      gl_lds16(gBl0 + kf, base + 16384  + woff);
      gl_lds16(gBl1 + kf, base + 20480  + woff);
    }
    float* Axf = (float*)(smem + cur*BUFB);
    short* Bh  = (short*)(smem + cur*BUFB + 8192);
    short* Bl  = (short*)(smem + cur*BUFB + 16384);
    bf16x8 ah[2], al2[2];
    #pragma unroll
    for(int mt=0;mt<2;mt++){
      float4 f0 = *((const float4*)&Axf[offAf[mt][0]]);
      float4 f1 = *((const float4*)&Axf[offAf[mt][1]]);
      float fa[8] = {f0.x,f0.y,f0.z,f0.w,f1.x,f1.y,f1.z,f1.w};
      #pragma unroll
      for(int j=0;j<8;j++){
        unsigned short hb = bfr(fa[j]);
        float hf = __uint_as_float(((unsigned)hb) << 16);
        ah[mt][j]  = (short)hb;
        al2[mt][j] = (short)bfr(fa[j] - hf);
      }
    }
    #pragma unroll
    for(int nt=0;nt<4;nt++){
      bf16x8 bh = *((bf16x8*)&Bh[offB[nt]]);
      bf16x8 bl = *((bf16x8*)&Bl[offB[nt]]);
      #pragma unroll
      for(int mt=0;mt<2;mt++){
        acc[mt][nt] = __builtin_amdgcn_mfma_f32_16x16x32_bf16(ah[mt],  bh, acc[mt][nt], 0,0,0);
        acc[mt][nt] = __builtin_amdgcn_mfma_f32_16x16x32_bf16(ah[mt],  bl, acc[mt][nt], 0,0,0);
        acc[mt][nt] = __builtin_amdgcn_mfma_f32_16x16x32_bf16(al2[mt], bh, acc[mt][nt], 0,0,0);
      }
    }
    __syncthreads();
    cur ^= 1;
  }

  #pragma unroll
  for(int mt=0;mt<2;mt++){
    #pragma unroll
    for(int v=0;v<4;v++){
      int row = n0 + wm*32 + mt*16 + lq*4 + v;
      if(row < N){
        unsigned p0 = (unsigned)bfr(acc[mt][0][v]) | ((unsigned)bfr(acc[mt][2][v])<<16);
        unsigned p1 = (unsigned)bfr(acc[mt][1][v]) | ((unsigned)bfr(acc[mt][3][v])<<16);
        int jb = wn*32 + lm;
        xtb[(size_t)row*64 + jb]      = p0;
        xtb[(size_t)row*64 + jb + 16] = p1;
      }
    }
  }

  att_sh[tid] = att1[tid];
  #pragma unroll 1
  for(int p=0;p<2;p++){
    __syncthreads();
    if(wn == p){
      #pragma unroll
      for(int mt=0;mt<2;mt++)
        #pragma unroll
        for(int nt=0;nt<4;nt++)
          #pragma unroll
          for(int v=0;v<4;v++)
            fx[(wm*32 + mt*16 + lq*4 + v)*68 + nt*16 + lm] = acc[mt][nt][v];
    }
    __syncthreads();
    if(tid < 128){
      int rloc = tid >> 1, hh = tid & 1;
      int head = p*2 + hh;
      float a = 0.f, b = 0.f;
      #pragma unroll
      for(int c4=0;c4<8;c4++){
        float4 xv  = *((const float4*)&fx[rloc*68 + hh*32 + c4*4]);
        float4 alv = *((const float4*)&att_sh[head*64 + c4*4]);
        float4 arv = *((const float4*)&att_sh[head*64 + 32 + c4*4]);
        a += xv.x*alv.x + xv.y*alv.y + xv.z*alv.z + xv.w*alv.w;
        b += xv.x*arv.x + xv.y*arv.y + xv.z*arv.z + xv.w*arv.w;
      }
      int row = n0 + rloc;
      if(row < N){
        sl[(size_t)row*4 + head] = a;
        sr[(size_t)row*4 + head] = b;
      }
    }
  }
}

// ---------------- layer 1 aggregation: one wave per target node ----------------
// (W2-projection fusion REVERTED: round-9 measured +30us on agg1 — the per-block
// serial projection tail isn't hidden at 100K 1-wave blocks. hbuf stays fp32.)

__global__ __launch_bounds__(64) void k_agg1(const int* __restrict__ offs, const int* __restrict__ srcs,
    const float* __restrict__ sl, const float* __restrict__ sr, const float* __restrict__ dinv,
    const unsigned* __restrict__ xtb, const float* __restrict__ b1, float* __restrict__ h, int N){
  __shared__ int   s_sh[64];
  __shared__ float w_sh[64*4];
  int n = blockIdx.x;
  if(n >= N) return;
  int lane = threadIdx.x;
  int beg = offs[n], end = offs[n+1];
  int deg = end - beg;
  float4 sln = *((const float4*)(sl + (size_t)n*4));
  int h0 = lane >> 5;
  float den0=0.f,den1=0.f,den2=0.f,den3=0.f;
  float acc0=0.f, acc1=0.f;

  if(deg <= 64){
    int j = beg + lane;
    int s = 0; float wd = 0.f;
    float a0=-1e30f, a1=-1e30f, a2=-1e30f, a3=-1e30f;
    if(j < end){
      s = srcs[j];
      float4 a = *((const float4*)(sr + (size_t)s*4));
      a0 = lrelu(sln.x + a.x);
      a1 = lrelu(sln.y + a.y);
      a2 = lrelu(sln.z + a.z);
      a3 = lrelu(sln.w + a.w);
      wd = dinv[s];
    }
    float m0=a0,m1=a1,m2=a2,m3=a3;
    #pragma unroll
    for(int o=32;o>0;o>>=1){
      m0 = fmaxf(m0, __shfl_xor(m0,o));
      m1 = fmaxf(m1, __shfl_xor(m1,o));
      m2 = fmaxf(m2, __shfl_xor(m2,o));
      m3 = fmaxf(m3, __shfl_xor(m3,o));
    }
    den0 = __expf(a0 - m0);
    den1 = __expf(a1 - m1);
    den2 = __expf(a2 - m2);
    den3 = __expf(a3 - m3);
    s_sh[lane] = s;
    w_sh[lane*4+0] = wd*den0;
    w_sh[lane*4+1] = wd*den1;
    w_sh[lane*4+2] = wd*den2;
    w_sh[lane*4+3] = wd*den3;
    __syncthreads();
    int k = 0;
    for(; k+8<=deg; k+=8){
      int sk[8];
      #pragma unroll
      for(int u=0;u<8;u++) sk[u] = __builtin_amdgcn_readfirstlane(s_sh[k+u]);
      unsigned pv[8];
      #pragma unroll
      for(int u=0;u<8;u++) pv[u] = xtb[(size_t)sk[u]*64 + lane];
      #pragma unroll
      for(int u=0;u<8;u++){
        float2 wv = *((const float2*)&w_sh[(k+u)*4 + h0*2]);
        acc0 += wv.x * __uint_as_float(pv[u] << 16);
        acc1 += wv.y * __uint_as_float(pv[u] & 0xffff0000u);
      }
    }
    for(; k<deg; k++){
      int sk = __builtin_amdgcn_readfirstlane(s_sh[k]);
      unsigned pvv = xtb[(size_t)sk*64 + lane];
      float2 wv = *((const float2*)&w_sh[k*4 + h0*2]);
      acc0 += wv.x * __uint_as_float(pvv << 16);
      acc1 += wv.y * __uint_as_float(pvv & 0xffff0000u);
    }
  } else {
    float m0=-1e30f,m1=-1e30f,m2=-1e30f,m3=-1e30f;
    for(int j=beg+lane; j<end; j+=64){
      int s = srcs[j];
      float4 a = *((const float4*)(sr + (size_t)s*4));
      m0 = fmaxf(m0, lrelu(sln.x + a.x));
      m1 = fmaxf(m1, lrelu(sln.y + a.y));
      m2 = fmaxf(m2, lrelu(sln.z + a.z));
      m3 = fmaxf(m3, lrelu(sln.w + a.w));
    }
    #pragma unroll
    for(int o=32;o>0;o>>=1){
      m0 = fmaxf(m0, __shfl_xor(m0,o));
      m1 = fmaxf(m1, __shfl_xor(m1,o));
      m2 = fmaxf(m2, __shfl_xor(m2,o));
      m3 = fmaxf(m3, __shfl_xor(m3,o));
    }
    for(int c0=beg; c0<end; c0+=64){
      int cnt = min(64, end-c0);
      int j = c0 + lane;
      float e0=0.f,e1=0.f,e2=0.f,e3=0.f, wd=0.f; int s=0;
      if(j<end){
        s = srcs[j];
        float4 a = *((const float4*)(sr + (size_t)s*4));
        e0 = __expf(lrelu(sln.x + a.x) - m0);
        e1 = __expf(lrelu(sln.y + a.y) - m1);
        e2 = __expf(lrelu(sln.z + a.z) - m2);
        e3 = __expf(lrelu(sln.w + a.w) - m3);
        wd = dinv[s];
      }
      den0+=e0; den1+=e1; den2+=e2; den3+=e3;
      s_sh[lane] = s;
      w_sh[lane*4+0] = wd*e0;
      w_sh[lane*4+1] = wd*e1;
      w_sh[lane*4+2] = wd*e2;
      w_sh[lane*4+3] = wd*e3;
      __syncthreads();
      int k = 0;
      for(; k+8<=cnt; k+=8){
        int sk[8];
        #pragma unroll
        for(int u=0;u<8;u++) sk[u] = __builtin_amdgcn_readfirstlane(s_sh[k+u]);
        unsigned pv[8];
        #pragma unroll
        for(int u=0;u<8;u++) pv[u] = xtb[(size_t)sk[u]*64 + lane];
        #pragma unroll
        for(int u=0;u<8;u++){
          float2 wv = *((const float2*)&w_sh[(k+u)*4 + h0*2]);
          acc0 += wv.x * __uint_as_float(pv[u] << 16);
          acc1 += wv.y * __uint_as_float(pv[u] & 0xffff0000u);
        }
      }
      for(; k<cnt; k++){
        int sk = __builtin_amdgcn_readfirstlane(s_sh[k]);
        unsigned pvv = xtb[(size_t)sk*64 + lane];
        float2 wv = *((const float2*)&w_sh[k*4 + h0*2]);
        acc0 += wv.x * __uint_as_float(pvv << 16);
        acc1 += wv.y * __uint_as_float(pvv & 0xffff0000u);
      }
      __syncthreads();
    }
  }
  #pragma unroll
  for(int o=32;o>0;o>>=1){
    den0 += __shfl_xor(den0,o);
    den1 += __shfl_xor(den1,o);
    den2 += __shfl_xor(den2,o);
    den3 += __shfl_xor(den3,o);
  }
  float din = dinv[n];
  int ch0 = (lane < 32) ? lane : lane + 32;   // pairs (c, c+32)
  int ch1 = ch0 + 32;
  float d0 = (lane < 32) ? den0 : den2;
  float d1 = (lane < 32) ? den1 : den3;
  float o0 = din*acc0/(d0 + 1e-16f) + b1[ch0];
  float o1 = din*acc1/(d1 + 1e-16f) + b1[ch1];
  h[(size_t)n*128 + ch0] = o0 > 0.f ? o0 : 0.f;
  h[(size_t)n*128 + ch1] = o1 > 0.f ? o1 : 0.f;
}

// ---------------- layer 2 GEMM (128->16) + attention scalars ----------------

__global__ __launch_bounds__(256) void k_gemm2(const float* __restrict__ hmat, const float* __restrict__ W2,
    const float* __restrict__ att2, unsigned* __restrict__ xt2b,
    float* __restrict__ sl2, float* __restrict__ sr2, int N){
  __shared__ float hs[16*132];
  __shared__ float ws[16*132];
  __shared__ float xs[16*16];
  int t = threadIdx.x;
  int n0 = blockIdx.x * 16;
  #pragma unroll
  for(int i=0;i<8;i++){
    int idx = t + 256*i;
    int k = idx >> 4, c = idx & 15;
    ws[c*132 + k] = W2[idx];
  }
  #pragma unroll
  for(int i=0;i<2;i++){
    int idx = t + 256*i;
    int r = idx >> 5, k4 = idx & 31;
    int n = n0 + r;
    float4 v = make_float4(0.f,0.f,0.f,0.f);
    if(n < N) v = ((const float4*)hmat)[(size_t)n*32 + k4];
    *((float4*)&hs[r*132 + k4*4]) = v;
  }
  __syncthreads();
  int r = t >> 4, c = t & 15;
  float acc = 0.f;
  for(int k=0;k<128;k+=4){
    float4 hv = *((const float4*)&hs[r*132+k]);
    float4 wv = *((const float4*)&ws[c*132+k]);
    acc += hv.x*wv.x + hv.y*wv.y + hv.z*wv.z + hv.w*wv.w;
  }
  xs[r*16 + c] = acc;
  __syncthreads();
  int n = n0 + r;
  if(c < 8 && n < N){
    unsigned pk = (unsigned)bfr(xs[r*16+c]) | ((unsigned)bfr(xs[r*16+c+8])<<16);
    xt2b[(size_t)n*8 + c] = pk;
  }
  if(t < 16){
    int nn = n0 + t;
    if(nn < N){
      float a = 0.f, b = 0.f;
      #pragma unroll
      for(int cc=0;cc<16;cc++){ float v = xs[t*16+cc]; a += v*att2[cc]; b += v*att2[16+cc]; }
      sl2[nn] = a; sr2[nn] = b;
    }
  }
}

// ---------------- layer 2 aggregation ----------------

__global__ __launch_bounds__(64) void k_agg2(const int* __restrict__ offs, const int* __restrict__ srcs,
    const float* __restrict__ sl2, const float* __restrict__ sr2, const float* __restrict__ dinv,
    const unsigned* __restrict__ xt2b, const float* __restrict__ b2, float* __restrict__ out, int N){
  __shared__ int   s_sh[64];
  __shared__ float w_sh[64];
  int n = blockIdx.x;
  if(n >= N) return;
  int lane = threadIdx.x;
  int beg = offs[n], end = offs[n+1];
  int deg = end - beg;
  float sln = sl2[n];
  float den = 0.f, acc0 = 0.f, acc1 = 0.f;
  int grp = lane >> 3, ch = lane & 7;

  if(deg <= 64){
    int j = beg + lane;
    int s = 0; float wd = 0.f; float a = -1e30f;
    if(j < end){
      s = srcs[j];
      a = lrelu(sln + sr2[s]);
      wd = dinv[s];
    }
    float m = a;
    #pragma unroll
    for(int o=32;o>0;o>>=1) m = fmaxf(m, __shfl_xor(m,o));
    float e = __expf(a - m);
    den = e;
    s_sh[lane] = s;
    w_sh[lane] = wd*e;
    __syncthreads();
    for(int k=0;k<deg;k+=8){
      int kk = k + grp;
      if(kk < deg){
        int sk = s_sh[kk];
        float wk = w_sh[kk];
        unsigned pv = xt2b[(size_t)sk*8 + ch];
        acc0 += wk * __uint_as_float(pv << 16);
        acc1 += wk * __uint_as_float(pv & 0xffff0000u);
      }
    }
  } else {
    float m = -1e30f;
    for(int j=beg+lane; j<end; j+=64)
      m = fmaxf(m, lrelu(sln + sr2[srcs[j]]));
    #pragma unroll
    for(int o=32;o>0;o>>=1) m = fmaxf(m, __shfl_xor(m,o));
    for(int c0=beg; c0<end; c0+=64){
      int cnt = min(64, end-c0);
      int j = c0 + lane;
      float e=0.f, wd=0.f; int s=0;
      if(j<end){
        s = srcs[j];
        e = __expf(lrelu(sln + sr2[s]) - m);
        wd = dinv[s];
      }
      den += e;
      s_sh[lane] = s;
      w_sh[lane] = wd*e;
      __syncthreads();
      for(int k=0;k<cnt;k+=8){
        int kk = k + grp;
        if(kk < cnt){
          int sk = s_sh[kk];
          float wk = w_sh[kk];
          unsigned pv = xt2b[(size_t)sk*8 + ch];
          acc0 += wk * __uint_as_float(pv << 16);
          acc1 += wk * __uint_as_float(pv & 0xffff0000u);
        }
      }
      __syncthreads();
    }
  }
  #pragma unroll
  for(int o=32;o>0;o>>=1) den += __shfl_xor(den,o);
  acc0 += __shfl_xor(acc0,8);  acc0 += __shfl_xor(acc0,16);  acc0 += __shfl_xor(acc0,32);
  acc1 += __shfl_xor(acc1,8);  acc1 += __shfl_xor(acc1,16);  acc1 += __shfl_xor(acc1,32);
  if(lane < 8){
    float din = dinv[n];
    out[(size_t)n*16 + lane]     = din*acc0/(den + 1e-16f) + b2[lane];
    out[(size_t)n*16 + lane + 8] = din*acc1/(den + 1e-16f) + b2[lane+8];
  }
}

// ---------------- host launch ----------------

extern "C" void kernel_launch(void* const* d_in, const int* in_sizes, int n_in,
                              void* d_out, int out_size, void* d_ws, size_t ws_size,
                              hipStream_t stream){
  const float* x    = (const float*)d_in[0];
  const int*   ei   = (const int*)d_in[1];
  const float* W1   = (const float*)d_in[2];
  const float* att1 = (const float*)d_in[3];
  const float* b1   = (const float*)d_in[4];
  const float* W2   = (const float*)d_in[5];
  const float* att2 = (const float*)d_in[6];
  const float* b2   = (const float*)d_in[7];
  int N = in_sizes[0] / 256;
  int E = in_sizes[1] / 2;
  const int* rows = ei;
  const int* cols = ei + E;
  float* out = (float*)d_out;

  int ET    = E + N;
  int NSEG2 = (N + SEGN - 1) / SEGN;   // requires N < 131072 (17-bit row pack), <=256 segs

  char* p = (char*)d_ws;
  auto alloc = [&](size_t bytes)->void*{ void* q = p; p += (bytes + 255) & ~(size_t)255; return q; };
  int*      cnt     = (int*)alloc((size_t)N*4);
  int*      offs    = (int*)alloc((size_t)(N+1)*4);
  int*      bsum    = (int*)alloc(256*4);
  int*      bcur    = (int*)alloc(512*4);     // [0:256)=C cursors, [256:512)=R cursors
  int*      csr     = (int*)alloc((size_t)ET*4);
  float*    dinv    = (float*)alloc((size_t)N*4);
  unsigned* xtb     = (unsigned*)alloc((size_t)N*64*4);
  float*    sl1     = (float*)alloc((size_t)N*16);
  float*    sr1     = (float*)alloc((size_t)N*16);
  float*    hbuf    = (float*)alloc((size_t)N*128*4);
  unsigned* xt2b    = (unsigned*)alloc((size_t)N*8*4);
  float*    sl2     = (float*)alloc((size_t)N*4);
  float*    sr2     = (float*)alloc((size_t)N*4);
  short*    Whi     = (short*)alloc((size_t)128*256*2);
  short*    Wlo     = (short*)alloc((size_t)128*256*2);

  int* bcurC = bcur;
  int* bcurR = bcur + 256;

  // transient aliases (consumed by cntseg/sortfill2 before k_gemm1 writes xtb):
  unsigned*       ebufC = (unsigned*)xtb;                                // ~9.6MB
  unsigned short* ebufR = (unsigned short*)(ebufC + (size_t)NSEG2*CAPC); // ~4.8MB

  int gB = (E + CHB - 1) / CHB;

  hipMemsetAsync(bcur, 0, 512*4, stream);
  k_bucketM<<<gB, 256, 0, stream>>>(rows, cols, bcurC, bcurR, ebufC, ebufR, E, NSEG2);
  k_cntseg<<<NSEG2, 256, 0, stream>>>(bcurC, bcurR, ebufC, ebufR, cnt, dinv, bsum, N);
  k_scan_bsum<<<1, 256, 0, stream>>>(bsum, NSEG2);
  k_sortfill2<<<NSEG2, 256, 0, stream>>>(cnt, bsum, bcurC, ebufC, offs, csr, N);

  k_prepW<<<128, 256, 0, stream>>>(W1, Whi, Wlo);
  k_gemm1<<<(N + 63)/64, 256, 0, stream>>>(x, Whi, Wlo, att1, xtb, sl1, sr1, N);
  k_agg1<<<N, 64, 0, stream>>>(offs, csr, sl1, sr1, dinv, xtb, b1, hbuf, N);

  k_gemm2<<<(N + 15)/16, 256, 0, stream>>>(hbuf, W2, att2, xt2b, sl2, sr2, N);
  k_agg2<<<N, 64, 0, stream>>>(offs, csr, sl2, sr2, dinv, xt2b, b2, out, N);
}

// Round 11
// 379.865 us; speedup vs baseline: 1.6241x; 1.0699x over previous
//
#include <hip/hip_runtime.h>
#include <math.h>

#define TPB 256
#define SEGN 512            // nodes per sort segment (col>>9)
#define SCAP 14336          // LDS sort buffer capacity (56KB)
#define CHB 8192            // edges per bucket block
#define CAPC 12288          // fixed bucket capacity per segment (mean 8163, +45 sigma)

__device__ __forceinline__ float lrelu(float a){ return a >= 0.f ? a : 0.2f*a; }

typedef __attribute__((ext_vector_type(8))) short bf16x8;
typedef __attribute__((ext_vector_type(4))) float f32x4;

// round-to-nearest-even fp32 -> bf16 bits
__device__ __forceinline__ unsigned short bfr(float f){
  unsigned u = __float_as_uint(f);
  return (unsigned short)((u + 0x7fffu + ((u >> 16) & 1u)) >> 16);
}

// async global->LDS, 16B per lane; dest must be wave-uniform base (lane*16 implicit)
__device__ __forceinline__ void gl_lds16(const void* g, void* l){
  __builtin_amdgcn_global_load_lds(
      (const __attribute__((address_space(1))) void*)g,
      (__attribute__((address_space(3))) void*)l, 16, 0, 0);
}

// ---------------- W1 prep: transpose + bf16 hi/lo split ----------------

__global__ void k_prepW(const float* __restrict__ W, short* __restrict__ Whi,
                        short* __restrict__ Wlo){
  int idx = blockIdx.x*256 + threadIdx.x;   // 32768
  int n = idx >> 8, k = idx & 255;
  float f = W[k*128 + n];
  unsigned short h = bfr(f);
  float hf = __uint_as_float(((unsigned)h) << 16);
  Whi[n*256 + k] = (short)h;
  Wlo[n*256 + k] = (short)bfr(f - hf);
}

// ---------------- MEGA 1: bucket scatter (blocks < gB)  ||  layer-1 GEMM ----------------
// The build's edge-bucketing and the x@W1 GEMM are data-independent; fusing
// them in one launch overlaps bucketM's fabric/atomic latency under gemm1's
// MFMA/LDS work (serial stream: sum -> max). ebufC/R must NOT alias xtb here.

#define BUFB 24576
__global__ __launch_bounds__(256) void k_mega1(
    // bucket args
    const int* __restrict__ rows, const int* __restrict__ cols,
    int* __restrict__ bcurC, int* __restrict__ bcurR,
    unsigned* __restrict__ ebufC, unsigned short* __restrict__ ebufR,
    int E, int NSEG2, int gB,
    // gemm args
    const float* __restrict__ x,
    const short* __restrict__ Whi, const short* __restrict__ Wlo,
    const float* __restrict__ att1,
    unsigned* __restrict__ xtb, float* __restrict__ sl, float* __restrict__ sr, int N){
  __shared__ __align__(16) char smem[2*BUFB];

  if(blockIdx.x < gB){
    // ---- bucket path: LDS-rank per segment + block-level reservations ----
    int* lhC = (int*)smem;
    int* lbC = (int*)(smem + 1024);
    int* lhR = (int*)(smem + 2048);
    int* lbR = (int*)(smem + 3072);
    int tid = threadIdx.x;
    int e0 = blockIdx.x * CHB;
    #pragma unroll 1
    for(int r=0; r<4; r++){
      lhC[tid] = 0; lhR[tid] = 0;
      __syncthreads();
      int eb = e0 + r*2048;
      unsigned pk[8]; int sgC[8], rkC[8], sgR[8], rkR[8]; int pvR[8];
      #pragma unroll
      for(int i=0;i<8;i++){
        int e = eb + i*256 + tid;
        sgC[i] = -1;
        if(e < E){
          int cc = cols[e], rr = rows[e];
          sgC[i] = cc >> 9;
          pk[i]  = ((unsigned)(cc & (SEGN-1)) << 17) | (unsigned)rr;  // N < 131072
          rkC[i] = atomicAdd(&lhC[sgC[i]], 1);
          sgR[i] = rr >> 9;
          pvR[i] = rr & (SEGN-1);
          rkR[i] = atomicAdd(&lhR[sgR[i]], 1);
        }
      }
      __syncthreads();
      if(tid < NSEG2){
        int c = lhC[tid];  lbC[tid] = c  ? atomicAdd(&bcurC[tid], c)  : 0;
        int c2 = lhR[tid]; lbR[tid] = c2 ? atomicAdd(&bcurR[tid], c2) : 0;
      }
      __syncthreads();
      #pragma unroll
      for(int i=0;i<8;i++)
        if(sgC[i] >= 0){
          int p = lbC[sgC[i]] + rkC[i];
          if(p < CAPC) ebufC[sgC[i]*CAPC + p] = pk[i];     // overflow guard (never hits)
          int p2 = lbR[sgR[i]] + rkR[i];
          if(p2 < CAPC) ebufR[sgR[i]*CAPC + p2] = (unsigned short)pvR[i];
        }
      __syncthreads();
    }
    return;
  }

  // ---- gemm path: f32-A global_load_lds double-buffered pipeline ----
  int bid = blockIdx.x - gB;
  float* fx = (float*)smem;                  // epilogue alias: 64*68 floats
  float* att_sh = (float*)(smem + 17408);    // 256 floats

  int tid = threadIdx.x;
  int n0 = bid * 64;
  int w = tid >> 6, l = tid & 63;
  int wm = w & 1, wn = w >> 1;
  int lm = l & 15, lq = l >> 4;

  f32x4 acc[2][4];
  #pragma unroll
  for(int a=0;a<2;a++)
    #pragma unroll
    for(int b=0;b<4;b++) acc[a][b] = (f32x4){0.f,0.f,0.f,0.f};

  int ua0 = (w<<6) | l, ua1 = 256 + ua0;
  int ar0 = ua0 >> 3, as0 = (ua0 & 7) ^ (ar0 & 7);
  int ar1 = ua1 >> 3, as1 = (ua1 & 7) ^ (ar1 & 7);
  const float* gA0 = x + (size_t)min(n0 + ar0, N-1)*256 + as0*4;
  const float* gA1 = x + (size_t)min(n0 + ar1, N-1)*256 + as1*4;
  int ub0 = (w<<6) | l,  ub1 = 256 + ub0;
  int br0 = ub0 >> 2, bs0 = (ub0 & 3) ^ ((br0 >> 1) & 3);
  int br1 = ub1 >> 2, bs1 = (ub1 & 3) ^ ((br1 >> 1) & 3);
  const short* gBh0 = Whi + br0*256 + bs0*8;
  const short* gBh1 = Whi + br1*256 + bs1*8;
  const short* gBl0 = Wlo + br0*256 + bs0*8;
  const short* gBl1 = Wlo + br1*256 + bs1*8;
  int woff = w << 10;

  int offAf[2][2], offB[4];
  #pragma unroll
  for(int mt=0;mt<2;mt++){
    int rr = wm*32 + mt*16 + lm;
    offAf[mt][0] = rr*32 + (((2*lq+0) ^ (rr&7)) << 2);
    offAf[mt][1] = rr*32 + (((2*lq+1) ^ (rr&7)) << 2);
  }
  #pragma unroll
  for(int nt=0;nt<4;nt++){
    int rr = wn*64 + nt*16 + lm;
    offB[nt] = rr*32 + ((lq ^ ((rr>>1)&3)) << 3);
  }

  {
    char* base = smem;
    gl_lds16(gA0,  base          + woff);
    gl_lds16(gA1,  base + 4096   + woff);
    gl_lds16(gBh0, base + 8192   + woff);
    gl_lds16(gBh1, base + 12288  + woff);
    gl_lds16(gBl0, base + 16384  + woff);
    gl_lds16(gBl1, base + 20480  + woff);
  }
  __syncthreads();

  int cur = 0;
  #pragma unroll 1
  for(int c=0;c<8;c++){
    if(c < 7){
      int kf = (c+1) << 5;
      char* base = smem + (cur^1)*BUFB;
      gl_lds16(gA0  + kf, base          + woff);
      gl_lds16(gA1  + kf, base + 4096   + woff);
      gl_lds16(gBh0 + kf, base + 8192   + woff);
      gl_lds16(gBh1 + kf, base + 12288  + woff);
      gl_lds16(gBl0 + kf, base + 16384  + woff);
      gl_lds16(gBl1 + kf, base + 20480  + woff);
    }
    float* Axf = (float*)(smem + cur*BUFB);
    short* Bh  = (short*)(smem + cur*BUFB + 8192);
    short* Bl  = (short*)(smem + cur*BUFB + 16384);
    bf16x8 ah[2], al2[2];
    #pragma unroll
    for(int mt=0;mt<2;mt++){
      float4 f0 = *((const float4*)&Axf[offAf[mt][0]]);
      float4 f1 = *((const float4*)&Axf[offAf[mt][1]]);
      float fa[8] = {f0.x,f0.y,f0.z,f0.w,f1.x,f1.y,f1.z,f1.w};
      #pragma unroll
      for(int j=0;j<8;j++){
        unsigned short hb = bfr(fa[j]);
        float hf = __uint_as_float(((unsigned)hb) << 16);
        ah[mt][j]  = (short)hb;
        al2[mt][j] = (short)bfr(fa[j] - hf);
      }
    }
    #pragma unroll
    for(int nt=0;nt<4;nt++){
      bf16x8 bh = *((bf16x8*)&Bh[offB[nt]]);
      bf16x8 bl = *((bf16x8*)&Bl[offB[nt]]);
      #pragma unroll
      for(int mt=0;mt<2;mt++){
        acc[mt][nt] = __builtin_amdgcn_mfma_f32_16x16x32_bf16(ah[mt],  bh, acc[mt][nt], 0,0,0);
        acc[mt][nt] = __builtin_amdgcn_mfma_f32_16x16x32_bf16(ah[mt],  bl, acc[mt][nt], 0,0,0);
        acc[mt][nt] = __builtin_amdgcn_mfma_f32_16x16x32_bf16(al2[mt], bh, acc[mt][nt], 0,0,0);
      }
    }
    __syncthreads();
    cur ^= 1;
  }

  #pragma unroll
  for(int mt=0;mt<2;mt++){
    #pragma unroll
    for(int v=0;v<4;v++){
      int row = n0 + wm*32 + mt*16 + lq*4 + v;
      if(row < N){
        unsigned p0 = (unsigned)bfr(acc[mt][0][v]) | ((unsigned)bfr(acc[mt][2][v])<<16);
        unsigned p1 = (unsigned)bfr(acc[mt][1][v]) | ((unsigned)bfr(acc[mt][3][v])<<16);
        int jb = wn*32 + lm;
        xtb[(size_t)row*64 + jb]      = p0;
        xtb[(size_t)row*64 + jb + 16] = p1;
      }
    }
  }

  att_sh[tid] = att1[tid];
  #pragma unroll 1
  for(int p=0;p<2;p++){
    __syncthreads();
    if(wn == p){
      #pragma unroll
      for(int mt=0;mt<2;mt++)
        #pragma unroll
        for(int nt=0;nt<4;nt++)
          #pragma unroll
          for(int v=0;v<4;v++)
            fx[(wm*32 + mt*16 + lq*4 + v)*68 + nt*16 + lm] = acc[mt][nt][v];
    }
    __syncthreads();
    if(tid < 128){
      int rloc = tid >> 1, hh = tid & 1;
      int head = p*2 + hh;
      float a = 0.f, b = 0.f;
      #pragma unroll
      for(int c4=0;c4<8;c4++){
        float4 xv  = *((const float4*)&fx[rloc*68 + hh*32 + c4*4]);
        float4 alv = *((const float4*)&att_sh[head*64 + c4*4]);
        float4 arv = *((const float4*)&att_sh[head*64 + 32 + c4*4]);
        a += xv.x*alv.x + xv.y*alv.y + xv.z*alv.z + xv.w*alv.w;
        b += xv.x*arv.x + xv.y*arv.y + xv.z*arv.z + xv.w*arv.w;
      }
      int row = n0 + rloc;
      if(row < N){
        sl[(size_t)row*4 + head] = a;
        sr[(size_t)row*4 + head] = b;
      }
    }
  }
}

// ---------------- merged build: histogram + dinv + offs + counting-sort CSR ----------------
// One block per segment. Global base computed locally from bcurC (no global
// scan kernel needed): base(s) = sum_{s'<s} (min(bcurC[s'],CAPC) + nn(s')).
// Replaces k_cntseg + k_scan_bsum + k_sortfill2; ebufC's second read hits L2.

__global__ __launch_bounds__(256) void k_buildseg(const int* __restrict__ bcurC,
    const int* __restrict__ bcurR,
    const unsigned* __restrict__ ebufC, const unsigned short* __restrict__ ebufR,
    float* __restrict__ dinv, int* __restrict__ offs, int* __restrict__ csr,
    int N, int NSEG2){
  __shared__ int hc[SEGN];
  __shared__ int hr[SEGN];
  __shared__ int lcur[SEGN];
  __shared__ int sdata[256];
  __shared__ int stot[256];
  __shared__ int lbuf[SCAP];
  int s = blockIdx.x, tid = threadIdx.x;
  int lo = s*SEGN;
  int nn = min(SEGN, N - lo);

  // base via in-block prefix over all segments' totals (NSEG2 <= 256)
  int tot = 0;
  if(tid < NSEG2){
    int nn2 = min(SEGN, N - tid*SEGN);
    tot = min(bcurC[tid], CAPC) + nn2;
  }
  stot[tid] = tot; __syncthreads();
  for(int off=1; off<256; off<<=1){
    int add = (tid >= off) ? stot[tid-off] : 0;
    __syncthreads();
    stot[tid] += add;
    __syncthreads();
  }
  int cc = min(bcurC[s], CAPC);
  int base = stot[s] - (cc + nn);      // exclusive prefix at s

  // histograms
  for(int i=tid; i<SEGN; i+=256){ hc[i] = 0; hr[i] = 0; }
  __syncthreads();
  int cb = s*CAPC;
  int rc = min(bcurR[s], CAPC);
  for(int j=tid; j<cc; j+=256) atomicAdd(&hc[ebufC[cb + j] >> 17], 1);
  for(int j=tid; j<rc; j+=256) atomicAdd(&hr[ebufR[cb + j]], 1);
  __syncthreads();
  for(int i=tid; i<nn; i+=256) dinv[lo+i] = 1.f / sqrtf((float)(hr[i] + 1));

  // local exclusive scan of cnt = hc+1 (2 nodes/thread)
  int i0 = tid*2, i1 = i0+1;
  int v0 = (i0 < nn) ? hc[i0] + 1 : 0;
  int v1 = (i1 < nn) ? hc[i1] + 1 : 0;
  int ssum = v0 + v1;
  sdata[tid] = ssum; __syncthreads();
  int mine = ssum;
  for(int off=1; off<256; off<<=1){
    int add = (tid >= off) ? sdata[tid-off] : 0;
    __syncthreads();
    sdata[tid] += add;
    __syncthreads();
  }
  int total = sdata[255];
  int run0 = sdata[tid] - mine;
  int run1 = run0 + v0;

  if(total <= SCAP){
    if(i0 < nn){
      offs[lo+i0] = base + run0;
      lbuf[run0]  = lo + i0;        // self-loop at slot 0
      lcur[i0]    = run0 + 1;
      if(lo+i0 == N-1) offs[N] = base + run0 + v0;
    }
    if(i1 < nn){
      offs[lo+i1] = base + run1;
      lbuf[run1]  = lo + i1;
      lcur[i1]    = run1 + 1;
      if(lo+i1 == N-1) offs[N] = base + run1 + v1;
    }
    __syncthreads();
    for(int j=tid; j<cc; j+=256){
      unsigned pk = ebufC[cb + j];
      int li  = pk >> 17;
      int row = pk & 0x1FFFF;
      int p = atomicAdd(&lcur[li], 1);   // LDS atomic
      lbuf[p] = row;
    }
    __syncthreads();
    for(int j=tid; j<total; j+=256) csr[base + j] = lbuf[j];   // full-line streaming
  } else {
    // overflow fallback (statistically never): direct scatter, global cursors
    if(i0 < nn){
      offs[lo+i0] = base + run0;
      csr[base+run0] = lo + i0;
      lcur[i0] = base + run0 + 1;
      if(lo+i0 == N-1) offs[N] = base + run0 + v0;
    }
    if(i1 < nn){
      offs[lo+i1] = base + run1;
      csr[base+run1] = lo + i1;
      lcur[i1] = base + run1 + 1;
      if(lo+i1 == N-1) offs[N] = base + run1 + v1;
    }
    __syncthreads();
    for(int j=tid; j<cc; j+=256){
      unsigned pk = ebufC[cb + j];
      int li  = pk >> 17;
      int row = pk & 0x1FFFF;
      int p = atomicAdd(&lcur[li], 1);
      csr[p] = row;
    }
  }
}

// ---------------- layer 1 aggregation: one wave per target node ----------------

__global__ __launch_bounds__(64) void k_agg1(const int* __restrict__ offs, const int* __restrict__ srcs,
    const float* __restrict__ sl, const float* __restrict__ sr, const float* __restrict__ dinv,
    const unsigned* __restrict__ xtb, const float* __restrict__ b1, float* __restrict__ h, int N){
  __shared__ int   s_sh[64];
  __shared__ float w_sh[64*4];
  int n = blockIdx.x;
  if(n >= N) return;
  int lane = threadIdx.x;
  int beg = offs[n], end = offs[n+1];
  int deg = end - beg;
  float4 sln = *((const float4*)(sl + (size_t)n*4));
  int h0 = lane >> 5;
  float den0=0.f,den1=0.f,den2=0.f,den3=0.f;
  float acc0=0.f, acc1=0.f;

  if(deg <= 64){
    int j = beg + lane;
    int s = 0; float wd = 0.f;
    float a0=-1e30f, a1=-1e30f, a2=-1e30f, a3=-1e30f;
    if(j < end){
      s = srcs[j];
      float4 a = *((const float4*)(sr + (size_t)s*4));
      a0 = lrelu(sln.x + a.x);
      a1 = lrelu(sln.y + a.y);
      a2 = lrelu(sln.z + a.z);
      a3 = lrelu(sln.w + a.w);
      wd = dinv[s];
    }
    float m0=a0,m1=a1,m2=a2,m3=a3;
    #pragma unroll
    for(int o=32;o>0;o>>=1){
      m0 = fmaxf(m0, __shfl_xor(m0,o));
      m1 = fmaxf(m1, __shfl_xor(m1,o));
      m2 = fmaxf(m2, __shfl_xor(m2,o));
      m3 = fmaxf(m3, __shfl_xor(m3,o));
    }
    den0 = __expf(a0 - m0);
    den1 = __expf(a1 - m1);
    den2 = __expf(a2 - m2);
    den3 = __expf(a3 - m3);
    s_sh[lane] = s;
    w_sh[lane*4+0] = wd*den0;
    w_sh[lane*4+1] = wd*den1;
    w_sh[lane*4+2] = wd*den2;
    w_sh[lane*4+3] = wd*den3;
    __syncthreads();
    int k = 0;
    for(; k+8<=deg; k+=8){
      int sk[8];
      #pragma unroll
      for(int u=0;u<8;u++) sk[u] = __builtin_amdgcn_readfirstlane(s_sh[k+u]);
      unsigned pv[8];
      #pragma unroll
      for(int u=0;u<8;u++) pv[u] = xtb[(size_t)sk[u]*64 + lane];
      #pragma unroll
      for(int u=0;u<8;u++){
        float2 wv = *((const float2*)&w_sh[(k+u)*4 + h0*2]);
        acc0 += wv.x * __uint_as_float(pv[u] << 16);
        acc1 += wv.y * __uint_as_float(pv[u] & 0xffff0000u);
      }
    }
    for(; k<deg; k++){
      int sk = __builtin_amdgcn_readfirstlane(s_sh[k]);
      unsigned pvv = xtb[(size_t)sk*64 + lane];
      float2 wv = *((const float2*)&w_sh[k*4 + h0*2]);
      acc0 += wv.x * __uint_as_float(pvv << 16);
      acc1 += wv.y * __uint_as_float(pvv & 0xffff0000u);
    }
  } else {
    float m0=-1e30f,m1=-1e30f,m2=-1e30f,m3=-1e30f;
    for(int j=beg+lane; j<end; j+=64){
      int s = srcs[j];
      float4 a = *((const float4*)(sr + (size_t)s*4));
      m0 = fmaxf(m0, lrelu(sln.x + a.x));
      m1 = fmaxf(m1, lrelu(sln.y + a.y));
      m2 = fmaxf(m2, lrelu(sln.z + a.z));
      m3 = fmaxf(m3, lrelu(sln.w + a.w));
    }
    #pragma unroll
    for(int o=32;o>0;o>>=1){
      m0 = fmaxf(m0, __shfl_xor(m0,o));
      m1 = fmaxf(m1, __shfl_xor(m1,o));
      m2 = fmaxf(m2, __shfl_xor(m2,o));
      m3 = fmaxf(m3, __shfl_xor(m3,o));
    }
    for(int c0=beg; c0<end; c0+=64){
      int cnt = min(64, end-c0);
      int j = c0 + lane;
      float e0=0.f,e1=0.f,e2=0.f,e3=0.f, wd=0.f; int s=0;
      if(j<end){
        s = srcs[j];
        float4 a = *((const float4*)(sr + (size_t)s*4));
        e0 = __expf(lrelu(sln.x + a.x) - m0);
        e1 = __expf(lrelu(sln.y + a.y) - m1);
        e2 = __expf(lrelu(sln.z + a.z) - m2);
        e3 = __expf(lrelu(sln.w + a.w) - m3);
        wd = dinv[s];
      }
      den0+=e0; den1+=e1; den2+=e2; den3+=e3;
      s_sh[lane] = s;
      w_sh[lane*4+0] = wd*e0;
      w_sh[lane*4+1] = wd*e1;
      w_sh[lane*4+2] = wd*e2;
      w_sh[lane*4+3] = wd*e3;
      __syncthreads();
      int k = 0;
      for(; k+8<=cnt; k+=8){
        int sk[8];
        #pragma unroll
        for(int u=0;u<8;u++) sk[u] = __builtin_amdgcn_readfirstlane(s_sh[k+u]);
        unsigned pv[8];
        #pragma unroll
        for(int u=0;u<8;u++) pv[u] = xtb[(size_t)sk[u]*64 + lane];
        #pragma unroll
        for(int u=0;u<8;u++){
          float2 wv = *((const float2*)&w_sh[(k+u)*4 + h0*2]);
          acc0 += wv.x * __uint_as_float(pv[u] << 16);
          acc1 += wv.y * __uint_as_float(pv[u] & 0xffff0000u);
        }
      }
      for(; k<cnt; k++){
        int sk = __builtin_amdgcn_readfirstlane(s_sh[k]);
        unsigned pvv = xtb[(size_t)sk*64 + lane];
        float2 wv = *((const float2*)&w_sh[k*4 + h0*2]);
        acc0 += wv.x * __uint_as_float(pvv << 16);
        acc1 += wv.y * __uint_as_float(pvv & 0xffff0000u);
      }
      __syncthreads();
    }
  }
  #pragma unroll
  for(int o=32;o>0;o>>=1){
    den0 += __shfl_xor(den0,o);
    den1 += __shfl_xor(den1,o);
    den2 += __shfl_xor(den2,o);
    den3 += __shfl_xor(den3,o);
  }
  float din = dinv[n];
  int ch0 = (lane < 32) ? lane : lane + 32;   // pairs (c, c+32)
  int ch1 = ch0 + 32;
  float d0 = (lane < 32) ? den0 : den2;
  float d1 = (lane < 32) ? den1 : den3;
  float o0 = din*acc0/(d0 + 1e-16f) + b1[ch0];
  float o1 = din*acc1/(d1 + 1e-16f) + b1[ch1];
  h[(size_t)n*128 + ch0] = o0 > 0.f ? o0 : 0.f;
  h[(size_t)n*128 + ch1] = o1 > 0.f ? o1 : 0.f;
}

// ---------------- layer 2 GEMM (128->16) + attention scalars ----------------

__global__ __launch_bounds__(256) void k_gemm2(const float* __restrict__ hmat, const float* __restrict__ W2,
    const float* __restrict__ att2, unsigned* __restrict__ xt2b,
    float* __restrict__ sl2, float* __restrict__ sr2, int N){
  __shared__ float hs[16*132];
  __shared__ float ws[16*132];
  __shared__ float xs[16*16];
  int t = threadIdx.x;
  int n0 = blockIdx.x * 16;
  #pragma unroll
  for(int i=0;i<8;i++){
    int idx = t + 256*i;
    int k = idx >> 4, c = idx & 15;
    ws[c*132 + k] = W2[idx];
  }
  #pragma unroll
  for(int i=0;i<2;i++){
    int idx = t + 256*i;
    int r = idx >> 5, k4 = idx & 31;
    int n = n0 + r;
    float4 v = make_float4(0.f,0.f,0.f,0.f);
    if(n < N) v = ((const float4*)hmat)[(size_t)n*32 + k4];
    *((float4*)&hs[r*132 + k4*4]) = v;
  }
  __syncthreads();
  int r = t >> 4, c = t & 15;
  float acc = 0.f;
  for(int k=0;k<128;k+=4){
    float4 hv = *((const float4*)&hs[r*132+k]);
    float4 wv = *((const float4*)&ws[c*132+k]);
    acc += hv.x*wv.x + hv.y*wv.y + hv.z*wv.z + hv.w*wv.w;
  }
  xs[r*16 + c] = acc;
  __syncthreads();
  int n = n0 + r;
  if(c < 8 && n < N){
    unsigned pk = (unsigned)bfr(xs[r*16+c]) | ((unsigned)bfr(xs[r*16+c+8])<<16);
    xt2b[(size_t)n*8 + c] = pk;
  }
  if(t < 16){
    int nn = n0 + t;
    if(nn < N){
      float a = 0.f, b = 0.f;
      #pragma unroll
      for(int cc=0;cc<16;cc++){ float v = xs[t*16+cc]; a += v*att2[cc]; b += v*att2[16+cc]; }
      sl2[nn] = a; sr2[nn] = b;
    }
  }
}

// ---------------- layer 2 aggregation ----------------

__global__ __launch_bounds__(64) void k_agg2(const int* __restrict__ offs, const int* __restrict__ srcs,
    const float* __restrict__ sl2, const float* __restrict__ sr2, const float* __restrict__ dinv,
    const unsigned* __restrict__ xt2b, const float* __restrict__ b2, float* __restrict__ out, int N){
  __shared__ int   s_sh[64];
  __shared__ float w_sh[64];
  int n = blockIdx.x;
  if(n >= N) return;
  int lane = threadIdx.x;
  int beg = offs[n], end = offs[n+1];
  int deg = end - beg;
  float sln = sl2[n];
  float den = 0.f, acc0 = 0.f, acc1 = 0.f;
  int grp = lane >> 3, ch = lane & 7;

  if(deg <= 64){
    int j = beg + lane;
    int s = 0; float wd = 0.f; float a = -1e30f;
    if(j < end){
      s = srcs[j];
      a = lrelu(sln + sr2[s]);
      wd = dinv[s];
    }
    float m = a;
    #pragma unroll
    for(int o=32;o>0;o>>=1) m = fmaxf(m, __shfl_xor(m,o));
    float e = __expf(a - m);
    den = e;
    s_sh[lane] = s;
    w_sh[lane] = wd*e;
    __syncthreads();
    for(int k=0;k<deg;k+=8){
      int kk = k + grp;
      if(kk < deg){
        int sk = s_sh[kk];
        float wk = w_sh[kk];
        unsigned pv = xt2b[(size_t)sk*8 + ch];
        acc0 += wk * __uint_as_float(pv << 16);
        acc1 += wk * __uint_as_float(pv & 0xffff0000u);
      }
    }
  } else {
    float m = -1e30f;
    for(int j=beg+lane; j<end; j+=64)
      m = fmaxf(m, lrelu(sln + sr2[srcs[j]]));
    #pragma unroll
    for(int o=32;o>0;o>>=1) m = fmaxf(m, __shfl_xor(m,o));
    for(int c0=beg; c0<end; c0+=64){
      int cnt = min(64, end-c0);
      int j = c0 + lane;
      float e=0.f, wd=0.f; int s=0;
      if(j<end){
        s = srcs[j];
        e = __expf(lrelu(sln + sr2[s]) - m);
        wd = dinv[s];
      }
      den += e;
      s_sh[lane] = s;
      w_sh[lane] = wd*e;
      __syncthreads();
      for(int k=0;k<cnt;k+=8){
        int kk = k + grp;
        if(kk < cnt){
          int sk = s_sh[kk];
          float wk = w_sh[kk];
          unsigned pv = xt2b[(size_t)sk*8 + ch];
          acc0 += wk * __uint_as_float(pv << 16);
          acc1 += wk * __uint_as_float(pv & 0xffff0000u);
        }
      }
      __syncthreads();
    }
  }
  #pragma unroll
  for(int o=32;o>0;o>>=1) den += __shfl_xor(den,o);
  acc0 += __shfl_xor(acc0,8);  acc0 += __shfl_xor(acc0,16);  acc0 += __shfl_xor(acc0,32);
  acc1 += __shfl_xor(acc1,8);  acc1 += __shfl_xor(acc1,16);  acc1 += __shfl_xor(acc1,32);
  if(lane < 8){
    float din = dinv[n];
    out[(size_t)n*16 + lane]     = din*acc0/(den + 1e-16f) + b2[lane];
    out[(size_t)n*16 + lane + 8] = din*acc1/(den + 1e-16f) + b2[lane+8];
  }
}

// ---------------- host launch ----------------

extern "C" void kernel_launch(void* const* d_in, const int* in_sizes, int n_in,
                              void* d_out, int out_size, void* d_ws, size_t ws_size,
                              hipStream_t stream){
  const float* x    = (const float*)d_in[0];
  const int*   ei   = (const int*)d_in[1];
  const float* W1   = (const float*)d_in[2];
  const float* att1 = (const float*)d_in[3];
  const float* b1   = (const float*)d_in[4];
  const float* W2   = (const float*)d_in[5];
  const float* att2 = (const float*)d_in[6];
  const float* b2   = (const float*)d_in[7];
  int N = in_sizes[0] / 256;
  int E = in_sizes[1] / 2;
  const int* rows = ei;
  const int* cols = ei + E;
  float* out = (float*)d_out;

  int ET    = E + N;
  int NSEG2 = (N + SEGN - 1) / SEGN;   // requires N < 131072 (17-bit row pack), <=256 segs

  char* p = (char*)d_ws;
  auto alloc = [&](size_t bytes)->void*{ void* q = p; p += (bytes + 255) & ~(size_t)255; return q; };
  int*      offs    = (int*)alloc((size_t)(N+1)*4);
  int*      bcur    = (int*)alloc(512*4);     // [0:256)=C cursors, [256:512)=R cursors
  int*      csr     = (int*)alloc((size_t)ET*4);
  float*    dinv    = (float*)alloc((size_t)N*4);
  unsigned* xtb     = (unsigned*)alloc((size_t)N*64*4);
  float*    sl1     = (float*)alloc((size_t)N*16);
  float*    sr1     = (float*)alloc((size_t)N*16);
  float*    hbuf    = (float*)alloc((size_t)N*128*4);
  unsigned* xt2b    = (unsigned*)alloc((size_t)N*8*4);
  float*    sl2     = (float*)alloc((size_t)N*4);
  float*    sr2     = (float*)alloc((size_t)N*4);
  short*    Whi     = (short*)alloc((size_t)128*256*2);
  short*    Wlo     = (short*)alloc((size_t)128*256*2);
  // ebufC/R now DEDICATED (mega-launch overlaps bucketM with gemm1's xtb writes
  // — aliasing xtb would race within the fused launch):
  unsigned*       ebufC = (unsigned*)alloc((size_t)NSEG2*CAPC*4);       // ~9.6MB
  unsigned short* ebufR = (unsigned short*)alloc((size_t)NSEG2*CAPC*2); // ~4.8MB

  int* bcurC = bcur;
  int* bcurR = bcur + 256;

  int gB = (E + CHB - 1) / CHB;
  int gG = (N + 63) / 64;

  hipMemsetAsync(bcur, 0, 512*4, stream);
  k_prepW<<<128, 256, 0, stream>>>(W1, Whi, Wlo);
  k_mega1<<<gB + gG, 256, 0, stream>>>(rows, cols, bcurC, bcurR, ebufC, ebufR,
                                       E, NSEG2, gB,
                                       x, Whi, Wlo, att1, xtb, sl1, sr1, N);
  k_buildseg<<<NSEG2, 256, 0, stream>>>(bcurC, bcurR, ebufC, ebufR, dinv, offs, csr, N, NSEG2);
  k_agg1<<<N, 64, 0, stream>>>(offs, csr, sl1, sr1, dinv, xtb, b1, hbuf, N);
  k_gemm2<<<(N + 15)/16, 256, 0, stream>>>(hbuf, W2, att2, xt2b, sl2, sr2, N);
  k_agg2<<<N, 64, 0, stream>>>(offs, csr, sl2, sr2, dinv, xt2b, b2, out, N);
}